// Round 10
// baseline (2920.089 us; speedup 1.0000x reference)
//
#include <hip/hip_runtime.h>

// STA-LSTM forward: B=2048, S=128, D=64, H1=H2=128, OUT=1
// Round 10: G0 hoist (ha@taW precomputed by g0mm MFMA kernel; ph3 K=256->128)
//           + ph1 gate-h MFMA moved into P1 (spreads the B-load blob)
//           + amdgpu_waves_per_eu(2,2) on the recurrent kernels (NT=512-safe).
// Kernels: repack -> mf_ph1 -> ph2 -> g0mm -> mf_ph3h   (full tier)
//          repack -> mf_ph1 -> ph2 -> mf_ph3full        (if ws lacks G0 space)
//          fb_* VALU kernels                             (if ws < 130 MB)
// NOTE: NT=512 + launch_bounds(512,2)/waves_per_eu(2,2) is the ONLY config that
// reliably avoids spills (NT=1024 variants collapse to VGPR=64 + scratch).

#define BB 2048
#define SS 128
#define DD 64
#define HH 128
#define NG 512
#define M  8
#define NT 512

#define A_OFF    ((size_t)BB)
#define BETA_OFF ((size_t)BB + (size_t)SS*BB*DD)
#define H_BYTES  ((size_t)BB*SS*HH*4)
#define G0_BYTES ((size_t)BB*SS*NG*4)

// fragment buffer layout in ws (ushort offsets)
// gate B: K=192 ([saU(h) kk0-3 | saW(xw) kk4-5]), N=512
// attn B: K=320 ([saUa_h kt0-3 | saUa_c kt4-7 | saWa(x) kt8-9]), N=64
// Va: 64x64.  B3: K=256 ([taU kt0-3 | taW kt4-7]), N=512 (ph3h reads kt0-3,
// g0mm reads kt4-7).  RW/RV: ph2 bf16.
#define B1G_ELEMS (192*512)
#define B1A_ELEMS (320*64)
#define BVA_ELEMS (64*64)
#define B3_ELEMS  (256*512)
#define BW_ELEMS  (128*128)
#define GH_OFF 0
#define GL_OFF (B1G_ELEMS)
#define AH_OFF (2*B1G_ELEMS)
#define AL_OFF (2*B1G_ELEMS + B1A_ELEMS)
#define VH_OFF (2*B1G_ELEMS + 2*B1A_ELEMS)
#define VL_OFF (VH_OFF + BVA_ELEMS)
#define B3H_OFF (VH_OFF + 2*BVA_ELEMS)
#define B3L_OFF (B3H_OFF + B3_ELEMS)
#define RW_OFF  (B3H_OFF + 2*B3_ELEMS)
#define RV_OFF  (RW_OFF + BW_ELEMS)
#define FRAG_BYTES ((size_t)(RV_OFF + BW_ELEMS)*2)
#define NEED2_BYTES (FRAG_BYTES + H_BYTES)
#define NEED3_BYTES (FRAG_BYTES + H_BYTES + G0_BYTES)

typedef float f32x4 __attribute__((ext_vector_type(4)));
typedef __bf16 bf16x8 __attribute__((ext_vector_type(8)));
union FB { uint4 u; bf16x8 v; };
__device__ __forceinline__ bf16x8 as_bf(uint4 u){ FB x; x.u = u; return x.v; }

__device__ __forceinline__ unsigned short bf16rne(float f){
  unsigned u = __float_as_uint(f);
  u = (u + 0x7FFFu + ((u >> 16) & 1u)) >> 16;
  return (unsigned short)u;
}
__device__ __forceinline__ float bfval(unsigned short h){
  return __uint_as_float(((unsigned)h) << 16);
}

__device__ __forceinline__ float sigf(float x){ return 1.0f/(1.0f + __expf(-x)); }
__device__ __forceinline__ float tanhx(float x){ return 1.0f - 2.0f/(1.0f + __expf(2.0f*x)); }

__device__ __forceinline__ float wmax64(float v){
#pragma unroll
  for (int m = 32; m; m >>= 1) v = fmaxf(v, __shfl_xor(v, m, 64));
  return v;
}
__device__ __forceinline__ float wsum64(float v){
#pragma unroll
  for (int m = 32; m; m >>= 1) v += __shfl_xor(v, m, 64);
  return v;
}

// ================= repack: weights -> fragment-ordered buffers =================
__global__ __launch_bounds__(256) void repack_kernel(
    const float* __restrict__ saW, const float* __restrict__ saU,
    const float* __restrict__ saWa, const float* __restrict__ saUa,
    const float* __restrict__ saVa,
    const float* __restrict__ taU, const float* __restrict__ taW,
    const float* __restrict__ taWa, const float* __restrict__ taVa,
    unsigned short* __restrict__ F)
{
  int id = blockIdx.x*256 + threadIdx.x;
  if (id < B1G_ELEMS){          // gate: k 0-127 = saU(h), 128-191 = saW(xw)
    int k = id >> 9, n = id & 511;
    float v = (k < 128) ? saU[(size_t)k*NG + n] : saW[(size_t)(k-128)*NG + n];
    int kk = k >> 5, kw = k & 31, nt = n >> 4, nc = n & 15;
    int lane = ((kw >> 3) << 4) | nc, j = kw & 7;
    size_t off = ((size_t)(nt*6 + kk)*64 + lane)*8 + j;
    unsigned short hi = bf16rne(v);
    F[GH_OFF + off] = hi; F[GL_OFF + off] = bf16rne(v - bfval(hi));
  }
  if (id < B1A_ELEMS){          // attn: k 0-255 = saUa(h,c), 256-319 = saWa(x)
    int k = id >> 6, n = id & 63;
    float v = (k < 256) ? saUa[(size_t)k*DD + n] : saWa[(size_t)(k-256)*DD + n];
    int kt = k >> 5, kw = k & 31, nt = n >> 4, nc = n & 15;
    int lane = ((kw >> 3) << 4) | nc, j = kw & 7;
    size_t off = ((size_t)(nt*10 + kt)*64 + lane)*8 + j;
    unsigned short hi = bf16rne(v);
    F[AH_OFF + off] = hi; F[AL_OFF + off] = bf16rne(v - bfval(hi));
  }
  if (id < BVA_ELEMS){          // saVa 64x64
    int k = id >> 6, n = id & 63;
    float v = saVa[(size_t)k*DD + n];
    int kt = k >> 5, kw = k & 31, nt = n >> 4, nc = n & 15;
    int lane = ((kw >> 3) << 4) | nc, j = kw & 7;
    size_t off = ((size_t)(nt*2 + kt)*64 + lane)*8 + j;
    unsigned short hi = bf16rne(v);
    F[VH_OFF + off] = hi; F[VL_OFF + off] = bf16rne(v - bfval(hi));
  }
  if (id < B3_ELEMS){           // ph3: k 0-127 = taU(lh), 128-255 = taW(ha)
    int k = id >> 9, n = id & 511;
    float v = (k < HH) ? taU[(size_t)k*NG + n] : taW[(size_t)(k-HH)*NG + n];
    int kt = k >> 5, kw = k & 31, nt = n >> 4, nc = n & 15;
    int lane = ((kw >> 3) << 4) | nc, j = kw & 7;
    size_t off = ((size_t)(nt*8 + kt)*64 + lane)*8 + j;
    unsigned short hi = bf16rne(v);
    F[B3H_OFF + off] = hi; F[B3L_OFF + off] = bf16rne(v - bfval(hi));
  }
  if (id < BW_ELEMS){           // ph2 bf16 frags
    int k = id >> 7, n = id & 127;
    int kt = k >> 5, kw = k & 31, nt = n >> 4, nc = n & 15;
    int lane = ((kw >> 3) << 4) | nc, j = kw & 7;
    size_t off = ((size_t)(nt*4 + kt)*64 + lane)*8 + j;
    F[RW_OFF + off] = bf16rne(taWa[(size_t)k*SS + n]);
    F[RV_OFF + off] = bf16rne(taVa[(size_t)k*SS + n]);
  }
}

// ================= mf_ph1: spatial-attn LSTM, fully MFMA =================
// af tiles: 0-3 h, 4-7 c, 8-9 x (attn A, K=320); {0-3 h, 10-11 xw} = gate A.
// Gate-h MFMA (kk0-3) runs in P1 (accg in regs); P5 finishes kk4-5 (xw part).
struct P1 {
  uint4 afh[12*64];    // 12K
  uint4 afl[12*64];    // 12K
  uint4 aah[2*64];     // 2K
  uint4 aal[2*64];     // 2K
  float xx[M][DD];     // 2K
  float cc[M][HH];     // 4K
  float red[2][M][64]; // 4K
  float g[M][NG];      // 16K
  float sbias[NG];     // 2K
};
struct P2S { float A[32][HH]; float tmp[32][SS]; float bp[32][SS]; };  // fallback
union __align__(16) SMA { P1 p1; float pad[21504]; };   // 84K -> 1 blk/CU

__global__ __launch_bounds__(NT, 2) __attribute__((amdgpu_waves_per_eu(2, 2)))
void mf_ph1_kernel(
    const float* __restrict__ X,   const float* __restrict__ sab,
    const float* __restrict__ saba,
    const unsigned short* __restrict__ Fr,
    float* __restrict__ out, float* __restrict__ Hws)
{
  __shared__ SMA sm;
  const int tid = threadIdx.x;
  const int b0  = blockIdx.x * M;
  const int w   = tid >> 6, l = tid & 63;

  {
    uint4 z4 = make_uint4(0,0,0,0);
    for (int i = tid; i < 12*64; i += NT){ sm.p1.afh[i] = z4; sm.p1.afl[i] = z4; }
    if (tid < 2*64){ sm.p1.aah[tid] = z4; sm.p1.aal[tid] = z4; }
    for (int i = tid; i < M*HH; i += NT) ((float*)sm.p1.cc)[i] = 0.f;
    sm.p1.sbias[tid] = sab[tid];
  }
  __syncthreads();
  if (tid < 128){   // x(0) + x-frags (tiles 8-9)
    int r = tid >> 4, d0 = (tid & 15)*4;
    float4 v = *(const float4*)(X + (size_t)(b0+r)*SS*DD + d0);
    *(float4*)&sm.p1.xx[r][d0] = v;
    unsigned short* AFH = (unsigned short*)sm.p1.afh;
    unsigned short* AFL = (unsigned short*)sm.p1.afl;
    int kt = 8 + (d0 >> 5), lane = (((d0 & 31) >> 3) << 4) | r, jj0 = d0 & 7;
    float vv[4] = {v.x, v.y, v.z, v.w};
#pragma unroll
    for (int p = 0; p < 4; ++p){
      unsigned short h_ = bf16rne(vv[p]);
      AFH[(kt*64 + lane)*8 + jj0 + p] = h_;
      AFL[(kt*64 + lane)*8 + jj0 + p] = bf16rne(vv[p] - bfval(h_));
    }
  }
  __syncthreads();

  for (int t = 0; t < SS; ++t){
    // ---- P1: attn MFMA -> red  +  gate-h partial MFMA (kk0-3) -> accg regs ----
    f32x4 accg[4];
    {
      f32x4 zf = {0.f,0.f,0.f,0.f};
#pragma unroll
      for (int n4 = 0; n4 < 4; ++n4) accg[n4] = zf;
    }
    {
      const int nt = w & 3, kh = w >> 2;
      f32x4 a0 = {0.f,0.f,0.f,0.f}, a1 = {0.f,0.f,0.f,0.f};
      const uint4* BAH = (const uint4*)(Fr + AH_OFF);
      const uint4* BAL = (const uint4*)(Fr + AL_OFF);
#pragma unroll
      for (int q = 0; q < 5; ++q){
        const int kt = kh*5 + q;
        bf16x8 ah = as_bf(sm.p1.afh[kt*64 + l]);
        bf16x8 av = as_bf(sm.p1.afl[kt*64 + l]);
        bf16x8 bh = as_bf(BAH[(nt*10 + kt)*64 + l]);
        bf16x8 bl = as_bf(BAL[(nt*10 + kt)*64 + l]);
        if (q & 1){
          a1 = __builtin_amdgcn_mfma_f32_16x16x32_bf16(ah, bh, a1, 0, 0, 0);
          a1 = __builtin_amdgcn_mfma_f32_16x16x32_bf16(av, bh, a1, 0, 0, 0);
          a1 = __builtin_amdgcn_mfma_f32_16x16x32_bf16(ah, bl, a1, 0, 0, 0);
        } else {
          a0 = __builtin_amdgcn_mfma_f32_16x16x32_bf16(ah, bh, a0, 0, 0, 0);
          a0 = __builtin_amdgcn_mfma_f32_16x16x32_bf16(av, bh, a0, 0, 0, 0);
          a0 = __builtin_amdgcn_mfma_f32_16x16x32_bf16(ah, bl, a0, 0, 0, 0);
        }
      }
      f32x4 acc = a0 + a1;
      const int row0 = (l >> 4)*4, c0 = l & 15;
      if (row0 < 8){
#pragma unroll
        for (int jj = 0; jj < 4; ++jj)
          sm.p1.red[kh][row0+jj][nt*16 + c0] = acc[jj];
      }
      // gate-h part (no LDS writes; results stay in accg)
      const uint4* GH = (const uint4*)(Fr + GH_OFF);
      const uint4* GL = (const uint4*)(Fr + GL_OFF);
#pragma unroll
      for (int kk = 0; kk < 4; ++kk){
        bf16x8 ah = as_bf(sm.p1.afh[kk*64 + l]);
        bf16x8 av = as_bf(sm.p1.afl[kk*64 + l]);
#pragma unroll
        for (int n4 = 0; n4 < 4; ++n4){
          const int ntg = w*4 + n4;
          bf16x8 bh = as_bf(GH[(ntg*6 + kk)*64 + l]);
          bf16x8 bl = as_bf(GL[(ntg*6 + kk)*64 + l]);
          accg[n4] = __builtin_amdgcn_mfma_f32_16x16x32_bf16(ah, bh, accg[n4], 0, 0, 0);
          accg[n4] = __builtin_amdgcn_mfma_f32_16x16x32_bf16(av, bh, accg[n4], 0, 0, 0);
          accg[n4] = __builtin_amdgcn_mfma_f32_16x16x32_bf16(ah, bl, accg[n4], 0, 0, 0);
        }
      }
    }
    __syncthreads();

    // ---- P2: combine + bias + tanh -> a-frags ----
    {
      const int r = w, col = l;
      float s = sm.p1.red[0][r][col] + sm.p1.red[1][r][col] + saba[col];
      float av = tanhx(s);
      unsigned short h_ = bf16rne(av);
      int kt = col >> 5, lane = (((col & 31) >> 3) << 4) | r, jj = col & 7;
      ((unsigned short*)sm.p1.aah)[(kt*64 + lane)*8 + jj] = h_;
      ((unsigned short*)sm.p1.aal)[(kt*64 + lane)*8 + jj] = bf16rne(av - bfval(h_));
    }
    __syncthreads();

    // ---- P3: GEMM2 MFMA  av = a @ saVa ----
    {
      const int nt = w & 3, kt = w >> 2;   // kt 0-1
      f32x4 acc = {0.f,0.f,0.f,0.f};
      bf16x8 ah = as_bf(sm.p1.aah[kt*64 + l]);
      bf16x8 av = as_bf(sm.p1.aal[kt*64 + l]);
      bf16x8 bh = as_bf(((const uint4*)(Fr + VH_OFF))[(nt*2 + kt)*64 + l]);
      bf16x8 bl = as_bf(((const uint4*)(Fr + VL_OFF))[(nt*2 + kt)*64 + l]);
      acc = __builtin_amdgcn_mfma_f32_16x16x32_bf16(ah, bh, acc, 0, 0, 0);
      acc = __builtin_amdgcn_mfma_f32_16x16x32_bf16(av, bh, acc, 0, 0, 0);
      acc = __builtin_amdgcn_mfma_f32_16x16x32_bf16(ah, bl, acc, 0, 0, 0);
      const int row0 = (l >> 4)*4, c0 = l & 15;
      if (row0 < 8){
#pragma unroll
        for (int jj = 0; jj < 4; ++jj)
          sm.p1.red[kt][row0+jj][nt*16 + c0] = acc[jj];
      }
    }
    __syncthreads();

    // ---- P4: softmax + alphas out + xw-frags (tiles 10-11) ----
    {
      const int r = w, col = l;
      float s = sm.p1.red[0][r][col] + sm.p1.red[1][r][col];
      float mm = wmax64(s);
      float e  = __expf(s - mm);
      float alv = e * (1.0f / wsum64(e));
      out[A_OFF + (size_t)t*BB*DD + (size_t)(b0+r)*DD + col] = alv;
      float xwv = alv * sm.p1.xx[r][col];
      unsigned short h_ = bf16rne(xwv);
      int kt = 10 + (col >> 5), lane = (((col & 31) >> 3) << 4) | r, jj = col & 7;
      ((unsigned short*)sm.p1.afh)[(kt*64 + lane)*8 + jj] = h_;
      ((unsigned short*)sm.p1.afl)[(kt*64 + lane)*8 + jj] = bf16rne(xwv - bfval(h_));
    }
    __syncthreads();

    // ---- P5: gates xw-part (kk4-5) + x(t+1) prefetch issue ----
    float4 pf;
    const bool dox = (tid < 128) && (t + 1 < SS);
    if (dox){
      int r = tid >> 4, d0 = (tid & 15)*4;
      pf = *(const float4*)(X + (size_t)(b0+r)*SS*DD + (size_t)(t+1)*DD + d0);
    }
    {
      const uint4* GH = (const uint4*)(Fr + GH_OFF);
      const uint4* GL = (const uint4*)(Fr + GL_OFF);
#pragma unroll
      for (int kk = 4; kk < 6; ++kk){
        const int afi = kk + 6;   // 10, 11
        bf16x8 ah = as_bf(sm.p1.afh[afi*64 + l]);
        bf16x8 av = as_bf(sm.p1.afl[afi*64 + l]);
#pragma unroll
        for (int n4 = 0; n4 < 4; ++n4){
          const int ntg = w*4 + n4;
          bf16x8 bh = as_bf(GH[(ntg*6 + kk)*64 + l]);
          bf16x8 bl = as_bf(GL[(ntg*6 + kk)*64 + l]);
          accg[n4] = __builtin_amdgcn_mfma_f32_16x16x32_bf16(ah, bh, accg[n4], 0, 0, 0);
          accg[n4] = __builtin_amdgcn_mfma_f32_16x16x32_bf16(av, bh, accg[n4], 0, 0, 0);
          accg[n4] = __builtin_amdgcn_mfma_f32_16x16x32_bf16(ah, bl, accg[n4], 0, 0, 0);
        }
      }
      const int row0 = (l >> 4)*4, c0 = l & 15;
      if (row0 < 8){
#pragma unroll
        for (int n4 = 0; n4 < 4; ++n4){
          int col = w*64 + n4*16 + c0;
          float b = sm.p1.sbias[col];
#pragma unroll
          for (int jj = 0; jj < 4; ++jj)
            sm.p1.g[row0+jj][col] = accg[n4][jj] + b;
        }
      }
    }
    __syncthreads();

    // ---- P6: pointwise + h/c frag build + H store + x(t+1) commit ----
    {
      unsigned short* AFH = (unsigned short*)sm.p1.afh;
      unsigned short* AFL = (unsigned short*)sm.p1.afl;
#pragma unroll
      for (int h2 = 0; h2 < 2; ++h2){
        int idx = h2*NT + tid;
        int r = idx >> 7, j = idx & 127;
        float iv = sigf (sm.p1.g[r][j]);
        float fv = sigf (sm.p1.g[r][j + 128]);
        float gv = tanhx(sm.p1.g[r][j + 256]);
        float ov = sigf (sm.p1.g[r][j + 384]);
        float cn = fv * sm.p1.cc[r][j] + iv * gv;
        float hn = ov * tanhx(cn);
        sm.p1.cc[r][j] = cn;
        Hws[(size_t)(b0+r)*SS*HH + (size_t)t*HH + j] = hn;
        int lane = (((j & 31) >> 3) << 4) | r, jj = j & 7;
        int ktH = j >> 5, ktC = 4 + (j >> 5);
        unsigned short hh_ = bf16rne(hn);
        unsigned short ch_ = bf16rne(cn);
        AFH[(ktH*64 + lane)*8 + jj] = hh_;
        AFL[(ktH*64 + lane)*8 + jj] = bf16rne(hn - bfval(hh_));
        AFH[(ktC*64 + lane)*8 + jj] = ch_;
        AFL[(ktC*64 + lane)*8 + jj] = bf16rne(cn - bfval(ch_));
      }
      if (dox){
        int r = tid >> 4, d0 = (tid & 15)*4;
        *(float4*)&sm.p1.xx[r][d0] = pf;
        int kt = 8 + (d0 >> 5), lane = (((d0 & 31) >> 3) << 4) | r, jj0 = d0 & 7;
        float vv[4] = {pf.x, pf.y, pf.z, pf.w};
#pragma unroll
        for (int p = 0; p < 4; ++p){
          unsigned short h_ = bf16rne(vv[p]);
          AFH[(kt*64 + lane)*8 + jj0 + p] = h_;
          AFL[(kt*64 + lane)*8 + jj0 + p] = bf16rne(vv[p] - bfval(h_));
        }
      }
    }
    __syncthreads();
  }
}

// ================= ph2_kernel: betas + h_att, all-MFMA (round 8) ===========
struct PH2SM {
  uint4 fA[8][4][64];          // 32 KB
  uint4 fB[8][4][64];          // 32 KB
  unsigned short S[128][136];  // 34 KB (pad 8)
  float bias[SS];
};

__global__ __launch_bounds__(NT, 2) void ph2_kernel(
    const float* __restrict__ taba, const unsigned short* __restrict__ Fr,
    float* __restrict__ out, float* __restrict__ Hws)
{
  __shared__ PH2SM sm;
  const int tid = threadIdx.x;
  const int b   = blockIdx.x;
  const int w   = tid >> 6, l = tid & 63;
  const int g   = l >> 4, c0 = l & 15;
  float* Hb = Hws + (size_t)b * SS * HH;

  if (tid < SS) sm.bias[tid] = taba[tid];
  {
    const float4* src = (const float4*)Hb;
#pragma unroll
    for (int i = 0; i < 8; ++i){
      int fidx = i*NT + tid;
      float4 v = src[fidx];
      int e0 = fidx*4, row = e0 >> 7, col = e0 & 127;
      sm.S[row][col+0] = bf16rne(v.x);
      sm.S[row][col+1] = bf16rne(v.y);
      sm.S[row][col+2] = bf16rne(v.z);
      sm.S[row][col+3] = bf16rne(v.w);
    }
  }
  __syncthreads();

#pragma unroll
  for (int i = 0; i < 4; ++i){
    int slot = i*NT + tid;
    int mt = slot >> 8, kt = (slot >> 6) & 3, ll = slot & 63;
    int row = mt*16 + (ll & 15), k0 = kt*32 + (ll >> 4)*8;
    ((uint4*)sm.fA)[slot] = *(const uint4*)&sm.S[row][k0];
  }
#pragma unroll
  for (int i = 0; i < 4; ++i){
    int slot = i*NT + tid;
    int nt = slot >> 8, kt = (slot >> 6) & 3, ll = slot & 63;
    int col = nt*16 + (ll & 15), s0 = kt*32 + (ll >> 4)*8;
    unsigned u[4];
#pragma unroll
    for (int p = 0; p < 4; ++p)
      u[p] = (unsigned)sm.S[s0+2*p][col] | ((unsigned)sm.S[s0+2*p+1][col] << 16);
    ((uint4*)sm.fB)[slot] = make_uint4(u[0], u[1], u[2], u[3]);
  }
  __syncthreads();

  f32x4 acc[8];
  f32x4 zero4 = {0.f, 0.f, 0.f, 0.f};

#pragma unroll
  for (int nt = 0; nt < 8; ++nt) acc[nt] = zero4;
  {
    const uint4* BW = (const uint4*)(Fr + RW_OFF);
#pragma unroll
    for (int kt = 0; kt < 4; ++kt){
      bf16x8 a = as_bf(sm.fA[w][kt][l]);
#pragma unroll
      for (int nt = 0; nt < 8; ++nt){
        bf16x8 bv = as_bf(BW[(nt*4 + kt)*64 + l]);
        acc[nt] = __builtin_amdgcn_mfma_f32_16x16x32_bf16(a, bv, acc[nt], 0, 0, 0);
      }
    }
  }
#pragma unroll
  for (int nt = 0; nt < 8; ++nt){
    int col = nt*16 + c0;
    float bv = sm.bias[col];
#pragma unroll
    for (int j = 0; j < 4; ++j)
      sm.S[w*16 + g*4 + j][col] = bf16rne(tanhx(acc[nt][j] + bv));
  }
  __syncthreads();

#pragma unroll
  for (int i = 0; i < 4; ++i){
    int slot = i*NT + tid;
    int mt = slot >> 8, kt = (slot >> 6) & 3, ll = slot & 63;
    int row = mt*16 + (ll & 15), k0 = kt*32 + (ll >> 4)*8;
    ((uint4*)sm.fA)[slot] = *(const uint4*)&sm.S[row][k0];
  }
  __syncthreads();

#pragma unroll
  for (int nt = 0; nt < 8; ++nt) acc[nt] = zero4;
  {
    const uint4* BV = (const uint4*)(Fr + RV_OFF);
#pragma unroll
    for (int kt = 0; kt < 4; ++kt){
      bf16x8 a = as_bf(sm.fA[w][kt][l]);
#pragma unroll
      for (int nt = 0; nt < 8; ++nt){
        bf16x8 bv = as_bf(BV[(nt*4 + kt)*64 + l]);
        acc[nt] = __builtin_amdgcn_mfma_f32_16x16x32_bf16(a, bv, acc[nt], 0, 0, 0);
      }
    }
  }

#pragma unroll
  for (int j = 0; j < 4; ++j){
    float m = acc[0][j];
#pragma unroll
    for (int nt = 1; nt < 8; ++nt) m = fmaxf(m, acc[nt][j]);
#pragma unroll
    for (int ms = 1; ms < 16; ms <<= 1) m = fmaxf(m, __shfl_xor(m, ms, 64));
    float e[8], s = 0.f;
#pragma unroll
    for (int nt = 0; nt < 8; ++nt){ e[nt] = __expf(acc[nt][j] - m); s += e[nt]; }
#pragma unroll
    for (int ms = 1; ms < 16; ms <<= 1) s += __shfl_xor(s, ms, 64);
    float inv = 1.0f / s;
    int row = w*16 + g*4 + j;
    size_t bo = BETA_OFF + (size_t)row*BB*SS + (size_t)b*SS;
#pragma unroll
    for (int nt = 0; nt < 8; ++nt){
      float bv = e[nt] * inv;
      out[bo + nt*16 + c0] = bv;
      sm.S[row][nt*16 + c0] = bf16rne(bv);
    }
  }
  __syncthreads();

#pragma unroll
  for (int i = 0; i < 4; ++i){
    int slot = i*NT + tid;
    int mt = slot >> 8, kt = (slot >> 6) & 3, ll = slot & 63;
    int row = mt*16 + (ll & 15), k0 = kt*32 + (ll >> 4)*8;
    ((uint4*)sm.fA)[slot] = *(const uint4*)&sm.S[row][k0];
  }
  __syncthreads();

#pragma unroll
  for (int nt = 0; nt < 8; ++nt) acc[nt] = zero4;
#pragma unroll
  for (int kt = 0; kt < 4; ++kt){
    bf16x8 a = as_bf(sm.fA[w][kt][l]);
#pragma unroll
    for (int nt = 0; nt < 8; ++nt){
      bf16x8 bv = as_bf(sm.fB[nt][kt][l]);
      acc[nt] = __builtin_amdgcn_mfma_f32_16x16x32_bf16(a, bv, acc[nt], 0, 0, 0);
    }
  }
#pragma unroll
  for (int nt = 0; nt < 8; ++nt){
#pragma unroll
    for (int j = 0; j < 4; ++j)
      Hb[(size_t)(w*16 + g*4 + j)*HH + nt*16 + c0] = acc[nt][j];
  }
}

// ================= g0mm: G0[t][b][:] = h_att @ taW + tab (split-bf16) ==========
// 2048 blocks x 512 thr; block handles 128 consecutive (b,t) rows of Ha.
struct GMM { uint4 afh[8][4][64]; uint4 afl[8][4][64]; };   // 64 KB

__global__ __launch_bounds__(NT, 2) void g0mm_kernel(
    const float* __restrict__ Ha, const unsigned short* __restrict__ Fr,
    const float* __restrict__ tab, float* __restrict__ G0)
{
  __shared__ GMM sm;
  const int tid = threadIdx.x;
  const size_t r0 = (size_t)blockIdx.x * 128;
  const int w = tid >> 6, l = tid & 63;
  const int row0 = (l >> 4)*4, c0 = l & 15;

  // stage Ha rows -> split-bf16 A-frags (mt 0..7, kt 0..3)
  {
    const float4* src = (const float4*)(Ha + r0*HH);
    unsigned short* AFH = (unsigned short*)sm.afh;
    unsigned short* AFL = (unsigned short*)sm.afl;
#pragma unroll
    for (int i = 0; i < 8; ++i){
      int f = i*NT + tid;            // 4096 float4
      float4 v = src[f];
      int e0 = f*4, rl = e0 >> 7, k0 = e0 & 127;
      int mt = rl >> 4, kt = k0 >> 5;
      int lane = (((k0 & 31) >> 3) << 4) | (rl & 15), j0 = k0 & 7;
      size_t base = ((size_t)(mt*4 + kt)*64 + lane)*8 + j0;
      float vv[4] = {v.x, v.y, v.z, v.w};
#pragma unroll
      for (int p = 0; p < 4; ++p){
        unsigned short h_ = bf16rne(vv[p]);
        AFH[base + p] = h_;
        AFL[base + p] = bf16rne(vv[p] - bfval(h_));
      }
    }
  }
  __syncthreads();

  const uint4* BH = (const uint4*)(Fr + B3H_OFF);
  const uint4* BL = (const uint4*)(Fr + B3L_OFF);
#pragma unroll
  for (int q = 0; q < 4; ++q){
    const int nt = w*4 + q;          // 0..31
    uint4 bh[4], bl[4];
#pragma unroll
    for (int kt = 0; kt < 4; ++kt){  // taW = kt 4-7 of B3 layout
      bh[kt] = BH[(nt*8 + 4 + kt)*64 + l];
      bl[kt] = BL[(nt*8 + 4 + kt)*64 + l];
    }
    const int col = nt*16 + c0;
    const float tb = tab[col];
    f32x4 zero4 = {0.f,0.f,0.f,0.f};
    f32x4 acc[8];
#pragma unroll
    for (int mt = 0; mt < 8; ++mt) acc[mt] = zero4;
#pragma unroll
    for (int mt = 0; mt < 8; ++mt){
#pragma unroll
      for (int kt = 0; kt < 4; ++kt){
        bf16x8 ah = as_bf(sm.afh[mt][kt][l]);
        bf16x8 av = as_bf(sm.afl[mt][kt][l]);
        bf16x8 vbh = as_bf(bh[kt]);
        bf16x8 vbl = as_bf(bl[kt]);
        acc[mt] = __builtin_amdgcn_mfma_f32_16x16x32_bf16(ah, vbh, acc[mt], 0, 0, 0);
        acc[mt] = __builtin_amdgcn_mfma_f32_16x16x32_bf16(av, vbh, acc[mt], 0, 0, 0);
        acc[mt] = __builtin_amdgcn_mfma_f32_16x16x32_bf16(ah, vbl, acc[mt], 0, 0, 0);
      }
    }
#pragma unroll
    for (int mt = 0; mt < 8; ++mt){
#pragma unroll
      for (int j = 0; j < 4; ++j){
        size_t row = r0 + mt*16 + row0 + j;       // flat (b,t)
        int b = (int)(row >> 7), t = (int)(row & 127);
        G0[((size_t)t*BB + b)*NG + col] = acc[mt][j] + tb;
      }
    }
  }
}

// ================= mf_ph3h: temporal LSTM, K=128 (G0-hoisted) =================
// af tiles 0-3: lh only.
struct P3H {
  uint4 afh[4*64];     // 4K
  uint4 afl[4*64];     // 4K
  float lh[M][HH];     // 4K
  float lc[M][HH];     // 4K
  float g[M][NG];      // 16K
  float wy[NG];        // 2K
  float fcv[HH];
  float yp[M];
};
union __align__(16) SMCH { P3H s; float pad[21504]; };   // 84K -> 1 blk/CU

__global__ __launch_bounds__(NT, 2) __attribute__((amdgpu_waves_per_eu(2, 2)))
void mf_ph3h_kernel(
    const float* __restrict__ X, const unsigned short* __restrict__ Fr,
    const float* __restrict__ G0,
    const float* __restrict__ taWy,
    const float* __restrict__ fcw, const float* __restrict__ fcb,
    float* __restrict__ out)
{
  __shared__ SMCH sm;
  const int tid = threadIdx.x;
  const int b0  = blockIdx.x * M;
  const int w   = tid >> 6, l = tid & 63;
  const int row0 = (l >> 4)*4, c0 = l & 15;

  {
    uint4 z4 = make_uint4(0,0,0,0);
    if (tid < 4*64){ sm.s.afh[tid] = z4; sm.s.afl[tid] = z4; }
    for (int i = tid; i < M*HH; i += NT){
      ((float*)sm.s.lh)[i] = 0.f; ((float*)sm.s.lc)[i] = 0.f;
    }
    sm.s.wy[tid] = taWy[tid];
    if (tid < HH) sm.s.fcv[tid] = fcw[tid];
    if (tid < M)  sm.s.yp[tid] = X[(size_t)(b0+tid)*SS*DD + (DD-1)];
  }
  __syncthreads();

  for (int t = 0; t < SS; ++t){
    // ---- Q1: G0 ext prefetch + gates MFMA (K=128) + g write ----
    {
      float g0v[16];
      if (row0 < 8){
#pragma unroll
        for (int n4 = 0; n4 < 4; ++n4){
#pragma unroll
          for (int j = 0; j < 4; ++j)
            g0v[n4*4+j] = G0[((size_t)t*BB + (b0+row0+j))*NG + (w*64 + n4*16 + c0)];
        }
      }
      f32x4 zero4 = {0.f,0.f,0.f,0.f};
      f32x4 acc[4];
#pragma unroll
      for (int n4 = 0; n4 < 4; ++n4) acc[n4] = zero4;
      const uint4* BH = (const uint4*)(Fr + B3H_OFF);
      const uint4* BL = (const uint4*)(Fr + B3L_OFF);
#pragma unroll
      for (int kt = 0; kt < 4; ++kt){      // taU = kt 0-3
        bf16x8 ah = as_bf(sm.s.afh[kt*64 + l]);
        bf16x8 av = as_bf(sm.s.afl[kt*64 + l]);
#pragma unroll
        for (int n4 = 0; n4 < 4; ++n4){
          const int ntg = w*4 + n4;
          bf16x8 bh = as_bf(BH[(ntg*8 + kt)*64 + l]);
          bf16x8 bl = as_bf(BL[(ntg*8 + kt)*64 + l]);
          acc[n4] = __builtin_amdgcn_mfma_f32_16x16x32_bf16(ah, bh, acc[n4], 0, 0, 0);
          acc[n4] = __builtin_amdgcn_mfma_f32_16x16x32_bf16(av, bh, acc[n4], 0, 0, 0);
          acc[n4] = __builtin_amdgcn_mfma_f32_16x16x32_bf16(ah, bl, acc[n4], 0, 0, 0);
        }
      }
      if (row0 < 8){
#pragma unroll
        for (int n4 = 0; n4 < 4; ++n4){
          int col = w*64 + n4*16 + c0;
          float wv = sm.s.wy[col];
#pragma unroll
          for (int j = 0; j < 4; ++j)
            sm.s.g[row0+j][col] = acc[n4][j] + g0v[n4*4+j] + sm.s.yp[row0+j]*wv;
        }
      }
    }
    __syncthreads();

    // ---- Q2: pointwise + lh-frag build (tiles 0-3) ----
    {
      unsigned short* AFH = (unsigned short*)sm.s.afh;
      unsigned short* AFL = (unsigned short*)sm.s.afl;
#pragma unroll
      for (int h2 = 0; h2 < 2; ++h2){
        int idx = h2*NT + tid;
        int r = idx >> 7, j = idx & 127;
        float iv = sigf (sm.s.g[r][j]);
        float fv = sigf (sm.s.g[r][j + 128]);
        float gv = tanhx(sm.s.g[r][j + 256]);
        float ov = sigf (sm.s.g[r][j + 384]);
        float cn = fv * sm.s.lc[r][j] + iv * gv;
        float hn = ov * tanhx(cn);
        sm.s.lc[r][j] = cn; sm.s.lh[r][j] = hn;
        int kt = j >> 5, lane = (((j & 31) >> 3) << 4) | r, jj = j & 7;
        unsigned short h_ = bf16rne(hn);
        AFH[(kt*64 + lane)*8 + jj] = h_;
        AFL[(kt*64 + lane)*8 + jj] = bf16rne(hn - bfval(h_));
      }
    }
    __syncthreads();

    // ---- Q3: fc reduce ----
    {
      const int r = w, lx = l;
      float p = sm.s.lh[r][lx]*sm.s.fcv[lx] + sm.s.lh[r][lx+64]*sm.s.fcv[lx+64];
      p = wsum64(p);
      if (lx == 0) sm.s.yp[r] = p + fcb[0];
    }
    __syncthreads();
  }

  if (tid < M) out[b0 + tid] = sm.s.yp[tid];
}

// ================= mf_ph3full: round-9 K=256 variant (tier-2 fallback) ==========
struct P3 {
  uint4 afh[8*64];
  uint4 afl[8*64];
  float lh[M][HH];
  float lc[M][HH];
  float g[M][NG];
  float sb[NG];
  float wy[NG];
  float fcv[HH];
  float yp[M];
};
union __align__(16) SMC { P3 s; float pad[21504]; };

__global__ __launch_bounds__(NT, 2) void mf_ph3_kernel(
    const float* __restrict__ X, const float* __restrict__ Ha,
    const unsigned short* __restrict__ Fr,
    const float* __restrict__ tab, const float* __restrict__ taWy,
    const float* __restrict__ fcw, const float* __restrict__ fcb,
    float* __restrict__ out)
{
  __shared__ SMC sm;
  const int tid = threadIdx.x;
  const int b0  = blockIdx.x * M;
  const int w   = tid >> 6, l = tid & 63;

  {
    uint4 z4 = make_uint4(0,0,0,0);
    sm.s.afh[tid] = z4; sm.s.afl[tid] = z4;
    for (int i = tid; i < M*HH; i += NT){
      ((float*)sm.s.lh)[i] = 0.f; ((float*)sm.s.lc)[i] = 0.f;
    }
    sm.s.sb[tid] = tab[tid];
    sm.s.wy[tid] = taWy[tid];
    if (tid < HH) sm.s.fcv[tid] = fcw[tid];
    if (tid < M)  sm.s.yp[tid] = X[(size_t)(b0+tid)*SS*DD + (DD-1)];
  }
  __syncthreads();
  if (tid < 256){
    int r = tid >> 5, d0 = (tid & 31)*4;
    float4 v = *(const float4*)(Ha + (size_t)(b0+r)*SS*HH + d0);
    unsigned short* AFH = (unsigned short*)sm.s.afh;
    unsigned short* AFL = (unsigned short*)sm.s.afl;
    int kt = 4 + (d0 >> 5), lane = (((d0 & 31) >> 3) << 4) | r, jj0 = d0 & 7;
    float vv[4] = {v.x, v.y, v.z, v.w};
#pragma unroll
    for (int p = 0; p < 4; ++p){
      unsigned short h_ = bf16rne(vv[p]);
      AFH[(kt*64 + lane)*8 + jj0 + p] = h_;
      AFL[(kt*64 + lane)*8 + jj0 + p] = bf16rne(vv[p] - bfval(h_));
    }
  }
  __syncthreads();

  for (int t = 0; t < SS; ++t){
    float4 pf;
    const bool dop = (tid < 256) && (t + 1 < SS);
    if (dop){
      int r = tid >> 5, d0 = (tid & 31)*4;
      pf = *(const float4*)(Ha + (size_t)(b0+r)*SS*HH + (size_t)(t+1)*HH + d0);
    }
    {
      f32x4 zero4 = {0.f,0.f,0.f,0.f};
      f32x4 acc[4];
#pragma unroll
      for (int n4 = 0; n4 < 4; ++n4) acc[n4] = zero4;
      const uint4* BH = (const uint4*)(Fr + B3H_OFF);
      const uint4* BL = (const uint4*)(Fr + B3L_OFF);
#pragma unroll
      for (int kt = 0; kt < 8; ++kt){
        bf16x8 ah = as_bf(sm.s.afh[kt*64 + l]);
        bf16x8 av = as_bf(sm.s.afl[kt*64 + l]);
#pragma unroll
        for (int n4 = 0; n4 < 4; ++n4){
          const int ntg = w*4 + n4;
          bf16x8 bh = as_bf(BH[(ntg*8 + kt)*64 + l]);
          bf16x8 bl = as_bf(BL[(ntg*8 + kt)*64 + l]);
          acc[n4] = __builtin_amdgcn_mfma_f32_16x16x32_bf16(ah, bh, acc[n4], 0, 0, 0);
          acc[n4] = __builtin_amdgcn_mfma_f32_16x16x32_bf16(av, bh, acc[n4], 0, 0, 0);
          acc[n4] = __builtin_amdgcn_mfma_f32_16x16x32_bf16(ah, bl, acc[n4], 0, 0, 0);
        }
      }
      const int row0 = (l >> 4)*4;
      if (row0 < 8){
        const int colb = w*64 + (l & 15);
#pragma unroll
        for (int n4 = 0; n4 < 4; ++n4){
          int col = colb + n4*16;
          float b = sm.s.sb[col];
          float wv = sm.s.wy[col];
#pragma unroll
          for (int j = 0; j < 4; ++j)
            sm.s.g[row0+j][col] = acc[n4][j] + b + sm.s.yp[row0+j]*wv;
        }
      }
    }
    __syncthreads();

    {
      unsigned short* AFH = (unsigned short*)sm.s.afh;
      unsigned short* AFL = (unsigned short*)sm.s.afl;
#pragma unroll
      for (int h2 = 0; h2 < 2; ++h2){
        int idx = h2*NT + tid;
        int r = idx >> 7, j = idx & 127;
        float iv = sigf (sm.s.g[r][j]);
        float fv = sigf (sm.s.g[r][j + 128]);
        float gv = tanhx(sm.s.g[r][j + 256]);
        float ov = sigf (sm.s.g[r][j + 384]);
        float cn = fv * sm.s.lc[r][j] + iv * gv;
        float hn = ov * tanhx(cn);
        sm.s.lc[r][j] = cn; sm.s.lh[r][j] = hn;
        int kt = j >> 5, lane = (((j & 31) >> 3) << 4) | r, jj = j & 7;
        unsigned short h_ = bf16rne(hn);
        AFH[(kt*64 + lane)*8 + jj] = h_;
        AFL[(kt*64 + lane)*8 + jj] = bf16rne(hn - bfval(h_));
      }
    }
    __syncthreads();

    {
      const int r = w, lx = l;
      float p = sm.s.lh[r][lx]*sm.s.fcv[lx] + sm.s.lh[r][lx+64]*sm.s.fcv[lx+64];
      p = wsum64(p);
      if (lx == 0) sm.s.yp[r] = p + fcb[0];
    }
    if (dop){
      int r = tid >> 5, d0 = (tid & 31)*4;
      unsigned short* AFH = (unsigned short*)sm.s.afh;
      unsigned short* AFL = (unsigned short*)sm.s.afl;
      int kt = 4 + (d0 >> 5), lane = (((d0 & 31) >> 3) << 4) | r, jj0 = d0 & 7;
      float vv[4] = {pf.x, pf.y, pf.z, pf.w};
#pragma unroll
      for (int p = 0; p < 4; ++p){
        unsigned short h_ = bf16rne(vv[p]);
        AFH[(kt*64 + lane)*8 + jj0 + p] = h_;
        AFL[(kt*64 + lane)*8 + jj0 + p] = bf16rne(vv[p] - bfval(h_));
      }
    }
    __syncthreads();
  }

  if (tid < M) out[b0 + tid] = sm.s.yp[tid];
}

// ================= Fallback (round-3 VALU kernels, if ws tiny) ===============
struct FSM1 {
  float x[M][DD]; float h[M][HH]; float c[M][HH];
  float a[M][DD]; float xw[M][DD]; float g[M][NG];
};
struct FP1 { FSM1 s; float red[8][512]; };
union __align__(16) FSMA { FP1 p1; P2S p2; float pad[21504]; };

__global__ __launch_bounds__(NT, 2) void fb_ph12_kernel(
    const float* __restrict__ X,
    const float* __restrict__ saW,  const float* __restrict__ saU,  const float* __restrict__ sab,
    const float* __restrict__ saWa, const float* __restrict__ saUa, const float* __restrict__ saba,
    const float* __restrict__ saVa,
    const float* __restrict__ taWa, const float* __restrict__ taba, const float* __restrict__ taVa,
    float* __restrict__ out, float* __restrict__ Hws)
{
  __shared__ FSMA sm;
  const int tid = threadIdx.x;
  const int b0  = blockIdx.x * M;
  const int w   = tid >> 6, l = tid & 63;

  for (int idx = tid; idx < M*HH; idx += NT){
    int r = idx >> 7, j = idx & 127;
    sm.p1.s.h[r][j] = 0.f; sm.p1.s.c[r][j] = 0.f;
  }
  { int r = tid >> 6, d = tid & 63;
    sm.p1.s.x[r][d] = X[(size_t)(b0+r)*SS*DD + d]; }
  __syncthreads();

  for (int t = 0; t < SS; ++t){
    {
      float pr[M];
#pragma unroll
      for (int r = 0; r < M; ++r) pr[r] = 0.f;
      { const int kb = w*8;
#pragma unroll
        for (int q = 0; q < 2; ++q){
          const int k = kb + q*4;
          const float* wp = saWa + (size_t)k*DD + l;
          float w0 = wp[0], w1 = wp[DD], w2 = wp[2*DD], w3 = wp[3*DD];
#pragma unroll
          for (int r = 0; r < M; ++r){
            float4 v = *(const float4*)&sm.p1.s.x[r][k];
            pr[r] += w0*v.x + w1*v.y + w2*v.z + w3*v.w;
          }
        }
      }
      { const int kb = w*16;
#pragma unroll
        for (int q = 0; q < 4; ++q){
          const int k = kb + q*4;
          const float* wp = saUa + (size_t)k*DD + l;
          float w0 = wp[0], w1 = wp[DD], w2 = wp[2*DD], w3 = wp[3*DD];
#pragma unroll
          for (int r = 0; r < M; ++r){
            float4 v = *(const float4*)&sm.p1.s.h[r][k];
            pr[r] += w0*v.x + w1*v.y + w2*v.z + w3*v.w;
          }
        }
      }
      { const int kb = w*16;
#pragma unroll
        for (int q = 0; q < 4; ++q){
          const int k = kb + q*4;
          const float* wp = saUa + (size_t)(HH + k)*DD + l;
          float w0 = wp[0], w1 = wp[DD], w2 = wp[2*DD], w3 = wp[3*DD];
#pragma unroll
          for (int r = 0; r < M; ++r){
            float4 v = *(const float4*)&sm.p1.s.c[r][k];
            pr[r] += w0*v.x + w1*v.y + w2*v.z + w3*v.w;
          }
        }
      }
#pragma unroll
      for (int r = 0; r < M; ++r) sm.p1.red[w][r*64 + l] = pr[r];
    }
    __syncthreads();
    {
      float s = saba[l];
#pragma unroll
      for (int u = 0; u < 8; ++u) s += sm.p1.red[u][w*64 + l];
      sm.p1.s.a[w][l] = tanhx(s);
    }
    __syncthreads();
    {
      float pr[M];
#pragma unroll
      for (int r = 0; r < M; ++r) pr[r] = 0.f;
      const int kb = w*8;
#pragma unroll
      for (int q = 0; q < 2; ++q){
        const int k = kb + q*4;
        const float* wp = saVa + (size_t)k*DD + l;
        float w0 = wp[0], w1 = wp[DD], w2 = wp[2*DD], w3 = wp[3*DD];
#pragma unroll
        for (int r = 0; r < M; ++r){
          float4 v = *(const float4*)&sm.p1.s.a[r][k];
          pr[r] += w0*v.x + w1*v.y + w2*v.z + w3*v.w;
        }
      }
#pragma unroll
      for (int r = 0; r < M; ++r) sm.p1.red[w][r*64 + l] = pr[r];
    }
    __syncthreads();
    {
      float s = 0.f;
#pragma unroll
      for (int u = 0; u < 8; ++u) s += sm.p1.red[u][w*64 + l];
      float mm = wmax64(s);
      float e  = __expf(s - mm);
      float al = e * (1.0f / wsum64(e));
      out[A_OFF + (size_t)t*BB*DD + (size_t)(b0+w)*DD + l] = al;
      sm.p1.s.xw[w][l] = al * sm.p1.s.x[w][l];
    }
    __syncthreads();
    {
      const int c0 = tid;
      float acc[M];
      const float bv = sab[c0];
#pragma unroll
      for (int r = 0; r < M; ++r) acc[r] = bv;
      for (int k = 0; k < DD; k += 4){
        const float* wp = saW + (size_t)k*NG + c0;
        float w0 = wp[0], w1 = wp[NG], w2 = wp[2*NG], w3 = wp[3*NG];
#pragma unroll
        for (int r = 0; r < M; ++r){
          float4 v = *(const float4*)&sm.p1.s.xw[r][k];
          acc[r] += w0*v.x + w1*v.y + w2*v.z + w3*v.w;
        }
      }
      for (int k = 0; k < HH; k += 4){
        const float* wp = saU + (size_t)k*NG + c0;
        float w0 = wp[0], w1 = wp[NG], w2 = wp[2*NG], w3 = wp[3*NG];
#pragma unroll
        for (int r = 0; r < M; ++r){
          float4 v = *(const float4*)&sm.p1.s.h[r][k];
          acc[r] += w0*v.x + w1*v.y + w2*v.z + w3*v.w;
        }
      }
#pragma unroll
      for (int r = 0; r < M; ++r) sm.p1.s.g[r][c0] = acc[r];
    }
    __syncthreads();
    for (int idx = tid; idx < M*HH; idx += NT){
      int r = idx >> 7, j = idx & 127;
      float iv = sigf (sm.p1.s.g[r][j]);
      float fv = sigf (sm.p1.s.g[r][j +   HH]);
      float gv = tanhx(sm.p1.s.g[r][j + 2*HH]);
      float ov = sigf (sm.p1.s.g[r][j + 3*HH]);
      float cn = fv * sm.p1.s.c[r][j] + iv * gv;
      float hn = ov * tanhx(cn);
      sm.p1.s.c[r][j] = cn; sm.p1.s.h[r][j] = hn;
      Hws[(size_t)(b0+r)*SS*HH + (size_t)t*HH + j] = hn;
    }
    if (t + 1 < SS){
      int r = tid >> 6, d = tid & 63;
      sm.p1.s.x[r][d] = X[(size_t)(b0+r)*SS*DD + (size_t)(t+1)*DD + d];
    }
    __syncthreads();
  }

  for (int r = 0; r < M; ++r){
    float* Hrow = Hws + (size_t)(b0+r)*SS*HH;
    const int c  = tid & 127;
    const int th = tid >> 7;
    float hacc[32];
#pragma unroll
    for (int i = 0; i < 32; ++i) hacc[i] = 0.f;
#pragma unroll
    for (int ch = 0; ch < 4; ++ch){
      for (int idx = tid; idx < 32*HH/4; idx += NT)
        ((float4*)sm.p2.A)[idx] = ((const float4*)(Hrow + (size_t)ch*32*HH))[idx];
      __syncthreads();
      { float acc[8];
        const float bv = taba[c];
#pragma unroll
        for (int i = 0; i < 8; ++i) acc[i] = bv;
        for (int k = 0; k < HH; k += 4){
          const float* wp = taWa + (size_t)k*SS + c;
          float w0 = wp[0], w1 = wp[SS], w2 = wp[2*SS], w3 = wp[3*SS];
#pragma unroll
          for (int i = 0; i < 8; ++i){
            float4 v = *(const float4*)&sm.p2.A[th*8+i][k];
            acc[i] += w0*v.x + w1*v.y + w2*v.z + w3*v.w;
          }
        }
#pragma unroll
        for (int i = 0; i < 8; ++i) sm.p2.tmp[th*8+i][c] = tanhx(acc[i]);
      }
      __syncthreads();
      { float acc[8];
#pragma unroll
        for (int i = 0; i < 8; ++i) acc[i] = 0.f;
        for (int k = 0; k < SS; k += 4){
          const float* wp = taVa + (size_t)k*SS + c;
          float w0 = wp[0], w1 = wp[SS], w2 = wp[2*SS], w3 = wp[3*SS];
#pragma unroll
          for (int i = 0; i < 8; ++i){
            float4 v = *(const float4*)&sm.p2.tmp[th*8+i][k];
            acc[i] += w0*v.x + w1*v.y + w2*v.z + w3*v.w;
          }
        }
#pragma unroll
        for (int i = 0; i < 8; ++i) sm.p2.bp[th*8+i][c] = acc[i];
      }
      __syncthreads();
      { const int wv = tid >> 6, lane = tid & 63;
#pragma unroll
        for (int it = 0; it < 4; ++it){
          int tl = wv + 8*it;
          float v0 = sm.p2.bp[tl][lane], v1 = sm.p2.bp[tl][lane+64];
          float mm = wmax64(fmaxf(v0, v1));
          float e0 = __expf(v0 - mm), e1 = __expf(v1 - mm);
          float inv = 1.0f / wsum64(e0 + e1);
          e0 *= inv; e1 *= inv;
          size_t bo = BETA_OFF + (size_t)(ch*32+tl)*BB*SS + (size_t)(b0+r)*SS;
          out[bo + lane]      = e0;
          out[bo + lane + 64] = e1;
          sm.p2.bp[tl][lane]      = e0;
          sm.p2.bp[tl][lane + 64] = e1;
        }
      }
      __syncthreads();
      for (int k = 0; k < SS; k += 4){
        const float* hp = Hrow + (size_t)k*HH + c;
        float hv0 = hp[0], hv1 = hp[HH], hv2 = hp[2*HH], hv3 = hp[3*HH];
#pragma unroll
        for (int i = 0; i < 8; ++i){
          float4 bv = *(const float4*)&sm.p2.bp[th*8+i][k];
          hacc[ch*8+i] += bv.x*hv0 + bv.y*hv1 + bv.z*hv2 + bv.w*hv3;
        }
      }
    }
    __syncthreads();
#pragma unroll
    for (int ch = 0; ch < 4; ++ch)
#pragma unroll
      for (int i = 0; i < 8; ++i)
        Hrow[(size_t)(ch*32 + th*8 + i)*HH + c] = hacc[ch*8+i];
    __syncthreads();
  }
}

__global__ __launch_bounds__(NT, 2) void fb_ph3_kernel(
    const float* __restrict__ X, const float* __restrict__ Ha,
    const float* __restrict__ taW, const float* __restrict__ taU,
    const float* __restrict__ tab, const float* __restrict__ taWy,
    const float* __restrict__ fcw, const float* __restrict__ fcb,
    float* __restrict__ out)
{
  __shared__ struct {
    float ha[M][HH]; float lh[M][HH]; float lc[M][HH];
    float g[M][NG];  float yp[M];
  } s;
  const int tid = threadIdx.x;
  const int b0  = blockIdx.x * M;

  for (int idx = tid; idx < M*HH; idx += NT){
    int r = idx >> 7, j = idx & 127;
    s.lh[r][j] = 0.f; s.lc[r][j] = 0.f;
  }
  if (tid < M) s.yp[tid] = X[(size_t)(b0+tid)*SS*DD + (DD-1)];
  if (tid < M*HH/4){
    int r = tid >> 5, q = tid & 31;
    ((float4*)s.ha)[tid] = *(const float4*)(Ha + (size_t)(b0+r)*SS*HH + q*4);
  }
  __syncthreads();

  for (int t = 0; t < SS; ++t){
    {
      const int c0 = tid;
      const float wy = taWy[c0];
      const float tb = tab[c0];
      float acc[M];
#pragma unroll
      for (int r = 0; r < M; ++r) acc[r] = tb + s.yp[r]*wy;
      for (int k = 0; k < HH; k += 4){
        const float* wp = taW + (size_t)k*NG + c0;
        float a0 = wp[0], a1 = wp[NG], a2 = wp[2*NG], a3 = wp[3*NG];
#pragma unroll
        for (int r = 0; r < M; ++r){
          float4 v = *(const float4*)&s.ha[r][k];
          acc[r] += a0*v.x + a1*v.y + a2*v.z + a3*v.w;
        }
      }
      for (int k = 0; k < HH; k += 4){
        const float* wp = taU + (size_t)k*NG + c0;
        float a0 = wp[0], a1 = wp[NG], a2 = wp[2*NG], a3 = wp[3*NG];
#pragma unroll
        for (int r = 0; r < M; ++r){
          float4 v = *(const float4*)&s.lh[r][k];
          acc[r] += a0*v.x + a1*v.y + a2*v.z + a3*v.w;
        }
      }
#pragma unroll
      for (int r = 0; r < M; ++r) s.g[r][c0] = acc[r];
    }
    __syncthreads();
    for (int idx = tid; idx < M*HH; idx += NT){
      int r = idx >> 7, j = idx & 127;
      float iv = sigf (s.g[r][j]);
      float fv = sigf (s.g[r][j +   HH]);
      float gv = tanhx(s.g[r][j + 2*HH]);
      float ov = sigf (s.g[r][j + 3*HH]);
      float cn = fv * s.lc[r][j] + iv * gv;
      float hn = ov * tanhx(cn);
      s.lc[r][j] = cn; s.lh[r][j] = hn;
    }
    if (t + 1 < SS && tid < M*HH/4){
      int r = tid >> 5, q = tid & 31;
      ((float4*)s.ha)[tid] =
        *(const float4*)(Ha + (size_t)(b0+r)*SS*HH + (size_t)(t+1)*HH + q*4);
    }
    __syncthreads();
    {
      const int r = tid >> 6, lx = tid & 63;
      float p = s.lh[r][lx]*fcw[lx] + s.lh[r][lx+64]*fcw[lx+64];
      p = wsum64(p);
      if (lx == 0) s.yp[r] = p + fcb[0];
    }
    __syncthreads();
  }
  if (tid < M) out[b0 + tid] = s.yp[tid];
}

extern "C" void kernel_launch(void* const* d_in, const int* in_sizes, int n_in,
                              void* d_out, int out_size, void* d_ws, size_t ws_size,
                              hipStream_t stream) {
  (void)in_sizes; (void)n_in; (void)out_size;
  const float* X    = (const float*)d_in[0];
  const float* saW  = (const float*)d_in[1];
  const float* saU  = (const float*)d_in[2];
  const float* sab  = (const float*)d_in[3];
  const float* saWa = (const float*)d_in[4];
  const float* saUa = (const float*)d_in[5];
  const float* saba = (const float*)d_in[6];
  const float* saVa = (const float*)d_in[7];
  const float* taWa = (const float*)d_in[8];
  // d_in[9] = ta_Ua: unused by the reference forward pass
  const float* taba = (const float*)d_in[10];
  const float* taVa = (const float*)d_in[11];
  const float* taW  = (const float*)d_in[12];
  const float* taU  = (const float*)d_in[13];
  const float* tab  = (const float*)d_in[14];
  const float* taWy = (const float*)d_in[15];
  const float* fcw  = (const float*)d_in[16];
  const float* fcb  = (const float*)d_in[17];
  float* out = (float*)d_out;

  if (ws_size >= NEED2_BYTES){
    unsigned short* Fr = (unsigned short*)d_ws;
    float* Hws = (float*)((char*)d_ws + FRAG_BYTES);
    hipLaunchKernelGGL(repack_kernel, dim3(512), dim3(256), 0, stream,
                       saW, saU, saWa, saUa, saVa, taU, taW, taWa, taVa, Fr);
    hipLaunchKernelGGL(mf_ph1_kernel, dim3(BB / M), dim3(NT), 0, stream,
                       X, sab, saba, Fr, out, Hws);
    hipLaunchKernelGGL(ph2_kernel, dim3(BB), dim3(NT), 0, stream,
                       taba, Fr, out, Hws);
    if (ws_size >= NEED3_BYTES){
      float* G0 = (float*)((char*)d_ws + FRAG_BYTES + H_BYTES);
      hipLaunchKernelGGL(g0mm_kernel, dim3((BB*SS)/128), dim3(NT), 0, stream,
                         Hws, Fr, tab, G0);
      hipLaunchKernelGGL(mf_ph3h_kernel, dim3(BB / M), dim3(NT), 0, stream,
                         X, Fr, G0, taWy, fcw, fcb, out);
    } else {
      hipLaunchKernelGGL(mf_ph3_kernel, dim3(BB / M), dim3(NT), 0, stream,
                         X, Hws, Fr, tab, taWy, fcw, fcb, out);
    }
  } else {
    float* Hws = (float*)d_ws;
    hipLaunchKernelGGL(fb_ph12_kernel, dim3(BB / M), dim3(NT), 0, stream,
                       X, saW, saU, sab, saWa, saUa, saba, saVa,
                       taWa, taba, taVa, out, Hws);
    hipLaunchKernelGGL(fb_ph3_kernel, dim3(BB / M), dim3(NT), 0, stream,
                       X, Hws, taW, taU, tab, taWy, fcw, fcb, out);
  }
}

// Round 11
// 2876.940 us; speedup vs baseline: 1.0150x; 1.0150x over previous
//
#include <hip/hip_runtime.h>

// STA-LSTM forward: B=2048, S=128, D=64, H1=H2=128, OUT=1
// Round 11: round 10 with ONE fix — G0 stored [b][t][NG] (natural), not [t][b][NG].
//   The transposed layout made g0mm's stores a 4MB-stride scatter (3.1 GB write
//   amplification, 1373 us). Natural layout: contiguous 2KB-row writes; ph3h's
//   per-step reads are 8 x 2KB contiguous segments (still coalesced).
// Kernels: repack -> mf_ph1 -> ph2 -> g0mm -> mf_ph3h   (full tier)
//          repack -> mf_ph1 -> ph2 -> mf_ph3full        (if ws lacks G0 space)
//          fb_* VALU kernels                             (if ws < 130 MB)
// NOTE: NT=512 + launch_bounds(512,2)/waves_per_eu(2,2) is the ONLY config that
// reliably avoids spills (NT=1024 variants collapse to VGPR=64 + scratch).

#define BB 2048
#define SS 128
#define DD 64
#define HH 128
#define NG 512
#define M  8
#define NT 512

#define A_OFF    ((size_t)BB)
#define BETA_OFF ((size_t)BB + (size_t)SS*BB*DD)
#define H_BYTES  ((size_t)BB*SS*HH*4)
#define G0_BYTES ((size_t)BB*SS*NG*4)

// fragment buffer layout in ws (ushort offsets)
// gate B: K=192 ([saU(h) kk0-3 | saW(xw) kk4-5]), N=512
// attn B: K=320 ([saUa_h kt0-3 | saUa_c kt4-7 | saWa(x) kt8-9]), N=64
// Va: 64x64.  B3: K=256 ([taU kt0-3 | taW kt4-7]), N=512 (ph3h reads kt0-3,
// g0mm reads kt4-7).  RW/RV: ph2 bf16.
#define B1G_ELEMS (192*512)
#define B1A_ELEMS (320*64)
#define BVA_ELEMS (64*64)
#define B3_ELEMS  (256*512)
#define BW_ELEMS  (128*128)
#define GH_OFF 0
#define GL_OFF (B1G_ELEMS)
#define AH_OFF (2*B1G_ELEMS)
#define AL_OFF (2*B1G_ELEMS + B1A_ELEMS)
#define VH_OFF (2*B1G_ELEMS + 2*B1A_ELEMS)
#define VL_OFF (VH_OFF + BVA_ELEMS)
#define B3H_OFF (VH_OFF + 2*BVA_ELEMS)
#define B3L_OFF (B3H_OFF + B3_ELEMS)
#define RW_OFF  (B3H_OFF + 2*B3_ELEMS)
#define RV_OFF  (RW_OFF + BW_ELEMS)
#define FRAG_BYTES ((size_t)(RV_OFF + BW_ELEMS)*2)
#define NEED2_BYTES (FRAG_BYTES + H_BYTES)
#define NEED3_BYTES (FRAG_BYTES + H_BYTES + G0_BYTES)

typedef float f32x4 __attribute__((ext_vector_type(4)));
typedef __bf16 bf16x8 __attribute__((ext_vector_type(8)));
union FB { uint4 u; bf16x8 v; };
__device__ __forceinline__ bf16x8 as_bf(uint4 u){ FB x; x.u = u; return x.v; }

__device__ __forceinline__ unsigned short bf16rne(float f){
  unsigned u = __float_as_uint(f);
  u = (u + 0x7FFFu + ((u >> 16) & 1u)) >> 16;
  return (unsigned short)u;
}
__device__ __forceinline__ float bfval(unsigned short h){
  return __uint_as_float(((unsigned)h) << 16);
}

__device__ __forceinline__ float sigf(float x){ return 1.0f/(1.0f + __expf(-x)); }
__device__ __forceinline__ float tanhx(float x){ return 1.0f - 2.0f/(1.0f + __expf(2.0f*x)); }

__device__ __forceinline__ float wmax64(float v){
#pragma unroll
  for (int m = 32; m; m >>= 1) v = fmaxf(v, __shfl_xor(v, m, 64));
  return v;
}
__device__ __forceinline__ float wsum64(float v){
#pragma unroll
  for (int m = 32; m; m >>= 1) v += __shfl_xor(v, m, 64);
  return v;
}

// ================= repack: weights -> fragment-ordered buffers =================
__global__ __launch_bounds__(256) void repack_kernel(
    const float* __restrict__ saW, const float* __restrict__ saU,
    const float* __restrict__ saWa, const float* __restrict__ saUa,
    const float* __restrict__ saVa,
    const float* __restrict__ taU, const float* __restrict__ taW,
    const float* __restrict__ taWa, const float* __restrict__ taVa,
    unsigned short* __restrict__ F)
{
  int id = blockIdx.x*256 + threadIdx.x;
  if (id < B1G_ELEMS){          // gate: k 0-127 = saU(h), 128-191 = saW(xw)
    int k = id >> 9, n = id & 511;
    float v = (k < 128) ? saU[(size_t)k*NG + n] : saW[(size_t)(k-128)*NG + n];
    int kk = k >> 5, kw = k & 31, nt = n >> 4, nc = n & 15;
    int lane = ((kw >> 3) << 4) | nc, j = kw & 7;
    size_t off = ((size_t)(nt*6 + kk)*64 + lane)*8 + j;
    unsigned short hi = bf16rne(v);
    F[GH_OFF + off] = hi; F[GL_OFF + off] = bf16rne(v - bfval(hi));
  }
  if (id < B1A_ELEMS){          // attn: k 0-255 = saUa(h,c), 256-319 = saWa(x)
    int k = id >> 6, n = id & 63;
    float v = (k < 256) ? saUa[(size_t)k*DD + n] : saWa[(size_t)(k-256)*DD + n];
    int kt = k >> 5, kw = k & 31, nt = n >> 4, nc = n & 15;
    int lane = ((kw >> 3) << 4) | nc, j = kw & 7;
    size_t off = ((size_t)(nt*10 + kt)*64 + lane)*8 + j;
    unsigned short hi = bf16rne(v);
    F[AH_OFF + off] = hi; F[AL_OFF + off] = bf16rne(v - bfval(hi));
  }
  if (id < BVA_ELEMS){          // saVa 64x64
    int k = id >> 6, n = id & 63;
    float v = saVa[(size_t)k*DD + n];
    int kt = k >> 5, kw = k & 31, nt = n >> 4, nc = n & 15;
    int lane = ((kw >> 3) << 4) | nc, j = kw & 7;
    size_t off = ((size_t)(nt*2 + kt)*64 + lane)*8 + j;
    unsigned short hi = bf16rne(v);
    F[VH_OFF + off] = hi; F[VL_OFF + off] = bf16rne(v - bfval(hi));
  }
  if (id < B3_ELEMS){           // ph3: k 0-127 = taU(lh), 128-255 = taW(ha)
    int k = id >> 9, n = id & 511;
    float v = (k < HH) ? taU[(size_t)k*NG + n] : taW[(size_t)(k-HH)*NG + n];
    int kt = k >> 5, kw = k & 31, nt = n >> 4, nc = n & 15;
    int lane = ((kw >> 3) << 4) | nc, j = kw & 7;
    size_t off = ((size_t)(nt*8 + kt)*64 + lane)*8 + j;
    unsigned short hi = bf16rne(v);
    F[B3H_OFF + off] = hi; F[B3L_OFF + off] = bf16rne(v - bfval(hi));
  }
  if (id < BW_ELEMS){           // ph2 bf16 frags
    int k = id >> 7, n = id & 127;
    int kt = k >> 5, kw = k & 31, nt = n >> 4, nc = n & 15;
    int lane = ((kw >> 3) << 4) | nc, j = kw & 7;
    size_t off = ((size_t)(nt*4 + kt)*64 + lane)*8 + j;
    F[RW_OFF + off] = bf16rne(taWa[(size_t)k*SS + n]);
    F[RV_OFF + off] = bf16rne(taVa[(size_t)k*SS + n]);
  }
}

// ================= mf_ph1: spatial-attn LSTM, fully MFMA =================
// af tiles: 0-3 h, 4-7 c, 8-9 x (attn A, K=320); {0-3 h, 10-11 xw} = gate A.
// Gate-h MFMA (kk0-3) runs in P1 (accg in regs); P5 finishes kk4-5 (xw part).
struct P1 {
  uint4 afh[12*64];    // 12K
  uint4 afl[12*64];    // 12K
  uint4 aah[2*64];     // 2K
  uint4 aal[2*64];     // 2K
  float xx[M][DD];     // 2K
  float cc[M][HH];     // 4K
  float red[2][M][64]; // 4K
  float g[M][NG];      // 16K
  float sbias[NG];     // 2K
};
struct P2S { float A[32][HH]; float tmp[32][SS]; float bp[32][SS]; };  // fallback
union __align__(16) SMA { P1 p1; float pad[21504]; };   // 84K -> 1 blk/CU

__global__ __launch_bounds__(NT, 2) __attribute__((amdgpu_waves_per_eu(2, 2)))
void mf_ph1_kernel(
    const float* __restrict__ X,   const float* __restrict__ sab,
    const float* __restrict__ saba,
    const unsigned short* __restrict__ Fr,
    float* __restrict__ out, float* __restrict__ Hws)
{
  __shared__ SMA sm;
  const int tid = threadIdx.x;
  const int b0  = blockIdx.x * M;
  const int w   = tid >> 6, l = tid & 63;

  {
    uint4 z4 = make_uint4(0,0,0,0);
    for (int i = tid; i < 12*64; i += NT){ sm.p1.afh[i] = z4; sm.p1.afl[i] = z4; }
    if (tid < 2*64){ sm.p1.aah[tid] = z4; sm.p1.aal[tid] = z4; }
    for (int i = tid; i < M*HH; i += NT) ((float*)sm.p1.cc)[i] = 0.f;
    sm.p1.sbias[tid] = sab[tid];
  }
  __syncthreads();
  if (tid < 128){   // x(0) + x-frags (tiles 8-9)
    int r = tid >> 4, d0 = (tid & 15)*4;
    float4 v = *(const float4*)(X + (size_t)(b0+r)*SS*DD + d0);
    *(float4*)&sm.p1.xx[r][d0] = v;
    unsigned short* AFH = (unsigned short*)sm.p1.afh;
    unsigned short* AFL = (unsigned short*)sm.p1.afl;
    int kt = 8 + (d0 >> 5), lane = (((d0 & 31) >> 3) << 4) | r, jj0 = d0 & 7;
    float vv[4] = {v.x, v.y, v.z, v.w};
#pragma unroll
    for (int p = 0; p < 4; ++p){
      unsigned short h_ = bf16rne(vv[p]);
      AFH[(kt*64 + lane)*8 + jj0 + p] = h_;
      AFL[(kt*64 + lane)*8 + jj0 + p] = bf16rne(vv[p] - bfval(h_));
    }
  }
  __syncthreads();

  for (int t = 0; t < SS; ++t){
    // ---- P1: attn MFMA -> red  +  gate-h partial MFMA (kk0-3) -> accg regs ----
    f32x4 accg[4];
    {
      f32x4 zf = {0.f,0.f,0.f,0.f};
#pragma unroll
      for (int n4 = 0; n4 < 4; ++n4) accg[n4] = zf;
    }
    {
      const int nt = w & 3, kh = w >> 2;
      f32x4 a0 = {0.f,0.f,0.f,0.f}, a1 = {0.f,0.f,0.f,0.f};
      const uint4* BAH = (const uint4*)(Fr + AH_OFF);
      const uint4* BAL = (const uint4*)(Fr + AL_OFF);
#pragma unroll
      for (int q = 0; q < 5; ++q){
        const int kt = kh*5 + q;
        bf16x8 ah = as_bf(sm.p1.afh[kt*64 + l]);
        bf16x8 av = as_bf(sm.p1.afl[kt*64 + l]);
        bf16x8 bh = as_bf(BAH[(nt*10 + kt)*64 + l]);
        bf16x8 bl = as_bf(BAL[(nt*10 + kt)*64 + l]);
        if (q & 1){
          a1 = __builtin_amdgcn_mfma_f32_16x16x32_bf16(ah, bh, a1, 0, 0, 0);
          a1 = __builtin_amdgcn_mfma_f32_16x16x32_bf16(av, bh, a1, 0, 0, 0);
          a1 = __builtin_amdgcn_mfma_f32_16x16x32_bf16(ah, bl, a1, 0, 0, 0);
        } else {
          a0 = __builtin_amdgcn_mfma_f32_16x16x32_bf16(ah, bh, a0, 0, 0, 0);
          a0 = __builtin_amdgcn_mfma_f32_16x16x32_bf16(av, bh, a0, 0, 0, 0);
          a0 = __builtin_amdgcn_mfma_f32_16x16x32_bf16(ah, bl, a0, 0, 0, 0);
        }
      }
      f32x4 acc = a0 + a1;
      const int row0 = (l >> 4)*4, c0 = l & 15;
      if (row0 < 8){
#pragma unroll
        for (int jj = 0; jj < 4; ++jj)
          sm.p1.red[kh][row0+jj][nt*16 + c0] = acc[jj];
      }
      // gate-h part (no LDS writes; results stay in accg)
      const uint4* GH = (const uint4*)(Fr + GH_OFF);
      const uint4* GL = (const uint4*)(Fr + GL_OFF);
#pragma unroll
      for (int kk = 0; kk < 4; ++kk){
        bf16x8 ah = as_bf(sm.p1.afh[kk*64 + l]);
        bf16x8 av = as_bf(sm.p1.afl[kk*64 + l]);
#pragma unroll
        for (int n4 = 0; n4 < 4; ++n4){
          const int ntg = w*4 + n4;
          bf16x8 bh = as_bf(GH[(ntg*6 + kk)*64 + l]);
          bf16x8 bl = as_bf(GL[(ntg*6 + kk)*64 + l]);
          accg[n4] = __builtin_amdgcn_mfma_f32_16x16x32_bf16(ah, bh, accg[n4], 0, 0, 0);
          accg[n4] = __builtin_amdgcn_mfma_f32_16x16x32_bf16(av, bh, accg[n4], 0, 0, 0);
          accg[n4] = __builtin_amdgcn_mfma_f32_16x16x32_bf16(ah, bl, accg[n4], 0, 0, 0);
        }
      }
    }
    __syncthreads();

    // ---- P2: combine + bias + tanh -> a-frags ----
    {
      const int r = w, col = l;
      float s = sm.p1.red[0][r][col] + sm.p1.red[1][r][col] + saba[col];
      float av = tanhx(s);
      unsigned short h_ = bf16rne(av);
      int kt = col >> 5, lane = (((col & 31) >> 3) << 4) | r, jj = col & 7;
      ((unsigned short*)sm.p1.aah)[(kt*64 + lane)*8 + jj] = h_;
      ((unsigned short*)sm.p1.aal)[(kt*64 + lane)*8 + jj] = bf16rne(av - bfval(h_));
    }
    __syncthreads();

    // ---- P3: GEMM2 MFMA  av = a @ saVa ----
    {
      const int nt = w & 3, kt = w >> 2;   // kt 0-1
      f32x4 acc = {0.f,0.f,0.f,0.f};
      bf16x8 ah = as_bf(sm.p1.aah[kt*64 + l]);
      bf16x8 av = as_bf(sm.p1.aal[kt*64 + l]);
      bf16x8 bh = as_bf(((const uint4*)(Fr + VH_OFF))[(nt*2 + kt)*64 + l]);
      bf16x8 bl = as_bf(((const uint4*)(Fr + VL_OFF))[(nt*2 + kt)*64 + l]);
      acc = __builtin_amdgcn_mfma_f32_16x16x32_bf16(ah, bh, acc, 0, 0, 0);
      acc = __builtin_amdgcn_mfma_f32_16x16x32_bf16(av, bh, acc, 0, 0, 0);
      acc = __builtin_amdgcn_mfma_f32_16x16x32_bf16(ah, bl, acc, 0, 0, 0);
      const int row0 = (l >> 4)*4, c0 = l & 15;
      if (row0 < 8){
#pragma unroll
        for (int jj = 0; jj < 4; ++jj)
          sm.p1.red[kt][row0+jj][nt*16 + c0] = acc[jj];
      }
    }
    __syncthreads();

    // ---- P4: softmax + alphas out + xw-frags (tiles 10-11) ----
    {
      const int r = w, col = l;
      float s = sm.p1.red[0][r][col] + sm.p1.red[1][r][col];
      float mm = wmax64(s);
      float e  = __expf(s - mm);
      float alv = e * (1.0f / wsum64(e));
      out[A_OFF + (size_t)t*BB*DD + (size_t)(b0+r)*DD + col] = alv;
      float xwv = alv * sm.p1.xx[r][col];
      unsigned short h_ = bf16rne(xwv);
      int kt = 10 + (col >> 5), lane = (((col & 31) >> 3) << 4) | r, jj = col & 7;
      ((unsigned short*)sm.p1.afh)[(kt*64 + lane)*8 + jj] = h_;
      ((unsigned short*)sm.p1.afl)[(kt*64 + lane)*8 + jj] = bf16rne(xwv - bfval(h_));
    }
    __syncthreads();

    // ---- P5: gates xw-part (kk4-5) + x(t+1) prefetch issue ----
    float4 pf;
    const bool dox = (tid < 128) && (t + 1 < SS);
    if (dox){
      int r = tid >> 4, d0 = (tid & 15)*4;
      pf = *(const float4*)(X + (size_t)(b0+r)*SS*DD + (size_t)(t+1)*DD + d0);
    }
    {
      const uint4* GH = (const uint4*)(Fr + GH_OFF);
      const uint4* GL = (const uint4*)(Fr + GL_OFF);
#pragma unroll
      for (int kk = 4; kk < 6; ++kk){
        const int afi = kk + 6;   // 10, 11
        bf16x8 ah = as_bf(sm.p1.afh[afi*64 + l]);
        bf16x8 av = as_bf(sm.p1.afl[afi*64 + l]);
#pragma unroll
        for (int n4 = 0; n4 < 4; ++n4){
          const int ntg = w*4 + n4;
          bf16x8 bh = as_bf(GH[(ntg*6 + kk)*64 + l]);
          bf16x8 bl = as_bf(GL[(ntg*6 + kk)*64 + l]);
          accg[n4] = __builtin_amdgcn_mfma_f32_16x16x32_bf16(ah, bh, accg[n4], 0, 0, 0);
          accg[n4] = __builtin_amdgcn_mfma_f32_16x16x32_bf16(av, bh, accg[n4], 0, 0, 0);
          accg[n4] = __builtin_amdgcn_mfma_f32_16x16x32_bf16(ah, bl, accg[n4], 0, 0, 0);
        }
      }
      const int row0 = (l >> 4)*4, c0 = l & 15;
      if (row0 < 8){
#pragma unroll
        for (int n4 = 0; n4 < 4; ++n4){
          int col = w*64 + n4*16 + c0;
          float b = sm.p1.sbias[col];
#pragma unroll
          for (int jj = 0; jj < 4; ++jj)
            sm.p1.g[row0+jj][col] = accg[n4][jj] + b;
        }
      }
    }
    __syncthreads();

    // ---- P6: pointwise + h/c frag build + H store + x(t+1) commit ----
    {
      unsigned short* AFH = (unsigned short*)sm.p1.afh;
      unsigned short* AFL = (unsigned short*)sm.p1.afl;
#pragma unroll
      for (int h2 = 0; h2 < 2; ++h2){
        int idx = h2*NT + tid;
        int r = idx >> 7, j = idx & 127;
        float iv = sigf (sm.p1.g[r][j]);
        float fv = sigf (sm.p1.g[r][j + 128]);
        float gv = tanhx(sm.p1.g[r][j + 256]);
        float ov = sigf (sm.p1.g[r][j + 384]);
        float cn = fv * sm.p1.cc[r][j] + iv * gv;
        float hn = ov * tanhx(cn);
        sm.p1.cc[r][j] = cn;
        Hws[(size_t)(b0+r)*SS*HH + (size_t)t*HH + j] = hn;
        int lane = (((j & 31) >> 3) << 4) | r, jj = j & 7;
        int ktH = j >> 5, ktC = 4 + (j >> 5);
        unsigned short hh_ = bf16rne(hn);
        unsigned short ch_ = bf16rne(cn);
        AFH[(ktH*64 + lane)*8 + jj] = hh_;
        AFL[(ktH*64 + lane)*8 + jj] = bf16rne(hn - bfval(hh_));
        AFH[(ktC*64 + lane)*8 + jj] = ch_;
        AFL[(ktC*64 + lane)*8 + jj] = bf16rne(cn - bfval(ch_));
      }
      if (dox){
        int r = tid >> 4, d0 = (tid & 15)*4;
        *(float4*)&sm.p1.xx[r][d0] = pf;
        int kt = 8 + (d0 >> 5), lane = (((d0 & 31) >> 3) << 4) | r, jj0 = d0 & 7;
        float vv[4] = {pf.x, pf.y, pf.z, pf.w};
#pragma unroll
        for (int p = 0; p < 4; ++p){
          unsigned short h_ = bf16rne(vv[p]);
          AFH[(kt*64 + lane)*8 + jj0 + p] = h_;
          AFL[(kt*64 + lane)*8 + jj0 + p] = bf16rne(vv[p] - bfval(h_));
        }
      }
    }
    __syncthreads();
  }
}

// ================= ph2_kernel: betas + h_att, all-MFMA (round 8) ===========
struct PH2SM {
  uint4 fA[8][4][64];          // 32 KB
  uint4 fB[8][4][64];          // 32 KB
  unsigned short S[128][136];  // 34 KB (pad 8)
  float bias[SS];
};

__global__ __launch_bounds__(NT, 2) void ph2_kernel(
    const float* __restrict__ taba, const unsigned short* __restrict__ Fr,
    float* __restrict__ out, float* __restrict__ Hws)
{
  __shared__ PH2SM sm;
  const int tid = threadIdx.x;
  const int b   = blockIdx.x;
  const int w   = tid >> 6, l = tid & 63;
  const int g   = l >> 4, c0 = l & 15;
  float* Hb = Hws + (size_t)b * SS * HH;

  if (tid < SS) sm.bias[tid] = taba[tid];
  {
    const float4* src = (const float4*)Hb;
#pragma unroll
    for (int i = 0; i < 8; ++i){
      int fidx = i*NT + tid;
      float4 v = src[fidx];
      int e0 = fidx*4, row = e0 >> 7, col = e0 & 127;
      sm.S[row][col+0] = bf16rne(v.x);
      sm.S[row][col+1] = bf16rne(v.y);
      sm.S[row][col+2] = bf16rne(v.z);
      sm.S[row][col+3] = bf16rne(v.w);
    }
  }
  __syncthreads();

#pragma unroll
  for (int i = 0; i < 4; ++i){
    int slot = i*NT + tid;
    int mt = slot >> 8, kt = (slot >> 6) & 3, ll = slot & 63;
    int row = mt*16 + (ll & 15), k0 = kt*32 + (ll >> 4)*8;
    ((uint4*)sm.fA)[slot] = *(const uint4*)&sm.S[row][k0];
  }
#pragma unroll
  for (int i = 0; i < 4; ++i){
    int slot = i*NT + tid;
    int nt = slot >> 8, kt = (slot >> 6) & 3, ll = slot & 63;
    int col = nt*16 + (ll & 15), s0 = kt*32 + (ll >> 4)*8;
    unsigned u[4];
#pragma unroll
    for (int p = 0; p < 4; ++p)
      u[p] = (unsigned)sm.S[s0+2*p][col] | ((unsigned)sm.S[s0+2*p+1][col] << 16);
    ((uint4*)sm.fB)[slot] = make_uint4(u[0], u[1], u[2], u[3]);
  }
  __syncthreads();

  f32x4 acc[8];
  f32x4 zero4 = {0.f, 0.f, 0.f, 0.f};

#pragma unroll
  for (int nt = 0; nt < 8; ++nt) acc[nt] = zero4;
  {
    const uint4* BW = (const uint4*)(Fr + RW_OFF);
#pragma unroll
    for (int kt = 0; kt < 4; ++kt){
      bf16x8 a = as_bf(sm.fA[w][kt][l]);
#pragma unroll
      for (int nt = 0; nt < 8; ++nt){
        bf16x8 bv = as_bf(BW[(nt*4 + kt)*64 + l]);
        acc[nt] = __builtin_amdgcn_mfma_f32_16x16x32_bf16(a, bv, acc[nt], 0, 0, 0);
      }
    }
  }
#pragma unroll
  for (int nt = 0; nt < 8; ++nt){
    int col = nt*16 + c0;
    float bv = sm.bias[col];
#pragma unroll
    for (int j = 0; j < 4; ++j)
      sm.S[w*16 + g*4 + j][col] = bf16rne(tanhx(acc[nt][j] + bv));
  }
  __syncthreads();

#pragma unroll
  for (int i = 0; i < 4; ++i){
    int slot = i*NT + tid;
    int mt = slot >> 8, kt = (slot >> 6) & 3, ll = slot & 63;
    int row = mt*16 + (ll & 15), k0 = kt*32 + (ll >> 4)*8;
    ((uint4*)sm.fA)[slot] = *(const uint4*)&sm.S[row][k0];
  }
  __syncthreads();

#pragma unroll
  for (int nt = 0; nt < 8; ++nt) acc[nt] = zero4;
  {
    const uint4* BV = (const uint4*)(Fr + RV_OFF);
#pragma unroll
    for (int kt = 0; kt < 4; ++kt){
      bf16x8 a = as_bf(sm.fA[w][kt][l]);
#pragma unroll
      for (int nt = 0; nt < 8; ++nt){
        bf16x8 bv = as_bf(BV[(nt*4 + kt)*64 + l]);
        acc[nt] = __builtin_amdgcn_mfma_f32_16x16x32_bf16(a, bv, acc[nt], 0, 0, 0);
      }
    }
  }

#pragma unroll
  for (int j = 0; j < 4; ++j){
    float m = acc[0][j];
#pragma unroll
    for (int nt = 1; nt < 8; ++nt) m = fmaxf(m, acc[nt][j]);
#pragma unroll
    for (int ms = 1; ms < 16; ms <<= 1) m = fmaxf(m, __shfl_xor(m, ms, 64));
    float e[8], s = 0.f;
#pragma unroll
    for (int nt = 0; nt < 8; ++nt){ e[nt] = __expf(acc[nt][j] - m); s += e[nt]; }
#pragma unroll
    for (int ms = 1; ms < 16; ms <<= 1) s += __shfl_xor(s, ms, 64);
    float inv = 1.0f / s;
    int row = w*16 + g*4 + j;
    size_t bo = BETA_OFF + (size_t)row*BB*SS + (size_t)b*SS;
#pragma unroll
    for (int nt = 0; nt < 8; ++nt){
      float bv = e[nt] * inv;
      out[bo + nt*16 + c0] = bv;
      sm.S[row][nt*16 + c0] = bf16rne(bv);
    }
  }
  __syncthreads();

#pragma unroll
  for (int i = 0; i < 4; ++i){
    int slot = i*NT + tid;
    int mt = slot >> 8, kt = (slot >> 6) & 3, ll = slot & 63;
    int row = mt*16 + (ll & 15), k0 = kt*32 + (ll >> 4)*8;
    ((uint4*)sm.fA)[slot] = *(const uint4*)&sm.S[row][k0];
  }
  __syncthreads();

#pragma unroll
  for (int nt = 0; nt < 8; ++nt) acc[nt] = zero4;
#pragma unroll
  for (int kt = 0; kt < 4; ++kt){
    bf16x8 a = as_bf(sm.fA[w][kt][l]);
#pragma unroll
    for (int nt = 0; nt < 8; ++nt){
      bf16x8 bv = as_bf(sm.fB[nt][kt][l]);
      acc[nt] = __builtin_amdgcn_mfma_f32_16x16x32_bf16(a, bv, acc[nt], 0, 0, 0);
    }
  }
#pragma unroll
  for (int nt = 0; nt < 8; ++nt){
#pragma unroll
    for (int j = 0; j < 4; ++j)
      Hb[(size_t)(w*16 + g*4 + j)*HH + nt*16 + c0] = acc[nt][j];
  }
}

// ================= g0mm: G0[b][t][:] = h_att @ taW + tab (split-bf16) ==========
// 2048 blocks x 512 thr; block handles 128 consecutive flat (b,t) rows of Ha.
// G0 layout is NATURAL [b][t][NG] -> fully coalesced row writes.
struct GMM { uint4 afh[8][4][64]; uint4 afl[8][4][64]; };   // 64 KB

__global__ __launch_bounds__(NT, 2) void g0mm_kernel(
    const float* __restrict__ Ha, const unsigned short* __restrict__ Fr,
    const float* __restrict__ tab, float* __restrict__ G0)
{
  __shared__ GMM sm;
  const int tid = threadIdx.x;
  const size_t r0 = (size_t)blockIdx.x * 128;
  const int w = tid >> 6, l = tid & 63;
  const int row0 = (l >> 4)*4, c0 = l & 15;

  // stage Ha rows -> split-bf16 A-frags (mt 0..7, kt 0..3)
  {
    const float4* src = (const float4*)(Ha + r0*HH);
    unsigned short* AFH = (unsigned short*)sm.afh;
    unsigned short* AFL = (unsigned short*)sm.afl;
#pragma unroll
    for (int i = 0; i < 8; ++i){
      int f = i*NT + tid;            // 4096 float4
      float4 v = src[f];
      int e0 = f*4, rl = e0 >> 7, k0 = e0 & 127;
      int mt = rl >> 4, kt = k0 >> 5;
      int lane = (((k0 & 31) >> 3) << 4) | (rl & 15), j0 = k0 & 7;
      size_t base = ((size_t)(mt*4 + kt)*64 + lane)*8 + j0;
      float vv[4] = {v.x, v.y, v.z, v.w};
#pragma unroll
      for (int p = 0; p < 4; ++p){
        unsigned short h_ = bf16rne(vv[p]);
        AFH[base + p] = h_;
        AFL[base + p] = bf16rne(vv[p] - bfval(h_));
      }
    }
  }
  __syncthreads();

  const uint4* BH = (const uint4*)(Fr + B3H_OFF);
  const uint4* BL = (const uint4*)(Fr + B3L_OFF);
#pragma unroll
  for (int q = 0; q < 4; ++q){
    const int nt = w*4 + q;          // 0..31
    uint4 bh[4], bl[4];
#pragma unroll
    for (int kt = 0; kt < 4; ++kt){  // taW = kt 4-7 of B3 layout
      bh[kt] = BH[(nt*8 + 4 + kt)*64 + l];
      bl[kt] = BL[(nt*8 + 4 + kt)*64 + l];
    }
    const int col = nt*16 + c0;
    const float tb = tab[col];
    f32x4 zero4 = {0.f,0.f,0.f,0.f};
    f32x4 acc[8];
#pragma unroll
    for (int mt = 0; mt < 8; ++mt) acc[mt] = zero4;
#pragma unroll
    for (int mt = 0; mt < 8; ++mt){
#pragma unroll
      for (int kt = 0; kt < 4; ++kt){
        bf16x8 ah = as_bf(sm.afh[mt][kt][l]);
        bf16x8 av = as_bf(sm.afl[mt][kt][l]);
        bf16x8 vbh = as_bf(bh[kt]);
        bf16x8 vbl = as_bf(bl[kt]);
        acc[mt] = __builtin_amdgcn_mfma_f32_16x16x32_bf16(ah, vbh, acc[mt], 0, 0, 0);
        acc[mt] = __builtin_amdgcn_mfma_f32_16x16x32_bf16(av, vbh, acc[mt], 0, 0, 0);
        acc[mt] = __builtin_amdgcn_mfma_f32_16x16x32_bf16(ah, vbl, acc[mt], 0, 0, 0);
      }
    }
#pragma unroll
    for (int mt = 0; mt < 8; ++mt){
#pragma unroll
      for (int j = 0; j < 4; ++j){
        size_t row = r0 + mt*16 + row0 + j;       // flat (b,t), natural layout
        G0[row*NG + col] = acc[mt][j] + tb;
      }
    }
  }
}

// ================= mf_ph3h: temporal LSTM, K=128 (G0-hoisted) =================
// af tiles 0-3: lh only.
struct P3H {
  uint4 afh[4*64];     // 4K
  uint4 afl[4*64];     // 4K
  float lh[M][HH];     // 4K
  float lc[M][HH];     // 4K
  float g[M][NG];      // 16K
  float wy[NG];        // 2K
  float fcv[HH];
  float yp[M];
};
union __align__(16) SMCH { P3H s; float pad[21504]; };   // 84K -> 1 blk/CU

__global__ __launch_bounds__(NT, 2) __attribute__((amdgpu_waves_per_eu(2, 2)))
void mf_ph3h_kernel(
    const float* __restrict__ X, const unsigned short* __restrict__ Fr,
    const float* __restrict__ G0,
    const float* __restrict__ taWy,
    const float* __restrict__ fcw, const float* __restrict__ fcb,
    float* __restrict__ out)
{
  __shared__ SMCH sm;
  const int tid = threadIdx.x;
  const int b0  = blockIdx.x * M;
  const int w   = tid >> 6, l = tid & 63;
  const int row0 = (l >> 4)*4, c0 = l & 15;

  {
    uint4 z4 = make_uint4(0,0,0,0);
    if (tid < 4*64){ sm.s.afh[tid] = z4; sm.s.afl[tid] = z4; }
    for (int i = tid; i < M*HH; i += NT){
      ((float*)sm.s.lh)[i] = 0.f; ((float*)sm.s.lc)[i] = 0.f;
    }
    sm.s.wy[tid] = taWy[tid];
    if (tid < HH) sm.s.fcv[tid] = fcw[tid];
    if (tid < M)  sm.s.yp[tid] = X[(size_t)(b0+tid)*SS*DD + (DD-1)];
  }
  __syncthreads();

  for (int t = 0; t < SS; ++t){
    // ---- Q1: G0 ext prefetch (natural [b][t][NG] layout) + gates MFMA ----
    {
      float g0v[16];
      if (row0 < 8){
#pragma unroll
        for (int n4 = 0; n4 < 4; ++n4){
#pragma unroll
          for (int j = 0; j < 4; ++j)
            g0v[n4*4+j] = G0[((size_t)(b0+row0+j)*SS + t)*NG + (w*64 + n4*16 + c0)];
        }
      }
      f32x4 zero4 = {0.f,0.f,0.f,0.f};
      f32x4 acc[4];
#pragma unroll
      for (int n4 = 0; n4 < 4; ++n4) acc[n4] = zero4;
      const uint4* BH = (const uint4*)(Fr + B3H_OFF);
      const uint4* BL = (const uint4*)(Fr + B3L_OFF);
#pragma unroll
      for (int kt = 0; kt < 4; ++kt){      // taU = kt 0-3
        bf16x8 ah = as_bf(sm.s.afh[kt*64 + l]);
        bf16x8 av = as_bf(sm.s.afl[kt*64 + l]);
#pragma unroll
        for (int n4 = 0; n4 < 4; ++n4){
          const int ntg = w*4 + n4;
          bf16x8 bh = as_bf(BH[(ntg*8 + kt)*64 + l]);
          bf16x8 bl = as_bf(BL[(ntg*8 + kt)*64 + l]);
          acc[n4] = __builtin_amdgcn_mfma_f32_16x16x32_bf16(ah, bh, acc[n4], 0, 0, 0);
          acc[n4] = __builtin_amdgcn_mfma_f32_16x16x32_bf16(av, bh, acc[n4], 0, 0, 0);
          acc[n4] = __builtin_amdgcn_mfma_f32_16x16x32_bf16(ah, bl, acc[n4], 0, 0, 0);
        }
      }
      if (row0 < 8){
#pragma unroll
        for (int n4 = 0; n4 < 4; ++n4){
          int col = w*64 + n4*16 + c0;
          float wv = sm.s.wy[col];
#pragma unroll
          for (int j = 0; j < 4; ++j)
            sm.s.g[row0+j][col] = acc[n4][j] + g0v[n4*4+j] + sm.s.yp[row0+j]*wv;
        }
      }
    }
    __syncthreads();

    // ---- Q2: pointwise + lh-frag build (tiles 0-3) ----
    {
      unsigned short* AFH = (unsigned short*)sm.s.afh;
      unsigned short* AFL = (unsigned short*)sm.s.afl;
#pragma unroll
      for (int h2 = 0; h2 < 2; ++h2){
        int idx = h2*NT + tid;
        int r = idx >> 7, j = idx & 127;
        float iv = sigf (sm.s.g[r][j]);
        float fv = sigf (sm.s.g[r][j + 128]);
        float gv = tanhx(sm.s.g[r][j + 256]);
        float ov = sigf (sm.s.g[r][j + 384]);
        float cn = fv * sm.s.lc[r][j] + iv * gv;
        float hn = ov * tanhx(cn);
        sm.s.lc[r][j] = cn; sm.s.lh[r][j] = hn;
        int kt = j >> 5, lane = (((j & 31) >> 3) << 4) | r, jj = j & 7;
        unsigned short h_ = bf16rne(hn);
        AFH[(kt*64 + lane)*8 + jj] = h_;
        AFL[(kt*64 + lane)*8 + jj] = bf16rne(hn - bfval(h_));
      }
    }
    __syncthreads();

    // ---- Q3: fc reduce ----
    {
      const int r = w, lx = l;
      float p = sm.s.lh[r][lx]*sm.s.fcv[lx] + sm.s.lh[r][lx+64]*sm.s.fcv[lx+64];
      p = wsum64(p);
      if (lx == 0) sm.s.yp[r] = p + fcb[0];
    }
    __syncthreads();
  }

  if (tid < M) out[b0 + tid] = sm.s.yp[tid];
}

// ================= mf_ph3full: round-9 K=256 variant (tier-2 fallback) ==========
struct P3 {
  uint4 afh[8*64];
  uint4 afl[8*64];
  float lh[M][HH];
  float lc[M][HH];
  float g[M][NG];
  float sb[NG];
  float wy[NG];
  float fcv[HH];
  float yp[M];
};
union __align__(16) SMC { P3 s; float pad[21504]; };

__global__ __launch_bounds__(NT, 2) void mf_ph3_kernel(
    const float* __restrict__ X, const float* __restrict__ Ha,
    const unsigned short* __restrict__ Fr,
    const float* __restrict__ tab, const float* __restrict__ taWy,
    const float* __restrict__ fcw, const float* __restrict__ fcb,
    float* __restrict__ out)
{
  __shared__ SMC sm;
  const int tid = threadIdx.x;
  const int b0  = blockIdx.x * M;
  const int w   = tid >> 6, l = tid & 63;

  {
    uint4 z4 = make_uint4(0,0,0,0);
    sm.s.afh[tid] = z4; sm.s.afl[tid] = z4;
    for (int i = tid; i < M*HH; i += NT){
      ((float*)sm.s.lh)[i] = 0.f; ((float*)sm.s.lc)[i] = 0.f;
    }
    sm.s.sb[tid] = tab[tid];
    sm.s.wy[tid] = taWy[tid];
    if (tid < HH) sm.s.fcv[tid] = fcw[tid];
    if (tid < M)  sm.s.yp[tid] = X[(size_t)(b0+tid)*SS*DD + (DD-1)];
  }
  __syncthreads();
  if (tid < 256){
    int r = tid >> 5, d0 = (tid & 31)*4;
    float4 v = *(const float4*)(Ha + (size_t)(b0+r)*SS*HH + d0);
    unsigned short* AFH = (unsigned short*)sm.s.afh;
    unsigned short* AFL = (unsigned short*)sm.s.afl;
    int kt = 4 + (d0 >> 5), lane = (((d0 & 31) >> 3) << 4) | r, jj0 = d0 & 7;
    float vv[4] = {v.x, v.y, v.z, v.w};
#pragma unroll
    for (int p = 0; p < 4; ++p){
      unsigned short h_ = bf16rne(vv[p]);
      AFH[(kt*64 + lane)*8 + jj0 + p] = h_;
      AFL[(kt*64 + lane)*8 + jj0 + p] = bf16rne(vv[p] - bfval(h_));
    }
  }
  __syncthreads();

  for (int t = 0; t < SS; ++t){
    float4 pf;
    const bool dop = (tid < 256) && (t + 1 < SS);
    if (dop){
      int r = tid >> 5, d0 = (tid & 31)*4;
      pf = *(const float4*)(Ha + (size_t)(b0+r)*SS*HH + (size_t)(t+1)*HH + d0);
    }
    {
      f32x4 zero4 = {0.f,0.f,0.f,0.f};
      f32x4 acc[4];
#pragma unroll
      for (int n4 = 0; n4 < 4; ++n4) acc[n4] = zero4;
      const uint4* BH = (const uint4*)(Fr + B3H_OFF);
      const uint4* BL = (const uint4*)(Fr + B3L_OFF);
#pragma unroll
      for (int kt = 0; kt < 8; ++kt){
        bf16x8 ah = as_bf(sm.s.afh[kt*64 + l]);
        bf16x8 av = as_bf(sm.s.afl[kt*64 + l]);
#pragma unroll
        for (int n4 = 0; n4 < 4; ++n4){
          const int ntg = w*4 + n4;
          bf16x8 bh = as_bf(BH[(ntg*8 + kt)*64 + l]);
          bf16x8 bl = as_bf(BL[(ntg*8 + kt)*64 + l]);
          acc[n4] = __builtin_amdgcn_mfma_f32_16x16x32_bf16(ah, bh, acc[n4], 0, 0, 0);
          acc[n4] = __builtin_amdgcn_mfma_f32_16x16x32_bf16(av, bh, acc[n4], 0, 0, 0);
          acc[n4] = __builtin_amdgcn_mfma_f32_16x16x32_bf16(ah, bl, acc[n4], 0, 0, 0);
        }
      }
      const int row0 = (l >> 4)*4;
      if (row0 < 8){
        const int colb = w*64 + (l & 15);
#pragma unroll
        for (int n4 = 0; n4 < 4; ++n4){
          int col = colb + n4*16;
          float b = sm.s.sb[col];
          float wv = sm.s.wy[col];
#pragma unroll
          for (int j = 0; j < 4; ++j)
            sm.s.g[row0+j][col] = acc[n4][j] + b + sm.s.yp[row0+j]*wv;
        }
      }
    }
    __syncthreads();

    {
      unsigned short* AFH = (unsigned short*)sm.s.afh;
      unsigned short* AFL = (unsigned short*)sm.s.afl;
#pragma unroll
      for (int h2 = 0; h2 < 2; ++h2){
        int idx = h2*NT + tid;
        int r = idx >> 7, j = idx & 127;
        float iv = sigf (sm.s.g[r][j]);
        float fv = sigf (sm.s.g[r][j + 128]);
        float gv = tanhx(sm.s.g[r][j + 256]);
        float ov = sigf (sm.s.g[r][j + 384]);
        float cn = fv * sm.s.lc[r][j] + iv * gv;
        float hn = ov * tanhx(cn);
        sm.s.lc[r][j] = cn; sm.s.lh[r][j] = hn;
        int kt = j >> 5, lane = (((j & 31) >> 3) << 4) | r, jj = j & 7;
        unsigned short h_ = bf16rne(hn);
        AFH[(kt*64 + lane)*8 + jj] = h_;
        AFL[(kt*64 + lane)*8 + jj] = bf16rne(hn - bfval(h_));
      }
    }
    __syncthreads();

    {
      const int r = w, lx = l;
      float p = sm.s.lh[r][lx]*sm.s.fcv[lx] + sm.s.lh[r][lx+64]*sm.s.fcv[lx+64];
      p = wsum64(p);
      if (lx == 0) sm.s.yp[r] = p + fcb[0];
    }
    if (dop){
      int r = tid >> 5, d0 = (tid & 31)*4;
      unsigned short* AFH = (unsigned short*)sm.s.afh;
      unsigned short* AFL = (unsigned short*)sm.s.afl;
      int kt = 4 + (d0 >> 5), lane = (((d0 & 31) >> 3) << 4) | r, jj0 = d0 & 7;
      float vv[4] = {pf.x, pf.y, pf.z, pf.w};
#pragma unroll
      for (int p = 0; p < 4; ++p){
        unsigned short h_ = bf16rne(vv[p]);
        AFH[(kt*64 + lane)*8 + jj0 + p] = h_;
        AFL[(kt*64 + lane)*8 + jj0 + p] = bf16rne(vv[p] - bfval(h_));
      }
    }
    __syncthreads();
  }

  if (tid < M) out[b0 + tid] = sm.s.yp[tid];
}

// ================= Fallback (round-3 VALU kernels, if ws tiny) ===============
struct FSM1 {
  float x[M][DD]; float h[M][HH]; float c[M][HH];
  float a[M][DD]; float xw[M][DD]; float g[M][NG];
};
struct FP1 { FSM1 s; float red[8][512]; };
union __align__(16) FSMA { FP1 p1; P2S p2; float pad[21504]; };

__global__ __launch_bounds__(NT, 2) void fb_ph12_kernel(
    const float* __restrict__ X,
    const float* __restrict__ saW,  const float* __restrict__ saU,  const float* __restrict__ sab,
    const float* __restrict__ saWa, const float* __restrict__ saUa, const float* __restrict__ saba,
    const float* __restrict__ saVa,
    const float* __restrict__ taWa, const float* __restrict__ taba, const float* __restrict__ taVa,
    float* __restrict__ out, float* __restrict__ Hws)
{
  __shared__ FSMA sm;
  const int tid = threadIdx.x;
  const int b0  = blockIdx.x * M;
  const int w   = tid >> 6, l = tid & 63;

  for (int idx = tid; idx < M*HH; idx += NT){
    int r = idx >> 7, j = idx & 127;
    sm.p1.s.h[r][j] = 0.f; sm.p1.s.c[r][j] = 0.f;
  }
  { int r = tid >> 6, d = tid & 63;
    sm.p1.s.x[r][d] = X[(size_t)(b0+r)*SS*DD + d]; }
  __syncthreads();

  for (int t = 0; t < SS; ++t){
    {
      float pr[M];
#pragma unroll
      for (int r = 0; r < M; ++r) pr[r] = 0.f;
      { const int kb = w*8;
#pragma unroll
        for (int q = 0; q < 2; ++q){
          const int k = kb + q*4;
          const float* wp = saWa + (size_t)k*DD + l;
          float w0 = wp[0], w1 = wp[DD], w2 = wp[2*DD], w3 = wp[3*DD];
#pragma unroll
          for (int r = 0; r < M; ++r){
            float4 v = *(const float4*)&sm.p1.s.x[r][k];
            pr[r] += w0*v.x + w1*v.y + w2*v.z + w3*v.w;
          }
        }
      }
      { const int kb = w*16;
#pragma unroll
        for (int q = 0; q < 4; ++q){
          const int k = kb + q*4;
          const float* wp = saUa + (size_t)k*DD + l;
          float w0 = wp[0], w1 = wp[DD], w2 = wp[2*DD], w3 = wp[3*DD];
#pragma unroll
          for (int r = 0; r < M; ++r){
            float4 v = *(const float4*)&sm.p1.s.h[r][k];
            pr[r] += w0*v.x + w1*v.y + w2*v.z + w3*v.w;
          }
        }
      }
      { const int kb = w*16;
#pragma unroll
        for (int q = 0; q < 4; ++q){
          const int k = kb + q*4;
          const float* wp = saUa + (size_t)(HH + k)*DD + l;
          float w0 = wp[0], w1 = wp[DD], w2 = wp[2*DD], w3 = wp[3*DD];
#pragma unroll
          for (int r = 0; r < M; ++r){
            float4 v = *(const float4*)&sm.p1.s.c[r][k];
            pr[r] += w0*v.x + w1*v.y + w2*v.z + w3*v.w;
          }
        }
      }
#pragma unroll
      for (int r = 0; r < M; ++r) sm.p1.red[w][r*64 + l] = pr[r];
    }
    __syncthreads();
    {
      float s = saba[l];
#pragma unroll
      for (int u = 0; u < 8; ++u) s += sm.p1.red[u][w*64 + l];
      sm.p1.s.a[w][l] = tanhx(s);
    }
    __syncthreads();
    {
      float pr[M];
#pragma unroll
      for (int r = 0; r < M; ++r) pr[r] = 0.f;
      const int kb = w*8;
#pragma unroll
      for (int q = 0; q < 2; ++q){
        const int k = kb + q*4;
        const float* wp = saVa + (size_t)k*DD + l;
        float w0 = wp[0], w1 = wp[DD], w2 = wp[2*DD], w3 = wp[3*DD];
#pragma unroll
        for (int r = 0; r < M; ++r){
          float4 v = *(const float4*)&sm.p1.s.a[r][k];
          pr[r] += w0*v.x + w1*v.y + w2*v.z + w3*v.w;
        }
      }
#pragma unroll
      for (int r = 0; r < M; ++r) sm.p1.red[w][r*64 + l] = pr[r];
    }
    __syncthreads();
    {
      float s = 0.f;
#pragma unroll
      for (int u = 0; u < 8; ++u) s += sm.p1.red[u][w*64 + l];
      float mm = wmax64(s);
      float e  = __expf(s - mm);
      float al = e * (1.0f / wsum64(e));
      out[A_OFF + (size_t)t*BB*DD + (size_t)(b0+w)*DD + l] = al;
      sm.p1.s.xw[w][l] = al * sm.p1.s.x[w][l];
    }
    __syncthreads();
    {
      const int c0 = tid;
      float acc[M];
      const float bv = sab[c0];
#pragma unroll
      for (int r = 0; r < M; ++r) acc[r] = bv;
      for (int k = 0; k < DD; k += 4){
        const float* wp = saW + (size_t)k*NG + c0;
        float w0 = wp[0], w1 = wp[NG], w2 = wp[2*NG], w3 = wp[3*NG];
#pragma unroll
        for (int r = 0; r < M; ++r){
          float4 v = *(const float4*)&sm.p1.s.xw[r][k];
          acc[r] += w0*v.x + w1*v.y + w2*v.z + w3*v.w;
        }
      }
      for (int k = 0; k < HH; k += 4){
        const float* wp = saU + (size_t)k*NG + c0;
        float w0 = wp[0], w1 = wp[NG], w2 = wp[2*NG], w3 = wp[3*NG];
#pragma unroll
        for (int r = 0; r < M; ++r){
          float4 v = *(const float4*)&sm.p1.s.h[r][k];
          acc[r] += w0*v.x + w1*v.y + w2*v.z + w3*v.w;
        }
      }
#pragma unroll
      for (int r = 0; r < M; ++r) sm.p1.s.g[r][c0] = acc[r];
    }
    __syncthreads();
    for (int idx = tid; idx < M*HH; idx += NT){
      int r = idx >> 7, j = idx & 127;
      float iv = sigf (sm.p1.s.g[r][j]);
      float fv = sigf (sm.p1.s.g[r][j +   HH]);
      float gv = tanhx(sm.p1.s.g[r][j + 2*HH]);
      float ov = sigf (sm.p1.s.g[r][j + 3*HH]);
      float cn = fv * sm.p1.s.c[r][j] + iv * gv;
      float hn = ov * tanhx(cn);
      sm.p1.s.c[r][j] = cn; sm.p1.s.h[r][j] = hn;
      Hws[(size_t)(b0+r)*SS*HH + (size_t)t*HH + j] = hn;
    }
    if (t + 1 < SS){
      int r = tid >> 6, d = tid & 63;
      sm.p1.s.x[r][d] = X[(size_t)(b0+r)*SS*DD + (size_t)(t+1)*DD + d];
    }
    __syncthreads();
  }

  for (int r = 0; r < M; ++r){
    float* Hrow = Hws + (size_t)(b0+r)*SS*HH;
    const int c  = tid & 127;
    const int th = tid >> 7;
    float hacc[32];
#pragma unroll
    for (int i = 0; i < 32; ++i) hacc[i] = 0.f;
#pragma unroll
    for (int ch = 0; ch < 4; ++ch){
      for (int idx = tid; idx < 32*HH/4; idx += NT)
        ((float4*)sm.p2.A)[idx] = ((const float4*)(Hrow + (size_t)ch*32*HH))[idx];
      __syncthreads();
      { float acc[8];
        const float bv = taba[c];
#pragma unroll
        for (int i = 0; i < 8; ++i) acc[i] = bv;
        for (int k = 0; k < HH; k += 4){
          const float* wp = taWa + (size_t)k*SS + c;
          float w0 = wp[0], w1 = wp[SS], w2 = wp[2*SS], w3 = wp[3*SS];
#pragma unroll
          for (int i = 0; i < 8; ++i){
            float4 v = *(const float4*)&sm.p2.A[th*8+i][k];
            acc[i] += w0*v.x + w1*v.y + w2*v.z + w3*v.w;
          }
        }
#pragma unroll
        for (int i = 0; i < 8; ++i) sm.p2.tmp[th*8+i][c] = tanhx(acc[i]);
      }
      __syncthreads();
      { float acc[8];
#pragma unroll
        for (int i = 0; i < 8; ++i) acc[i] = 0.f;
        for (int k = 0; k < SS; k += 4){
          const float* wp = taVa + (size_t)k*SS + c;
          float w0 = wp[0], w1 = wp[SS], w2 = wp[2*SS], w3 = wp[3*SS];
#pragma unroll
          for (int i = 0; i < 8; ++i){
            float4 v = *(const float4*)&sm.p2.tmp[th*8+i][k];
            acc[i] += w0*v.x + w1*v.y + w2*v.z + w3*v.w;
          }
        }
#pragma unroll
        for (int i = 0; i < 8; ++i) sm.p2.bp[th*8+i][c] = acc[i];
      }
      __syncthreads();
      { const int wv = tid >> 6, lane = tid & 63;
#pragma unroll
        for (int it = 0; it < 4; ++it){
          int tl = wv + 8*it;
          float v0 = sm.p2.bp[tl][lane], v1 = sm.p2.bp[tl][lane+64];
          float mm = wmax64(fmaxf(v0, v1));
          float e0 = __expf(v0 - mm), e1 = __expf(v1 - mm);
          float inv = 1.0f / wsum64(e0 + e1);
          e0 *= inv; e1 *= inv;
          size_t bo = BETA_OFF + (size_t)(ch*32+tl)*BB*SS + (size_t)(b0+r)*SS;
          out[bo + lane]      = e0;
          out[bo + lane + 64] = e1;
          sm.p2.bp[tl][lane]      = e0;
          sm.p2.bp[tl][lane + 64] = e1;
        }
      }
      __syncthreads();
      for (int k = 0; k < SS; k += 4){
        const float* hp = Hrow + (size_t)k*HH + c;
        float hv0 = hp[0], hv1 = hp[HH], hv2 = hp[2*HH], hv3 = hp[3*HH];
#pragma unroll
        for (int i = 0; i < 8; ++i){
          float4 bv = *(const float4*)&sm.p2.bp[th*8+i][k];
          hacc[ch*8+i] += bv.x*hv0 + bv.y*hv1 + bv.z*hv2 + bv.w*hv3;
        }
      }
    }
    __syncthreads();
#pragma unroll
    for (int ch = 0; ch < 4; ++ch)
#pragma unroll
      for (int i = 0; i < 8; ++i)
        Hrow[(size_t)(ch*32 + th*8 + i)*HH + c] = hacc[ch*8+i];
    __syncthreads();
  }
}

__global__ __launch_bounds__(NT, 2) void fb_ph3_kernel(
    const float* __restrict__ X, const float* __restrict__ Ha,
    const float* __restrict__ taW, const float* __restrict__ taU,
    const float* __restrict__ tab, const float* __restrict__ taWy,
    const float* __restrict__ fcw, const float* __restrict__ fcb,
    float* __restrict__ out)
{
  __shared__ struct {
    float ha[M][HH]; float lh[M][HH]; float lc[M][HH];
    float g[M][NG];  float yp[M];
  } s;
  const int tid = threadIdx.x;
  const int b0  = blockIdx.x * M;

  for (int idx = tid; idx < M*HH; idx += NT){
    int r = idx >> 7, j = idx & 127;
    s.lh[r][j] = 0.f; s.lc[r][j] = 0.f;
  }
  if (tid < M) s.yp[tid] = X[(size_t)(b0+tid)*SS*DD + (DD-1)];
  if (tid < M*HH/4){
    int r = tid >> 5, q = tid & 31;
    ((float4*)s.ha)[tid] = *(const float4*)(Ha + (size_t)(b0+r)*SS*HH + q*4);
  }
  __syncthreads();

  for (int t = 0; t < SS; ++t){
    {
      const int c0 = tid;
      const float wy = taWy[c0];
      const float tb = tab[c0];
      float acc[M];
#pragma unroll
      for (int r = 0; r < M; ++r) acc[r] = tb + s.yp[r]*wy;
      for (int k = 0; k < HH; k += 4){
        const float* wp = taW + (size_t)k*NG + c0;
        float a0 = wp[0], a1 = wp[NG], a2 = wp[2*NG], a3 = wp[3*NG];
#pragma unroll
        for (int r = 0; r < M; ++r){
          float4 v = *(const float4*)&s.ha[r][k];
          acc[r] += a0*v.x + a1*v.y + a2*v.z + a3*v.w;
        }
      }
      for (int k = 0; k < HH; k += 4){
        const float* wp = taU + (size_t)k*NG + c0;
        float a0 = wp[0], a1 = wp[NG], a2 = wp[2*NG], a3 = wp[3*NG];
#pragma unroll
        for (int r = 0; r < M; ++r){
          float4 v = *(const float4*)&s.lh[r][k];
          acc[r] += a0*v.x + a1*v.y + a2*v.z + a3*v.w;
        }
      }
#pragma unroll
      for (int r = 0; r < M; ++r) s.g[r][c0] = acc[r];
    }
    __syncthreads();
    for (int idx = tid; idx < M*HH; idx += NT){
      int r = idx >> 7, j = idx & 127;
      float iv = sigf (s.g[r][j]);
      float fv = sigf (s.g[r][j +   HH]);
      float gv = tanhx(s.g[r][j + 2*HH]);
      float ov = sigf (s.g[r][j + 3*HH]);
      float cn = fv * s.lc[r][j] + iv * gv;
      float hn = ov * tanhx(cn);
      s.lc[r][j] = cn; s.lh[r][j] = hn;
    }
    if (t + 1 < SS && tid < M*HH/4){
      int r = tid >> 5, q = tid & 31;
      ((float4*)s.ha)[tid] =
        *(const float4*)(Ha + (size_t)(b0+r)*SS*HH + (size_t)(t+1)*HH + q*4);
    }
    __syncthreads();
    {
      const int r = tid >> 6, lx = tid & 63;
      float p = s.lh[r][lx]*fcw[lx] + s.lh[r][lx+64]*fcw[lx+64];
      p = wsum64(p);
      if (lx == 0) s.yp[r] = p + fcb[0];
    }
    __syncthreads();
  }
  if (tid < M) out[b0 + tid] = s.yp[tid];
}

extern "C" void kernel_launch(void* const* d_in, const int* in_sizes, int n_in,
                              void* d_out, int out_size, void* d_ws, size_t ws_size,
                              hipStream_t stream) {
  (void)in_sizes; (void)n_in; (void)out_size;
  const float* X    = (const float*)d_in[0];
  const float* saW  = (const float*)d_in[1];
  const float* saU  = (const float*)d_in[2];
  const float* sab  = (const float*)d_in[3];
  const float* saWa = (const float*)d_in[4];
  const float* saUa = (const float*)d_in[5];
  const float* saba = (const float*)d_in[6];
  const float* saVa = (const float*)d_in[7];
  const float* taWa = (const float*)d_in[8];
  // d_in[9] = ta_Ua: unused by the reference forward pass
  const float* taba = (const float*)d_in[10];
  const float* taVa = (const float*)d_in[11];
  const float* taW  = (const float*)d_in[12];
  const float* taU  = (const float*)d_in[13];
  const float* tab  = (const float*)d_in[14];
  const float* taWy = (const float*)d_in[15];
  const float* fcw  = (const float*)d_in[16];
  const float* fcb  = (const float*)d_in[17];
  float* out = (float*)d_out;

  if (ws_size >= NEED2_BYTES){
    unsigned short* Fr = (unsigned short*)d_ws;
    float* Hws = (float*)((char*)d_ws + FRAG_BYTES);
    hipLaunchKernelGGL(repack_kernel, dim3(512), dim3(256), 0, stream,
                       saW, saU, saWa, saUa, saVa, taU, taW, taWa, taVa, Fr);
    hipLaunchKernelGGL(mf_ph1_kernel, dim3(BB / M), dim3(NT), 0, stream,
                       X, sab, saba, Fr, out, Hws);
    hipLaunchKernelGGL(ph2_kernel, dim3(BB), dim3(NT), 0, stream,
                       taba, Fr, out, Hws);
    if (ws_size >= NEED3_BYTES){
      float* G0 = (float*)((char*)d_ws + FRAG_BYTES + H_BYTES);
      hipLaunchKernelGGL(g0mm_kernel, dim3((BB*SS)/128), dim3(NT), 0, stream,
                         Hws, Fr, tab, G0);
      hipLaunchKernelGGL(mf_ph3h_kernel, dim3(BB / M), dim3(NT), 0, stream,
                         X, Fr, G0, taWy, fcw, fcb, out);
    } else {
      hipLaunchKernelGGL(mf_ph3_kernel, dim3(BB / M), dim3(NT), 0, stream,
                         X, Hws, Fr, tab, taWy, fcw, fcb, out);
    }
  } else {
    float* Hws = (float*)d_ws;
    hipLaunchKernelGGL(fb_ph12_kernel, dim3(BB / M), dim3(NT), 0, stream,
                       X, saW, saU, sab, saWa, saUa, saba, saVa,
                       taWa, taba, taVa, out, Hws);
    hipLaunchKernelGGL(fb_ph3_kernel, dim3(BB / M), dim3(NT), 0, stream,
                       X, Hws, taW, taU, tab, taWy, fcw, fcb, out);
  }
}

// Round 12
// 1620.597 us; speedup vs baseline: 1.8019x; 1.7752x over previous
//
#include <hip/hip_runtime.h>

// STA-LSTM forward: B=2048, S=128, D=64, H1=H2=128, OUT=1
// Round 12: fix scatter-store write amplification (6x WRITE_SIZE) at the two
//   MFMA-fragment->global store sites. Fragment-layout scalar stores emit 4x64B
//   scattered segments per wave-op -> L2/EA write amplification. Fix: stage
//   through padded LDS tile, then coalesced float4 pass (>=512B/row dense).
//   1. g0mm: nt=p*8+w (pass-contiguous cols) + SG[128][132] staging.
//   2. ph2: h_att staged via HO[128][132] (union over fA/fB) -> coalesced Hb write.
// Kernels: repack -> mf_ph1 -> ph2 -> g0mm -> mf_ph3h   (full tier)
//          repack -> mf_ph1 -> ph2 -> mf_ph3full        (if ws lacks G0 space)
//          fb_* VALU kernels                             (if ws < 130 MB)
// NOTE: NT=512 + launch_bounds(512,2)/waves_per_eu(2,2) is the ONLY config that
// reliably avoids spills (NT=1024 variants collapse to VGPR=64 + scratch).

#define BB 2048
#define SS 128
#define DD 64
#define HH 128
#define NG 512
#define M  8
#define NT 512

#define A_OFF    ((size_t)BB)
#define BETA_OFF ((size_t)BB + (size_t)SS*BB*DD)
#define H_BYTES  ((size_t)BB*SS*HH*4)
#define G0_BYTES ((size_t)BB*SS*NG*4)

// fragment buffer layout in ws (ushort offsets)
#define B1G_ELEMS (192*512)
#define B1A_ELEMS (320*64)
#define BVA_ELEMS (64*64)
#define B3_ELEMS  (256*512)
#define BW_ELEMS  (128*128)
#define GH_OFF 0
#define GL_OFF (B1G_ELEMS)
#define AH_OFF (2*B1G_ELEMS)
#define AL_OFF (2*B1G_ELEMS + B1A_ELEMS)
#define VH_OFF (2*B1G_ELEMS + 2*B1A_ELEMS)
#define VL_OFF (VH_OFF + BVA_ELEMS)
#define B3H_OFF (VH_OFF + 2*BVA_ELEMS)
#define B3L_OFF (B3H_OFF + B3_ELEMS)
#define RW_OFF  (B3H_OFF + 2*B3_ELEMS)
#define RV_OFF  (RW_OFF + BW_ELEMS)
#define FRAG_BYTES ((size_t)(RV_OFF + BW_ELEMS)*2)
#define NEED2_BYTES (FRAG_BYTES + H_BYTES)
#define NEED3_BYTES (FRAG_BYTES + H_BYTES + G0_BYTES)

typedef float f32x4 __attribute__((ext_vector_type(4)));
typedef __bf16 bf16x8 __attribute__((ext_vector_type(8)));
union FB { uint4 u; bf16x8 v; };
__device__ __forceinline__ bf16x8 as_bf(uint4 u){ FB x; x.u = u; return x.v; }

__device__ __forceinline__ unsigned short bf16rne(float f){
  unsigned u = __float_as_uint(f);
  u = (u + 0x7FFFu + ((u >> 16) & 1u)) >> 16;
  return (unsigned short)u;
}
__device__ __forceinline__ float bfval(unsigned short h){
  return __uint_as_float(((unsigned)h) << 16);
}

__device__ __forceinline__ float sigf(float x){ return 1.0f/(1.0f + __expf(-x)); }
__device__ __forceinline__ float tanhx(float x){ return 1.0f - 2.0f/(1.0f + __expf(2.0f*x)); }

__device__ __forceinline__ float wmax64(float v){
#pragma unroll
  for (int m = 32; m; m >>= 1) v = fmaxf(v, __shfl_xor(v, m, 64));
  return v;
}
__device__ __forceinline__ float wsum64(float v){
#pragma unroll
  for (int m = 32; m; m >>= 1) v += __shfl_xor(v, m, 64);
  return v;
}

// ================= repack: weights -> fragment-ordered buffers =================
__global__ __launch_bounds__(256) void repack_kernel(
    const float* __restrict__ saW, const float* __restrict__ saU,
    const float* __restrict__ saWa, const float* __restrict__ saUa,
    const float* __restrict__ saVa,
    const float* __restrict__ taU, const float* __restrict__ taW,
    const float* __restrict__ taWa, const float* __restrict__ taVa,
    unsigned short* __restrict__ F)
{
  int id = blockIdx.x*256 + threadIdx.x;
  if (id < B1G_ELEMS){          // gate: k 0-127 = saU(h), 128-191 = saW(xw)
    int k = id >> 9, n = id & 511;
    float v = (k < 128) ? saU[(size_t)k*NG + n] : saW[(size_t)(k-128)*NG + n];
    int kk = k >> 5, kw = k & 31, nt = n >> 4, nc = n & 15;
    int lane = ((kw >> 3) << 4) | nc, j = kw & 7;
    size_t off = ((size_t)(nt*6 + kk)*64 + lane)*8 + j;
    unsigned short hi = bf16rne(v);
    F[GH_OFF + off] = hi; F[GL_OFF + off] = bf16rne(v - bfval(hi));
  }
  if (id < B1A_ELEMS){          // attn: k 0-255 = saUa(h,c), 256-319 = saWa(x)
    int k = id >> 6, n = id & 63;
    float v = (k < 256) ? saUa[(size_t)k*DD + n] : saWa[(size_t)(k-256)*DD + n];
    int kt = k >> 5, kw = k & 31, nt = n >> 4, nc = n & 15;
    int lane = ((kw >> 3) << 4) | nc, j = kw & 7;
    size_t off = ((size_t)(nt*10 + kt)*64 + lane)*8 + j;
    unsigned short hi = bf16rne(v);
    F[AH_OFF + off] = hi; F[AL_OFF + off] = bf16rne(v - bfval(hi));
  }
  if (id < BVA_ELEMS){          // saVa 64x64
    int k = id >> 6, n = id & 63;
    float v = saVa[(size_t)k*DD + n];
    int kt = k >> 5, kw = k & 31, nt = n >> 4, nc = n & 15;
    int lane = ((kw >> 3) << 4) | nc, j = kw & 7;
    size_t off = ((size_t)(nt*2 + kt)*64 + lane)*8 + j;
    unsigned short hi = bf16rne(v);
    F[VH_OFF + off] = hi; F[VL_OFF + off] = bf16rne(v - bfval(hi));
  }
  if (id < B3_ELEMS){           // ph3: k 0-127 = taU(lh), 128-255 = taW(ha)
    int k = id >> 9, n = id & 511;
    float v = (k < HH) ? taU[(size_t)k*NG + n] : taW[(size_t)(k-HH)*NG + n];
    int kt = k >> 5, kw = k & 31, nt = n >> 4, nc = n & 15;
    int lane = ((kw >> 3) << 4) | nc, j = kw & 7;
    size_t off = ((size_t)(nt*8 + kt)*64 + lane)*8 + j;
    unsigned short hi = bf16rne(v);
    F[B3H_OFF + off] = hi; F[B3L_OFF + off] = bf16rne(v - bfval(hi));
  }
  if (id < BW_ELEMS){           // ph2 bf16 frags
    int k = id >> 7, n = id & 127;
    int kt = k >> 5, kw = k & 31, nt = n >> 4, nc = n & 15;
    int lane = ((kw >> 3) << 4) | nc, j = kw & 7;
    size_t off = ((size_t)(nt*4 + kt)*64 + lane)*8 + j;
    F[RW_OFF + off] = bf16rne(taWa[(size_t)k*SS + n]);
    F[RV_OFF + off] = bf16rne(taVa[(size_t)k*SS + n]);
  }
}

// ================= mf_ph1: spatial-attn LSTM, fully MFMA (round 10/11) =========
struct P1 {
  uint4 afh[12*64];    // 12K
  uint4 afl[12*64];    // 12K
  uint4 aah[2*64];     // 2K
  uint4 aal[2*64];     // 2K
  float xx[M][DD];     // 2K
  float cc[M][HH];     // 4K
  float red[2][M][64]; // 4K
  float g[M][NG];      // 16K
  float sbias[NG];     // 2K
};
struct P2S { float A[32][HH]; float tmp[32][SS]; float bp[32][SS]; };  // fallback
union __align__(16) SMA { P1 p1; float pad[21504]; };   // 84K -> 1 blk/CU

__global__ __launch_bounds__(NT, 2) __attribute__((amdgpu_waves_per_eu(2, 2)))
void mf_ph1_kernel(
    const float* __restrict__ X,   const float* __restrict__ sab,
    const float* __restrict__ saba,
    const unsigned short* __restrict__ Fr,
    float* __restrict__ out, float* __restrict__ Hws)
{
  __shared__ SMA sm;
  const int tid = threadIdx.x;
  const int b0  = blockIdx.x * M;
  const int w   = tid >> 6, l = tid & 63;

  {
    uint4 z4 = make_uint4(0,0,0,0);
    for (int i = tid; i < 12*64; i += NT){ sm.p1.afh[i] = z4; sm.p1.afl[i] = z4; }
    if (tid < 2*64){ sm.p1.aah[tid] = z4; sm.p1.aal[tid] = z4; }
    for (int i = tid; i < M*HH; i += NT) ((float*)sm.p1.cc)[i] = 0.f;
    sm.p1.sbias[tid] = sab[tid];
  }
  __syncthreads();
  if (tid < 128){   // x(0) + x-frags (tiles 8-9)
    int r = tid >> 4, d0 = (tid & 15)*4;
    float4 v = *(const float4*)(X + (size_t)(b0+r)*SS*DD + d0);
    *(float4*)&sm.p1.xx[r][d0] = v;
    unsigned short* AFH = (unsigned short*)sm.p1.afh;
    unsigned short* AFL = (unsigned short*)sm.p1.afl;
    int kt = 8 + (d0 >> 5), lane = (((d0 & 31) >> 3) << 4) | r, jj0 = d0 & 7;
    float vv[4] = {v.x, v.y, v.z, v.w};
#pragma unroll
    for (int p = 0; p < 4; ++p){
      unsigned short h_ = bf16rne(vv[p]);
      AFH[(kt*64 + lane)*8 + jj0 + p] = h_;
      AFL[(kt*64 + lane)*8 + jj0 + p] = bf16rne(vv[p] - bfval(h_));
    }
  }
  __syncthreads();

  for (int t = 0; t < SS; ++t){
    // ---- P1: attn MFMA -> red  +  gate-h partial MFMA (kk0-3) -> accg regs ----
    f32x4 accg[4];
    {
      f32x4 zf = {0.f,0.f,0.f,0.f};
#pragma unroll
      for (int n4 = 0; n4 < 4; ++n4) accg[n4] = zf;
    }
    {
      const int nt = w & 3, kh = w >> 2;
      f32x4 a0 = {0.f,0.f,0.f,0.f}, a1 = {0.f,0.f,0.f,0.f};
      const uint4* BAH = (const uint4*)(Fr + AH_OFF);
      const uint4* BAL = (const uint4*)(Fr + AL_OFF);
#pragma unroll
      for (int q = 0; q < 5; ++q){
        const int kt = kh*5 + q;
        bf16x8 ah = as_bf(sm.p1.afh[kt*64 + l]);
        bf16x8 av = as_bf(sm.p1.afl[kt*64 + l]);
        bf16x8 bh = as_bf(BAH[(nt*10 + kt)*64 + l]);
        bf16x8 bl = as_bf(BAL[(nt*10 + kt)*64 + l]);
        if (q & 1){
          a1 = __builtin_amdgcn_mfma_f32_16x16x32_bf16(ah, bh, a1, 0, 0, 0);
          a1 = __builtin_amdgcn_mfma_f32_16x16x32_bf16(av, bh, a1, 0, 0, 0);
          a1 = __builtin_amdgcn_mfma_f32_16x16x32_bf16(ah, bl, a1, 0, 0, 0);
        } else {
          a0 = __builtin_amdgcn_mfma_f32_16x16x32_bf16(ah, bh, a0, 0, 0, 0);
          a0 = __builtin_amdgcn_mfma_f32_16x16x32_bf16(av, bh, a0, 0, 0, 0);
          a0 = __builtin_amdgcn_mfma_f32_16x16x32_bf16(ah, bl, a0, 0, 0, 0);
        }
      }
      f32x4 acc = a0 + a1;
      const int row0 = (l >> 4)*4, c0 = l & 15;
      if (row0 < 8){
#pragma unroll
        for (int jj = 0; jj < 4; ++jj)
          sm.p1.red[kh][row0+jj][nt*16 + c0] = acc[jj];
      }
      // gate-h part (no LDS writes; results stay in accg)
      const uint4* GH = (const uint4*)(Fr + GH_OFF);
      const uint4* GL = (const uint4*)(Fr + GL_OFF);
#pragma unroll
      for (int kk = 0; kk < 4; ++kk){
        bf16x8 ah = as_bf(sm.p1.afh[kk*64 + l]);
        bf16x8 av = as_bf(sm.p1.afl[kk*64 + l]);
#pragma unroll
        for (int n4 = 0; n4 < 4; ++n4){
          const int ntg = w*4 + n4;
          bf16x8 bh = as_bf(GH[(ntg*6 + kk)*64 + l]);
          bf16x8 bl = as_bf(GL[(ntg*6 + kk)*64 + l]);
          accg[n4] = __builtin_amdgcn_mfma_f32_16x16x32_bf16(ah, bh, accg[n4], 0, 0, 0);
          accg[n4] = __builtin_amdgcn_mfma_f32_16x16x32_bf16(av, bh, accg[n4], 0, 0, 0);
          accg[n4] = __builtin_amdgcn_mfma_f32_16x16x32_bf16(ah, bl, accg[n4], 0, 0, 0);
        }
      }
    }
    __syncthreads();

    // ---- P2: combine + bias + tanh -> a-frags ----
    {
      const int r = w, col = l;
      float s = sm.p1.red[0][r][col] + sm.p1.red[1][r][col] + saba[col];
      float av = tanhx(s);
      unsigned short h_ = bf16rne(av);
      int kt = col >> 5, lane = (((col & 31) >> 3) << 4) | r, jj = col & 7;
      ((unsigned short*)sm.p1.aah)[(kt*64 + lane)*8 + jj] = h_;
      ((unsigned short*)sm.p1.aal)[(kt*64 + lane)*8 + jj] = bf16rne(av - bfval(h_));
    }
    __syncthreads();

    // ---- P3: GEMM2 MFMA  av = a @ saVa ----
    {
      const int nt = w & 3, kt = w >> 2;   // kt 0-1
      f32x4 acc = {0.f,0.f,0.f,0.f};
      bf16x8 ah = as_bf(sm.p1.aah[kt*64 + l]);
      bf16x8 av = as_bf(sm.p1.aal[kt*64 + l]);
      bf16x8 bh = as_bf(((const uint4*)(Fr + VH_OFF))[(nt*2 + kt)*64 + l]);
      bf16x8 bl = as_bf(((const uint4*)(Fr + VL_OFF))[(nt*2 + kt)*64 + l]);
      acc = __builtin_amdgcn_mfma_f32_16x16x32_bf16(ah, bh, acc, 0, 0, 0);
      acc = __builtin_amdgcn_mfma_f32_16x16x32_bf16(av, bh, acc, 0, 0, 0);
      acc = __builtin_amdgcn_mfma_f32_16x16x32_bf16(ah, bl, acc, 0, 0, 0);
      const int row0 = (l >> 4)*4, c0 = l & 15;
      if (row0 < 8){
#pragma unroll
        for (int jj = 0; jj < 4; ++jj)
          sm.p1.red[kt][row0+jj][nt*16 + c0] = acc[jj];
      }
    }
    __syncthreads();

    // ---- P4: softmax + alphas out + xw-frags (tiles 10-11) ----
    {
      const int r = w, col = l;
      float s = sm.p1.red[0][r][col] + sm.p1.red[1][r][col];
      float mm = wmax64(s);
      float e  = __expf(s - mm);
      float alv = e * (1.0f / wsum64(e));
      out[A_OFF + (size_t)t*BB*DD + (size_t)(b0+r)*DD + col] = alv;
      float xwv = alv * sm.p1.xx[r][col];
      unsigned short h_ = bf16rne(xwv);
      int kt = 10 + (col >> 5), lane = (((col & 31) >> 3) << 4) | r, jj = col & 7;
      ((unsigned short*)sm.p1.afh)[(kt*64 + lane)*8 + jj] = h_;
      ((unsigned short*)sm.p1.afl)[(kt*64 + lane)*8 + jj] = bf16rne(xwv - bfval(h_));
    }
    __syncthreads();

    // ---- P5: gates xw-part (kk4-5) + x(t+1) prefetch issue ----
    float4 pf;
    const bool dox = (tid < 128) && (t + 1 < SS);
    if (dox){
      int r = tid >> 4, d0 = (tid & 15)*4;
      pf = *(const float4*)(X + (size_t)(b0+r)*SS*DD + (size_t)(t+1)*DD + d0);
    }
    {
      const uint4* GH = (const uint4*)(Fr + GH_OFF);
      const uint4* GL = (const uint4*)(Fr + GL_OFF);
#pragma unroll
      for (int kk = 4; kk < 6; ++kk){
        const int afi = kk + 6;   // 10, 11
        bf16x8 ah = as_bf(sm.p1.afh[afi*64 + l]);
        bf16x8 av = as_bf(sm.p1.afl[afi*64 + l]);
#pragma unroll
        for (int n4 = 0; n4 < 4; ++n4){
          const int ntg = w*4 + n4;
          bf16x8 bh = as_bf(GH[(ntg*6 + kk)*64 + l]);
          bf16x8 bl = as_bf(GL[(ntg*6 + kk)*64 + l]);
          accg[n4] = __builtin_amdgcn_mfma_f32_16x16x32_bf16(ah, bh, accg[n4], 0, 0, 0);
          accg[n4] = __builtin_amdgcn_mfma_f32_16x16x32_bf16(av, bh, accg[n4], 0, 0, 0);
          accg[n4] = __builtin_amdgcn_mfma_f32_16x16x32_bf16(ah, bl, accg[n4], 0, 0, 0);
        }
      }
      const int row0 = (l >> 4)*4, c0 = l & 15;
      if (row0 < 8){
#pragma unroll
        for (int n4 = 0; n4 < 4; ++n4){
          int col = w*64 + n4*16 + c0;
          float b = sm.p1.sbias[col];
#pragma unroll
          for (int jj = 0; jj < 4; ++jj)
            sm.p1.g[row0+jj][col] = accg[n4][jj] + b;
        }
      }
    }
    __syncthreads();

    // ---- P6: pointwise + h/c frag build + H store + x(t+1) commit ----
    {
      unsigned short* AFH = (unsigned short*)sm.p1.afh;
      unsigned short* AFL = (unsigned short*)sm.p1.afl;
#pragma unroll
      for (int h2 = 0; h2 < 2; ++h2){
        int idx = h2*NT + tid;
        int r = idx >> 7, j = idx & 127;
        float iv = sigf (sm.p1.g[r][j]);
        float fv = sigf (sm.p1.g[r][j + 128]);
        float gv = tanhx(sm.p1.g[r][j + 256]);
        float ov = sigf (sm.p1.g[r][j + 384]);
        float cn = fv * sm.p1.cc[r][j] + iv * gv;
        float hn = ov * tanhx(cn);
        sm.p1.cc[r][j] = cn;
        Hws[(size_t)(b0+r)*SS*HH + (size_t)t*HH + j] = hn;
        int lane = (((j & 31) >> 3) << 4) | r, jj = j & 7;
        int ktH = j >> 5, ktC = 4 + (j >> 5);
        unsigned short hh_ = bf16rne(hn);
        unsigned short ch_ = bf16rne(cn);
        AFH[(ktH*64 + lane)*8 + jj] = hh_;
        AFL[(ktH*64 + lane)*8 + jj] = bf16rne(hn - bfval(hh_));
        AFH[(ktC*64 + lane)*8 + jj] = ch_;
        AFL[(ktC*64 + lane)*8 + jj] = bf16rne(cn - bfval(ch_));
      }
      if (dox){
        int r = tid >> 4, d0 = (tid & 15)*4;
        *(float4*)&sm.p1.xx[r][d0] = pf;
        int kt = 8 + (d0 >> 5), lane = (((d0 & 31) >> 3) << 4) | r, jj0 = d0 & 7;
        float vv[4] = {pf.x, pf.y, pf.z, pf.w};
#pragma unroll
        for (int p = 0; p < 4; ++p){
          unsigned short h_ = bf16rne(vv[p]);
          AFH[(kt*64 + lane)*8 + jj0 + p] = h_;
          AFL[(kt*64 + lane)*8 + jj0 + p] = bf16rne(vv[p] - bfval(h_));
        }
      }
    }
    __syncthreads();
  }
}

// ================= ph2_kernel: betas + h_att, all-MFMA, staged Hb write ========
struct PH2SM {
  union {
    struct { uint4 fA[8][4][64]; uint4 fB[8][4][64]; } f;   // 64 KB
    float HO[128][132];                                      // 67.6 KB (pad 4)
  } u;
  unsigned short S[128][136];  // 34 KB (pad 8)
  float bias[SS];
};

__global__ __launch_bounds__(NT, 2) void ph2_kernel(
    const float* __restrict__ taba, const unsigned short* __restrict__ Fr,
    float* __restrict__ out, float* __restrict__ Hws)
{
  __shared__ PH2SM sm;
  const int tid = threadIdx.x;
  const int b   = blockIdx.x;
  const int w   = tid >> 6, l = tid & 63;
  const int g   = l >> 4, c0 = l & 15;
  float* Hb = Hws + (size_t)b * SS * HH;

  if (tid < SS) sm.bias[tid] = taba[tid];
  {
    const float4* src = (const float4*)Hb;
#pragma unroll
    for (int i = 0; i < 8; ++i){
      int fidx = i*NT + tid;
      float4 v = src[fidx];
      int e0 = fidx*4, row = e0 >> 7, col = e0 & 127;
      sm.S[row][col+0] = bf16rne(v.x);
      sm.S[row][col+1] = bf16rne(v.y);
      sm.S[row][col+2] = bf16rne(v.z);
      sm.S[row][col+3] = bf16rne(v.w);
    }
  }
  __syncthreads();

#pragma unroll
  for (int i = 0; i < 4; ++i){
    int slot = i*NT + tid;
    int mt = slot >> 8, kt = (slot >> 6) & 3, ll = slot & 63;
    int row = mt*16 + (ll & 15), k0 = kt*32 + (ll >> 4)*8;
    ((uint4*)sm.u.f.fA)[slot] = *(const uint4*)&sm.S[row][k0];
  }
#pragma unroll
  for (int i = 0; i < 4; ++i){
    int slot = i*NT + tid;
    int nt = slot >> 8, kt = (slot >> 6) & 3, ll = slot & 63;
    int col = nt*16 + (ll & 15), s0 = kt*32 + (ll >> 4)*8;
    unsigned u[4];
#pragma unroll
    for (int p = 0; p < 4; ++p)
      u[p] = (unsigned)sm.S[s0+2*p][col] | ((unsigned)sm.S[s0+2*p+1][col] << 16);
    ((uint4*)sm.u.f.fB)[slot] = make_uint4(u[0], u[1], u[2], u[3]);
  }
  __syncthreads();

  f32x4 acc[8];
  f32x4 zero4 = {0.f, 0.f, 0.f, 0.f};

  // ---- GEMM1: tmp = tanh(H @ taWa + ba) ----
#pragma unroll
  for (int nt = 0; nt < 8; ++nt) acc[nt] = zero4;
  {
    const uint4* BW = (const uint4*)(Fr + RW_OFF);
#pragma unroll
    for (int kt = 0; kt < 4; ++kt){
      bf16x8 a = as_bf(sm.u.f.fA[w][kt][l]);
#pragma unroll
      for (int nt = 0; nt < 8; ++nt){
        bf16x8 bv = as_bf(BW[(nt*4 + kt)*64 + l]);
        acc[nt] = __builtin_amdgcn_mfma_f32_16x16x32_bf16(a, bv, acc[nt], 0, 0, 0);
      }
    }
  }
#pragma unroll
  for (int nt = 0; nt < 8; ++nt){
    int col = nt*16 + c0;
    float bv = sm.bias[col];
#pragma unroll
    for (int j = 0; j < 4; ++j)
      sm.S[w*16 + g*4 + j][col] = bf16rne(tanhx(acc[nt][j] + bv));
  }
  __syncthreads();

  // ---- rebuild fA from S (tmp) ----
#pragma unroll
  for (int i = 0; i < 4; ++i){
    int slot = i*NT + tid;
    int mt = slot >> 8, kt = (slot >> 6) & 3, ll = slot & 63;
    int row = mt*16 + (ll & 15), k0 = kt*32 + (ll >> 4)*8;
    ((uint4*)sm.u.f.fA)[slot] = *(const uint4*)&sm.S[row][k0];
  }
  __syncthreads();

  // ---- GEMM2: bp = tmp @ taVa ----
#pragma unroll
  for (int nt = 0; nt < 8; ++nt) acc[nt] = zero4;
  {
    const uint4* BV = (const uint4*)(Fr + RV_OFF);
#pragma unroll
    for (int kt = 0; kt < 4; ++kt){
      bf16x8 a = as_bf(sm.u.f.fA[w][kt][l]);
#pragma unroll
      for (int nt = 0; nt < 8; ++nt){
        bf16x8 bv = as_bf(BV[(nt*4 + kt)*64 + l]);
        acc[nt] = __builtin_amdgcn_mfma_f32_16x16x32_bf16(a, bv, acc[nt], 0, 0, 0);
      }
    }
  }

  // ---- in-register softmax + betas out ----
#pragma unroll
  for (int j = 0; j < 4; ++j){
    float m = acc[0][j];
#pragma unroll
    for (int nt = 1; nt < 8; ++nt) m = fmaxf(m, acc[nt][j]);
#pragma unroll
    for (int ms = 1; ms < 16; ms <<= 1) m = fmaxf(m, __shfl_xor(m, ms, 64));
    float e[8], s = 0.f;
#pragma unroll
    for (int nt = 0; nt < 8; ++nt){ e[nt] = __expf(acc[nt][j] - m); s += e[nt]; }
#pragma unroll
    for (int ms = 1; ms < 16; ms <<= 1) s += __shfl_xor(s, ms, 64);
    float inv = 1.0f / s;
    int row = w*16 + g*4 + j;
    size_t bo = BETA_OFF + (size_t)row*BB*SS + (size_t)b*SS;
#pragma unroll
    for (int nt = 0; nt < 8; ++nt){
      float bv = e[nt] * inv;
      out[bo + nt*16 + c0] = bv;
      sm.S[row][nt*16 + c0] = bf16rne(bv);
    }
  }
  __syncthreads();

  // ---- rebuild fA from S (beta) ----
#pragma unroll
  for (int i = 0; i < 4; ++i){
    int slot = i*NT + tid;
    int mt = slot >> 8, kt = (slot >> 6) & 3, ll = slot & 63;
    int row = mt*16 + (ll & 15), k0 = kt*32 + (ll >> 4)*8;
    ((uint4*)sm.u.f.fA)[slot] = *(const uint4*)&sm.S[row][k0];
  }
  __syncthreads();

  // ---- GEMM3: h_att = beta @ H ----
#pragma unroll
  for (int nt = 0; nt < 8; ++nt) acc[nt] = zero4;
#pragma unroll
  for (int kt = 0; kt < 4; ++kt){
    bf16x8 a = as_bf(sm.u.f.fA[w][kt][l]);
#pragma unroll
    for (int nt = 0; nt < 8; ++nt){
      bf16x8 bv = as_bf(sm.u.f.fB[nt][kt][l]);
      acc[nt] = __builtin_amdgcn_mfma_f32_16x16x32_bf16(a, bv, acc[nt], 0, 0, 0);
    }
  }
  __syncthreads();   // all fA/fB reads done before HO overwrites them

  // ---- stage h_att into HO, then coalesced write to Hb ----
#pragma unroll
  for (int nt = 0; nt < 8; ++nt)
#pragma unroll
    for (int j = 0; j < 4; ++j)
      sm.u.HO[w*16 + g*4 + j][nt*16 + c0] = acc[nt][j];
  __syncthreads();
#pragma unroll
  for (int it = 0; it < 8; ++it){
    int flat = it*NT + tid;          // 4096 float4 = 128 rows x 32
    int row = flat >> 5, cq = flat & 31;
    *(float4*)(Hb + (size_t)row*HH + cq*4) = *(const float4*)&sm.u.HO[row][cq*4];
  }
}

// ================= g0mm: G0[b][t][:] = h_att @ taW + tab, staged writes ========
// 2048 blocks x 512 thr; block handles 128 flat (b,t) rows.
// Pass p: waves cover contiguous cols [p*128, (p+1)*128); results staged in SG
// then written with coalesced float4 (512B dense per row segment).
struct GMM { uint4 afh[8][4][64]; uint4 afl[8][4][64]; float SG[128][132]; };  // 131.6 KB

__global__ __launch_bounds__(NT, 2) void g0mm_kernel(
    const float* __restrict__ Ha, const unsigned short* __restrict__ Fr,
    const float* __restrict__ tab, float* __restrict__ G0)
{
  __shared__ GMM sm;
  const int tid = threadIdx.x;
  const size_t r0 = (size_t)blockIdx.x * 128;
  const int w = tid >> 6, l = tid & 63;
  const int row0 = (l >> 4)*4, c0 = l & 15;

  // stage Ha rows -> split-bf16 A-frags (mt 0..7, kt 0..3)
  {
    const float4* src = (const float4*)(Ha + r0*HH);
    unsigned short* AFH = (unsigned short*)sm.afh;
    unsigned short* AFL = (unsigned short*)sm.afl;
#pragma unroll
    for (int i = 0; i < 8; ++i){
      int f = i*NT + tid;            // 4096 float4
      float4 v = src[f];
      int e0 = f*4, rl = e0 >> 7, k0 = e0 & 127;
      int mt = rl >> 4, kt = k0 >> 5;
      int lane = (((k0 & 31) >> 3) << 4) | (rl & 15), j0 = k0 & 7;
      size_t base = ((size_t)(mt*4 + kt)*64 + lane)*8 + j0;
      float vv[4] = {v.x, v.y, v.z, v.w};
#pragma unroll
      for (int p = 0; p < 4; ++p){
        unsigned short h_ = bf16rne(vv[p]);
        AFH[base + p] = h_;
        AFL[base + p] = bf16rne(vv[p] - bfval(h_));
      }
    }
  }
  __syncthreads();

  const uint4* BH = (const uint4*)(Fr + B3H_OFF);
  const uint4* BL = (const uint4*)(Fr + B3L_OFF);
#pragma unroll
  for (int p = 0; p < 4; ++p){
    const int nt = p*8 + w;          // pass p: 8 waves -> cols [p*128, p*128+128)
    uint4 bh[4], bl[4];
#pragma unroll
    for (int kt = 0; kt < 4; ++kt){  // taW = kt 4-7 of B3 layout
      bh[kt] = BH[(nt*8 + 4 + kt)*64 + l];
      bl[kt] = BL[(nt*8 + 4 + kt)*64 + l];
    }
    const float tb = tab[nt*16 + c0];
    f32x4 zero4 = {0.f,0.f,0.f,0.f};
    f32x4 acc[8];
#pragma unroll
    for (int mt = 0; mt < 8; ++mt) acc[mt] = zero4;
#pragma unroll
    for (int mt = 0; mt < 8; ++mt){
#pragma unroll
      for (int kt = 0; kt < 4; ++kt){
        bf16x8 ah = as_bf(sm.afh[mt][kt][l]);
        bf16x8 av = as_bf(sm.afl[mt][kt][l]);
        bf16x8 vbh = as_bf(bh[kt]);
        bf16x8 vbl = as_bf(bl[kt]);
        acc[mt] = __builtin_amdgcn_mfma_f32_16x16x32_bf16(ah, vbh, acc[mt], 0, 0, 0);
        acc[mt] = __builtin_amdgcn_mfma_f32_16x16x32_bf16(av, vbh, acc[mt], 0, 0, 0);
        acc[mt] = __builtin_amdgcn_mfma_f32_16x16x32_bf16(ah, vbl, acc[mt], 0, 0, 0);
      }
    }
    // scatter into SG (local col = w*16 + c0)
#pragma unroll
    for (int mt = 0; mt < 8; ++mt)
#pragma unroll
      for (int j = 0; j < 4; ++j)
        sm.SG[mt*16 + row0 + j][w*16 + c0] = acc[mt][j] + tb;
    __syncthreads();
    // coalesced write SG -> G0 cols [p*128, p*128+128)
#pragma unroll
    for (int it = 0; it < 8; ++it){
      int flat = it*NT + tid;        // 4096 float4 = 128 rows x 32
      int row = flat >> 5, cq = flat & 31;
      *(float4*)(G0 + (r0 + row)*NG + p*128 + cq*4) = *(const float4*)&sm.SG[row][cq*4];
    }
    __syncthreads();
  }
}

// ================= mf_ph3h: temporal LSTM, K=128 (G0-hoisted) =================
struct P3H {
  uint4 afh[4*64];     // 4K
  uint4 afl[4*64];     // 4K
  float lh[M][HH];     // 4K
  float lc[M][HH];     // 4K
  float g[M][NG];      // 16K
  float wy[NG];        // 2K
  float fcv[HH];
  float yp[M];
};
union __align__(16) SMCH { P3H s; float pad[21504]; };   // 84K -> 1 blk/CU

__global__ __launch_bounds__(NT, 2) __attribute__((amdgpu_waves_per_eu(2, 2)))
void mf_ph3h_kernel(
    const float* __restrict__ X, const unsigned short* __restrict__ Fr,
    const float* __restrict__ G0,
    const float* __restrict__ taWy,
    const float* __restrict__ fcw, const float* __restrict__ fcb,
    float* __restrict__ out)
{
  __shared__ SMCH sm;
  const int tid = threadIdx.x;
  const int b0  = blockIdx.x * M;
  const int w   = tid >> 6, l = tid & 63;
  const int row0 = (l >> 4)*4, c0 = l & 15;

  {
    uint4 z4 = make_uint4(0,0,0,0);
    if (tid < 4*64){ sm.s.afh[tid] = z4; sm.s.afl[tid] = z4; }
    for (int i = tid; i < M*HH; i += NT){
      ((float*)sm.s.lh)[i] = 0.f; ((float*)sm.s.lc)[i] = 0.f;
    }
    sm.s.wy[tid] = taWy[tid];
    if (tid < HH) sm.s.fcv[tid] = fcw[tid];
    if (tid < M)  sm.s.yp[tid] = X[(size_t)(b0+tid)*SS*DD + (DD-1)];
  }
  __syncthreads();

  for (int t = 0; t < SS; ++t){
    // ---- Q1: G0 ext prefetch + gates MFMA (K=128) ----
    {
      float g0v[16];
      if (row0 < 8){
#pragma unroll
        for (int n4 = 0; n4 < 4; ++n4){
#pragma unroll
          for (int j = 0; j < 4; ++j)
            g0v[n4*4+j] = G0[((size_t)(b0+row0+j)*SS + t)*NG + (w*64 + n4*16 + c0)];
        }
      }
      f32x4 zero4 = {0.f,0.f,0.f,0.f};
      f32x4 acc[4];
#pragma unroll
      for (int n4 = 0; n4 < 4; ++n4) acc[n4] = zero4;
      const uint4* BH = (const uint4*)(Fr + B3H_OFF);
      const uint4* BL = (const uint4*)(Fr + B3L_OFF);
#pragma unroll
      for (int kt = 0; kt < 4; ++kt){      // taU = kt 0-3
        bf16x8 ah = as_bf(sm.s.afh[kt*64 + l]);
        bf16x8 av = as_bf(sm.s.afl[kt*64 + l]);
#pragma unroll
        for (int n4 = 0; n4 < 4; ++n4){
          const int ntg = w*4 + n4;
          bf16x8 bh = as_bf(BH[(ntg*8 + kt)*64 + l]);
          bf16x8 bl = as_bf(BL[(ntg*8 + kt)*64 + l]);
          acc[n4] = __builtin_amdgcn_mfma_f32_16x16x32_bf16(ah, bh, acc[n4], 0, 0, 0);
          acc[n4] = __builtin_amdgcn_mfma_f32_16x16x32_bf16(av, bh, acc[n4], 0, 0, 0);
          acc[n4] = __builtin_amdgcn_mfma_f32_16x16x32_bf16(ah, bl, acc[n4], 0, 0, 0);
        }
      }
      if (row0 < 8){
#pragma unroll
        for (int n4 = 0; n4 < 4; ++n4){
          int col = w*64 + n4*16 + c0;
          float wv = sm.s.wy[col];
#pragma unroll
          for (int j = 0; j < 4; ++j)
            sm.s.g[row0+j][col] = acc[n4][j] + g0v[n4*4+j] + sm.s.yp[row0+j]*wv;
        }
      }
    }
    __syncthreads();

    // ---- Q2: pointwise + lh-frag build (tiles 0-3) ----
    {
      unsigned short* AFH = (unsigned short*)sm.s.afh;
      unsigned short* AFL = (unsigned short*)sm.s.afl;
#pragma unroll
      for (int h2 = 0; h2 < 2; ++h2){
        int idx = h2*NT + tid;
        int r = idx >> 7, j = idx & 127;
        float iv = sigf (sm.s.g[r][j]);
        float fv = sigf (sm.s.g[r][j + 128]);
        float gv = tanhx(sm.s.g[r][j + 256]);
        float ov = sigf (sm.s.g[r][j + 384]);
        float cn = fv * sm.s.lc[r][j] + iv * gv;
        float hn = ov * tanhx(cn);
        sm.s.lc[r][j] = cn; sm.s.lh[r][j] = hn;
        int kt = j >> 5, lane = (((j & 31) >> 3) << 4) | r, jj = j & 7;
        unsigned short h_ = bf16rne(hn);
        AFH[(kt*64 + lane)*8 + jj] = h_;
        AFL[(kt*64 + lane)*8 + jj] = bf16rne(hn - bfval(h_));
      }
    }
    __syncthreads();

    // ---- Q3: fc reduce ----
    {
      const int r = w, lx = l;
      float p = sm.s.lh[r][lx]*sm.s.fcv[lx] + sm.s.lh[r][lx+64]*sm.s.fcv[lx+64];
      p = wsum64(p);
      if (lx == 0) sm.s.yp[r] = p + fcb[0];
    }
    __syncthreads();
  }

  if (tid < M) out[b0 + tid] = sm.s.yp[tid];
}

// ================= mf_ph3full: round-9 K=256 variant (tier-2 fallback) ==========
struct P3 {
  uint4 afh[8*64];
  uint4 afl[8*64];
  float lh[M][HH];
  float lc[M][HH];
  float g[M][NG];
  float sb[NG];
  float wy[NG];
  float fcv[HH];
  float yp[M];
};
union __align__(16) SMC { P3 s; float pad[21504]; };

__global__ __launch_bounds__(NT, 2) void mf_ph3_kernel(
    const float* __restrict__ X, const float* __restrict__ Ha,
    const unsigned short* __restrict__ Fr,
    const float* __restrict__ tab, const float* __restrict__ taWy,
    const float* __restrict__ fcw, const float* __restrict__ fcb,
    float* __restrict__ out)
{
  __shared__ SMC sm;
  const int tid = threadIdx.x;
  const int b0  = blockIdx.x * M;
  const int w   = tid >> 6, l = tid & 63;

  {
    uint4 z4 = make_uint4(0,0,0,0);
    sm.s.afh[tid] = z4; sm.s.afl[tid] = z4;
    for (int i = tid; i < M*HH; i += NT){
      ((float*)sm.s.lh)[i] = 0.f; ((float*)sm.s.lc)[i] = 0.f;
    }
    sm.s.sb[tid] = tab[tid];
    sm.s.wy[tid] = taWy[tid];
    if (tid < HH) sm.s.fcv[tid] = fcw[tid];
    if (tid < M)  sm.s.yp[tid] = X[(size_t)(b0+tid)*SS*DD + (DD-1)];
  }
  __syncthreads();
  if (tid < 256){
    int r = tid >> 5, d0 = (tid & 31)*4;
    float4 v = *(const float4*)(Ha + (size_t)(b0+r)*SS*HH + d0);
    unsigned short* AFH = (unsigned short*)sm.s.afh;
    unsigned short* AFL = (unsigned short*)sm.s.afl;
    int kt = 4 + (d0 >> 5), lane = (((d0 & 31) >> 3) << 4) | r, jj0 = d0 & 7;
    float vv[4] = {v.x, v.y, v.z, v.w};
#pragma unroll
    for (int p = 0; p < 4; ++p){
      unsigned short h_ = bf16rne(vv[p]);
      AFH[(kt*64 + lane)*8 + jj0 + p] = h_;
      AFL[(kt*64 + lane)*8 + jj0 + p] = bf16rne(vv[p] - bfval(h_));
    }
  }
  __syncthreads();

  for (int t = 0; t < SS; ++t){
    float4 pf;
    const bool dop = (tid < 256) && (t + 1 < SS);
    if (dop){
      int r = tid >> 5, d0 = (tid & 31)*4;
      pf = *(const float4*)(Ha + (size_t)(b0+r)*SS*HH + (size_t)(t+1)*HH + d0);
    }
    {
      f32x4 zero4 = {0.f,0.f,0.f,0.f};
      f32x4 acc[4];
#pragma unroll
      for (int n4 = 0; n4 < 4; ++n4) acc[n4] = zero4;
      const uint4* BH = (const uint4*)(Fr + B3H_OFF);
      const uint4* BL = (const uint4*)(Fr + B3L_OFF);
#pragma unroll
      for (int kt = 0; kt < 8; ++kt){
        bf16x8 ah = as_bf(sm.s.afh[kt*64 + l]);
        bf16x8 av = as_bf(sm.s.afl[kt*64 + l]);
#pragma unroll
        for (int n4 = 0; n4 < 4; ++n4){
          const int ntg = w*4 + n4;
          bf16x8 bh = as_bf(BH[(ntg*8 + kt)*64 + l]);
          bf16x8 bl = as_bf(BL[(ntg*8 + kt)*64 + l]);
          acc[n4] = __builtin_amdgcn_mfma_f32_16x16x32_bf16(ah, bh, acc[n4], 0, 0, 0);
          acc[n4] = __builtin_amdgcn_mfma_f32_16x16x32_bf16(av, bh, acc[n4], 0, 0, 0);
          acc[n4] = __builtin_amdgcn_mfma_f32_16x16x32_bf16(ah, bl, acc[n4], 0, 0, 0);
        }
      }
      const int row0 = (l >> 4)*4;
      if (row0 < 8){
        const int colb = w*64 + (l & 15);
#pragma unroll
        for (int n4 = 0; n4 < 4; ++n4){
          int col = colb + n4*16;
          float b = sm.s.sb[col];
          float wv = sm.s.wy[col];
#pragma unroll
          for (int j = 0; j < 4; ++j)
            sm.s.g[row0+j][col] = acc[n4][j] + b + sm.s.yp[row0+j]*wv;
        }
      }
    }
    __syncthreads();

    {
      unsigned short* AFH = (unsigned short*)sm.s.afh;
      unsigned short* AFL = (unsigned short*)sm.s.afl;
#pragma unroll
      for (int h2 = 0; h2 < 2; ++h2){
        int idx = h2*NT + tid;
        int r = idx >> 7, j = idx & 127;
        float iv = sigf (sm.s.g[r][j]);
        float fv = sigf (sm.s.g[r][j + 128]);
        float gv = tanhx(sm.s.g[r][j + 256]);
        float ov = sigf (sm.s.g[r][j + 384]);
        float cn = fv * sm.s.lc[r][j] + iv * gv;
        float hn = ov * tanhx(cn);
        sm.s.lc[r][j] = cn; sm.s.lh[r][j] = hn;
        int kt = j >> 5, lane = (((j & 31) >> 3) << 4) | r, jj = j & 7;
        unsigned short h_ = bf16rne(hn);
        AFH[(kt*64 + lane)*8 + jj] = h_;
        AFL[(kt*64 + lane)*8 + jj] = bf16rne(hn - bfval(h_));
      }
    }
    __syncthreads();

    {
      const int r = w, lx = l;
      float p = sm.s.lh[r][lx]*sm.s.fcv[lx] + sm.s.lh[r][lx+64]*sm.s.fcv[lx+64];
      p = wsum64(p);
      if (lx == 0) sm.s.yp[r] = p + fcb[0];
    }
    if (dop){
      int r = tid >> 5, d0 = (tid & 31)*4;
      unsigned short* AFH = (unsigned short*)sm.s.afh;
      unsigned short* AFL = (unsigned short*)sm.s.afl;
      int kt = 4 + (d0 >> 5), lane = (((d0 & 31) >> 3) << 4) | r, jj0 = d0 & 7;
      float vv[4] = {pf.x, pf.y, pf.z, pf.w};
#pragma unroll
      for (int p = 0; p < 4; ++p){
        unsigned short h_ = bf16rne(vv[p]);
        AFH[(kt*64 + lane)*8 + jj0 + p] = h_;
        AFL[(kt*64 + lane)*8 + jj0 + p] = bf16rne(vv[p] - bfval(h_));
      }
    }
    __syncthreads();
  }

  if (tid < M) out[b0 + tid] = sm.s.yp[tid];
}

// ================= Fallback (round-3 VALU kernels, if ws tiny) ===============
struct FSM1 {
  float x[M][DD]; float h[M][HH]; float c[M][HH];
  float a[M][DD]; float xw[M][DD]; float g[M][NG];
};
struct FP1 { FSM1 s; float red[8][512]; };
union __align__(16) FSMA { FP1 p1; P2S p2; float pad[21504]; };

__global__ __launch_bounds__(NT, 2) void fb_ph12_kernel(
    const float* __restrict__ X,
    const float* __restrict__ saW,  const float* __restrict__ saU,  const float* __restrict__ sab,
    const float* __restrict__ saWa, const float* __restrict__ saUa, const float* __restrict__ saba,
    const float* __restrict__ saVa,
    const float* __restrict__ taWa, const float* __restrict__ taba, const float* __restrict__ taVa,
    float* __restrict__ out, float* __restrict__ Hws)
{
  __shared__ FSMA sm;
  const int tid = threadIdx.x;
  const int b0  = blockIdx.x * M;
  const int w   = tid >> 6, l = tid & 63;

  for (int idx = tid; idx < M*HH; idx += NT){
    int r = idx >> 7, j = idx & 127;
    sm.p1.s.h[r][j] = 0.f; sm.p1.s.c[r][j] = 0.f;
  }
  { int r = tid >> 6, d = tid & 63;
    sm.p1.s.x[r][d] = X[(size_t)(b0+r)*SS*DD + d]; }
  __syncthreads();

  for (int t = 0; t < SS; ++t){
    {
      float pr[M];
#pragma unroll
      for (int r = 0; r < M; ++r) pr[r] = 0.f;
      { const int kb = w*8;
#pragma unroll
        for (int q = 0; q < 2; ++q){
          const int k = kb + q*4;
          const float* wp = saWa + (size_t)k*DD + l;
          float w0 = wp[0], w1 = wp[DD], w2 = wp[2*DD], w3 = wp[3*DD];
#pragma unroll
          for (int r = 0; r < M; ++r){
            float4 v = *(const float4*)&sm.p1.s.x[r][k];
            pr[r] += w0*v.x + w1*v.y + w2*v.z + w3*v.w;
          }
        }
      }
      { const int kb = w*16;
#pragma unroll
        for (int q = 0; q < 4; ++q){
          const int k = kb + q*4;
          const float* wp = saUa + (size_t)k*DD + l;
          float w0 = wp[0], w1 = wp[DD], w2 = wp[2*DD], w3 = wp[3*DD];
#pragma unroll
          for (int r = 0; r < M; ++r){
            float4 v = *(const float4*)&sm.p1.s.h[r][k];
            pr[r] += w0*v.x + w1*v.y + w2*v.z + w3*v.w;
          }
        }
      }
      { const int kb = w*16;
#pragma unroll
        for (int q = 0; q < 4; ++q){
          const int k = kb + q*4;
          const float* wp = saUa + (size_t)(HH + k)*DD + l;
          float w0 = wp[0], w1 = wp[DD], w2 = wp[2*DD], w3 = wp[3*DD];
#pragma unroll
          for (int r = 0; r < M; ++r){
            float4 v = *(const float4*)&sm.p1.s.c[r][k];
            pr[r] += w0*v.x + w1*v.y + w2*v.z + w3*v.w;
          }
        }
      }
#pragma unroll
      for (int r = 0; r < M; ++r) sm.p1.red[w][r*64 + l] = pr[r];
    }
    __syncthreads();
    {
      float s = saba[l];
#pragma unroll
      for (int u = 0; u < 8; ++u) s += sm.p1.red[u][w*64 + l];
      sm.p1.s.a[w][l] = tanhx(s);
    }
    __syncthreads();
    {
      float pr[M];
#pragma unroll
      for (int r = 0; r < M; ++r) pr[r] = 0.f;
      const int kb = w*8;
#pragma unroll
      for (int q = 0; q < 2; ++q){
        const int k = kb + q*4;
        const float* wp = saVa + (size_t)k*DD + l;
        float w0 = wp[0], w1 = wp[DD], w2 = wp[2*DD], w3 = wp[3*DD];
#pragma unroll
        for (int r = 0; r < M; ++r){
          float4 v = *(const float4*)&sm.p1.s.a[r][k];
          pr[r] += w0*v.x + w1*v.y + w2*v.z + w3*v.w;
        }
      }
#pragma unroll
      for (int r = 0; r < M; ++r) sm.p1.red[w][r*64 + l] = pr[r];
    }
    __syncthreads();
    {
      float s = 0.f;
#pragma unroll
      for (int u = 0; u < 8; ++u) s += sm.p1.red[u][w*64 + l];
      float mm = wmax64(s);
      float e  = __expf(s - mm);
      float al = e * (1.0f / wsum64(e));
      out[A_OFF + (size_t)t*BB*DD + (size_t)(b0+w)*DD + l] = al;
      sm.p1.s.xw[w][l] = al * sm.p1.s.x[w][l];
    }
    __syncthreads();
    {
      const int c0 = tid;
      float acc[M];
      const float bv = sab[c0];
#pragma unroll
      for (int r = 0; r < M; ++r) acc[r] = bv;
      for (int k = 0; k < DD; k += 4){
        const float* wp = saW + (size_t)k*NG + c0;
        float w0 = wp[0], w1 = wp[NG], w2 = wp[2*NG], w3 = wp[3*NG];
#pragma unroll
        for (int r = 0; r < M; ++r){
          float4 v = *(const float4*)&sm.p1.s.xw[r][k];
          acc[r] += w0*v.x + w1*v.y + w2*v.z + w3*v.w;
        }
      }
      for (int k = 0; k < HH; k += 4){
        const float* wp = saU + (size_t)k*NG + c0;
        float w0 = wp[0], w1 = wp[NG], w2 = wp[2*NG], w3 = wp[3*NG];
#pragma unroll
        for (int r = 0; r < M; ++r){
          float4 v = *(const float4*)&sm.p1.s.h[r][k];
          acc[r] += w0*v.x + w1*v.y + w2*v.z + w3*v.w;
        }
      }
#pragma unroll
      for (int r = 0; r < M; ++r) sm.p1.s.g[r][c0] = acc[r];
    }
    __syncthreads();
    for (int idx = tid; idx < M*HH; idx += NT){
      int r = idx >> 7, j = idx & 127;
      float iv = sigf (sm.p1.s.g[r][j]);
      float fv = sigf (sm.p1.s.g[r][j +   HH]);
      float gv = tanhx(sm.p1.s.g[r][j + 2*HH]);
      float ov = sigf (sm.p1.s.g[r][j + 3*HH]);
      float cn = fv * sm.p1.s.c[r][j] + iv * gv;
      float hn = ov * tanhx(cn);
      sm.p1.s.c[r][j] = cn; sm.p1.s.h[r][j] = hn;
      Hws[(size_t)(b0+r)*SS*HH + (size_t)t*HH + j] = hn;
    }
    if (t + 1 < SS){
      int r = tid >> 6, d = tid & 63;
      sm.p1.s.x[r][d] = X[(size_t)(b0+r)*SS*DD + (size_t)(t+1)*DD + d];
    }
    __syncthreads();
  }

  for (int r = 0; r < M; ++r){
    float* Hrow = Hws + (size_t)(b0+r)*SS*HH;
    const int c  = tid & 127;
    const int th = tid >> 7;
    float hacc[32];
#pragma unroll
    for (int i = 0; i < 32; ++i) hacc[i] = 0.f;
#pragma unroll
    for (int ch = 0; ch < 4; ++ch){
      for (int idx = tid; idx < 32*HH/4; idx += NT)
        ((float4*)sm.p2.A)[idx] = ((const float4*)(Hrow + (size_t)ch*32*HH))[idx];
      __syncthreads();
      { float acc[8];
        const float bv = taba[c];
#pragma unroll
        for (int i = 0; i < 8; ++i) acc[i] = bv;
        for (int k = 0; k < HH; k += 4){
          const float* wp = taWa + (size_t)k*SS + c;
          float w0 = wp[0], w1 = wp[SS], w2 = wp[2*SS], w3 = wp[3*SS];
#pragma unroll
          for (int i = 0; i < 8; ++i){
            float4 v = *(const float4*)&sm.p2.A[th*8+i][k];
            acc[i] += w0*v.x + w1*v.y + w2*v.z + w3*v.w;
          }
        }
#pragma unroll
        for (int i = 0; i < 8; ++i) sm.p2.tmp[th*8+i][c] = tanhx(acc[i]);
      }
      __syncthreads();
      { float acc[8];
#pragma unroll
        for (int i = 0; i < 8; ++i) acc[i] = 0.f;
        for (int k = 0; k < SS; k += 4){
          const float* wp = taVa + (size_t)k*SS + c;
          float w0 = wp[0], w1 = wp[SS], w2 = wp[2*SS], w3 = wp[3*SS];
#pragma unroll
          for (int i = 0; i < 8; ++i){
            float4 v = *(const float4*)&sm.p2.tmp[th*8+i][k];
            acc[i] += w0*v.x + w1*v.y + w2*v.z + w3*v.w;
          }
        }
#pragma unroll
        for (int i = 0; i < 8; ++i) sm.p2.bp[th*8+i][c] = acc[i];
      }
      __syncthreads();
      { const int wv = tid >> 6, lane = tid & 63;
#pragma unroll
        for (int it = 0; it < 4; ++it){
          int tl = wv + 8*it;
          float v0 = sm.p2.bp[tl][lane], v1 = sm.p2.bp[tl][lane+64];
          float mm = wmax64(fmaxf(v0, v1));
          float e0 = __expf(v0 - mm), e1 = __expf(v1 - mm);
          float inv = 1.0f / wsum64(e0 + e1);
          e0 *= inv; e1 *= inv;
          size_t bo = BETA_OFF + (size_t)(ch*32+tl)*BB*SS + (size_t)(b0+r)*SS;
          out[bo + lane]      = e0;
          out[bo + lane + 64] = e1;
          sm.p2.bp[tl][lane]      = e0;
          sm.p2.bp[tl][lane + 64] = e1;
        }
      }
      __syncthreads();
      for (int k = 0; k < SS; k += 4){
        const float* hp = Hrow + (size_t)k*HH + c;
        float hv0 = hp[0], hv1 = hp[HH], hv2 = hp[2*HH], hv3 = hp[3*HH];
#pragma unroll
        for (int i = 0; i < 8; ++i){
          float4 bv = *(const float4*)&sm.p2.bp[th*8+i][k];
          hacc[ch*8+i] += bv.x*hv0 + bv.y*hv1 + bv.z*hv2 + bv.w*hv3;
        }
      }
    }
    __syncthreads();
#pragma unroll
    for (int ch = 0; ch < 4; ++ch)
#pragma unroll
      for (int i = 0; i < 8; ++i)
        Hrow[(size_t)(ch*32 + th*8 + i)*HH + c] = hacc[ch*8+i];
    __syncthreads();
  }
}

__global__ __launch_bounds__(NT, 2) void fb_ph3_kernel(
    const float* __restrict__ X, const float* __restrict__ Ha,
    const float* __restrict__ taW, const float* __restrict__ taU,
    const float* __restrict__ tab, const float* __restrict__ taWy,
    const float* __restrict__ fcw, const float* __restrict__ fcb,
    float* __restrict__ out)
{
  __shared__ struct {
    float ha[M][HH]; float lh[M][HH]; float lc[M][HH];
    float g[M][NG];  float yp[M];
  } s;
  const int tid = threadIdx.x;
  const int b0  = blockIdx.x * M;

  for (int idx = tid; idx < M*HH; idx += NT){
    int r = idx >> 7, j = idx & 127;
    s.lh[r][j] = 0.f; s.lc[r][j] = 0.f;
  }
  if (tid < M) s.yp[tid] = X[(size_t)(b0+tid)*SS*DD + (DD-1)];
  if (tid < M*HH/4){
    int r = tid >> 5, q = tid & 31;
    ((float4*)s.ha)[tid] = *(const float4*)(Ha + (size_t)(b0+r)*SS*HH + q*4);
  }
  __syncthreads();

  for (int t = 0; t < SS; ++t){
    {
      const int c0 = tid;
      const float wy = taWy[c0];
      const float tb = tab[c0];
      float acc[M];
#pragma unroll
      for (int r = 0; r < M; ++r) acc[r] = tb + s.yp[r]*wy;
      for (int k = 0; k < HH; k += 4){
        const float* wp = taW + (size_t)k*NG + c0;
        float a0 = wp[0], a1 = wp[NG], a2 = wp[2*NG], a3 = wp[3*NG];
#pragma unroll
        for (int r = 0; r < M; ++r){
          float4 v = *(const float4*)&s.ha[r][k];
          acc[r] += a0*v.x + a1*v.y + a2*v.z + a3*v.w;
        }
      }
      for (int k = 0; k < HH; k += 4){
        const float* wp = taU + (size_t)k*NG + c0;
        float a0 = wp[0], a1 = wp[NG], a2 = wp[2*NG], a3 = wp[3*NG];
#pragma unroll
        for (int r = 0; r < M; ++r){
          float4 v = *(const float4*)&s.lh[r][k];
          acc[r] += a0*v.x + a1*v.y + a2*v.z + a3*v.w;
        }
      }
#pragma unroll
      for (int r = 0; r < M; ++r) s.g[r][c0] = acc[r];
    }
    __syncthreads();
    for (int idx = tid; idx < M*HH; idx += NT){
      int r = idx >> 7, j = idx & 127;
      float iv = sigf (s.g[r][j]);
      float fv = sigf (s.g[r][j +   HH]);
      float gv = tanhx(s.g[r][j + 2*HH]);
      float ov = sigf (s.g[r][j + 3*HH]);
      float cn = fv * s.lc[r][j] + iv * gv;
      float hn = ov * tanhx(cn);
      s.lc[r][j] = cn; s.lh[r][j] = hn;
    }
    if (t + 1 < SS && tid < M*HH/4){
      int r = tid >> 5, q = tid & 31;
      ((float4*)s.ha)[tid] =
        *(const float4*)(Ha + (size_t)(b0+r)*SS*HH + (size_t)(t+1)*HH + q*4);
    }
    __syncthreads();
    {
      const int r = tid >> 6, lx = tid & 63;
      float p = s.lh[r][lx]*fcw[lx] + s.lh[r][lx+64]*fcw[lx+64];
      p = wsum64(p);
      if (lx == 0) s.yp[r] = p + fcb[0];
    }
    __syncthreads();
  }
  if (tid < M) out[b0 + tid] = s.yp[tid];
}

extern "C" void kernel_launch(void* const* d_in, const int* in_sizes, int n_in,
                              void* d_out, int out_size, void* d_ws, size_t ws_size,
                              hipStream_t stream) {
  (void)in_sizes; (void)n_in; (void)out_size;
  const float* X    = (const float*)d_in[0];
  const float* saW  = (const float*)d_in[1];
  const float* saU  = (const float*)d_in[2];
  const float* sab  = (const float*)d_in[3];
  const float* saWa = (const float*)d_in[4];
  const float* saUa = (const float*)d_in[5];
  const float* saba = (const float*)d_in[6];
  const float* saVa = (const float*)d_in[7];
  const float* taWa = (const float*)d_in[8];
  // d_in[9] = ta_Ua: unused by the reference forward pass
  const float* taba = (const float*)d_in[10];
  const float* taVa = (const float*)d_in[11];
  const float* taW  = (const float*)d_in[12];
  const float* taU  = (const float*)d_in[13];
  const float* tab  = (const float*)d_in[14];
  const float* taWy = (const float*)d_in[15];
  const float* fcw  = (const float*)d_in[16];
  const float* fcb  = (const float*)d_in[17];
  float* out = (float*)d_out;

  if (ws_size >= NEED2_BYTES){
    unsigned short* Fr = (unsigned short*)d_ws;
    float* Hws = (float*)((char*)d_ws + FRAG_BYTES);
    hipLaunchKernelGGL(repack_kernel, dim3(512), dim3(256), 0, stream,
                       saW, saU, saWa, saUa, saVa, taU, taW, taWa, taVa, Fr);
    hipLaunchKernelGGL(mf_ph1_kernel, dim3(BB / M), dim3(NT), 0, stream,
                       X, sab, saba, Fr, out, Hws);
    hipLaunchKernelGGL(ph2_kernel, dim3(BB), dim3(NT), 0, stream,
                       taba, Fr, out, Hws);
    if (ws_size >= NEED3_BYTES){
      float* G0 = (float*)((char*)d_ws + FRAG_BYTES + H_BYTES);
      hipLaunchKernelGGL(g0mm_kernel, dim3((BB*SS)/128), dim3(NT), 0, stream,
                         Hws, Fr, tab, G0);
      hipLaunchKernelGGL(mf_ph3h_kernel, dim3(BB / M), dim3(NT), 0, stream,
                         X, Fr, G0, taWy, fcw, fcb, out);
    } else {
      hipLaunchKernelGGL(mf_ph3_kernel, dim3(BB / M), dim3(NT), 0, stream,
                         X, Hws, Fr, tab, taWy, fcw, fcb, out);
    }
  } else {
    float* Hws = (float*)d_ws;
    hipLaunchKernelGGL(fb_ph12_kernel, dim3(BB / M), dim3(NT), 0, stream,
                       X, saW, saU, sab, saWa, saUa, saba, saVa,
                       taWa, taba, taVa, out, Hws);
    hipLaunchKernelGGL(fb_ph3_kernel, dim3(BB / M), dim3(NT), 0, stream,
                       X, Hws, taW, taU, tab, taWy, fcw, fcb, out);
  }
}

// Round 13
// 1431.643 us; speedup vs baseline: 2.0397x; 1.1320x over previous
//
#include <hip/hip_runtime.h>

// STA-LSTM forward: B=2048, S=128, D=64, H1=H2=128, OUT=1
// Round 13:
//  1. mf_ph1: attention B-frags + Va cached in LDS (one-time, 96KB; total 152KB,
//     still 1 blk/CU). P1-attn and P3 become LDS-only.
//  2. ph2g: g0mm fused into ph2 — h_att staged split-bf16 in LDS, G0 GEMM done
//     in-place (split x split, 8 passes, SG staging), G0 written coalesced.
//     h_att never touches global in tier-3.
//  3. mf_ph3h: G0 loads for t+1 issued at top of Q2 (loop-carried registers).
// Kernels: repack -> mf_ph1 -> ph2g -> mf_ph3h     (full tier)
//          repack -> mf_ph1 -> ph2  -> mf_ph3full  (if ws lacks G0 space)
//          fb_* VALU kernels                        (if ws < 130 MB)
// NOTE: NT=512 + launch_bounds(512,2)/waves_per_eu(2,2) is the ONLY config that
// reliably avoids spills (NT=1024 variants collapse to VGPR=64 + scratch).
// NOTE: MFMA-fragment register->global scalar stores cause ~6x write
// amplification — always stage through LDS and emit >=256B dense segments.

#define BB 2048
#define SS 128
#define DD 64
#define HH 128
#define NG 512
#define M  8
#define NT 512

#define A_OFF    ((size_t)BB)
#define BETA_OFF ((size_t)BB + (size_t)SS*BB*DD)
#define H_BYTES  ((size_t)BB*SS*HH*4)
#define G0_BYTES ((size_t)BB*SS*NG*4)

// fragment buffer layout in ws (ushort offsets)
#define B1G_ELEMS (192*512)
#define B1A_ELEMS (320*64)
#define BVA_ELEMS (64*64)
#define B3_ELEMS  (256*512)
#define BW_ELEMS  (128*128)
#define GH_OFF 0
#define GL_OFF (B1G_ELEMS)
#define AH_OFF (2*B1G_ELEMS)
#define AL_OFF (2*B1G_ELEMS + B1A_ELEMS)
#define VH_OFF (2*B1G_ELEMS + 2*B1A_ELEMS)
#define VL_OFF (VH_OFF + BVA_ELEMS)
#define B3H_OFF (VH_OFF + 2*BVA_ELEMS)
#define B3L_OFF (B3H_OFF + B3_ELEMS)
#define RW_OFF  (B3H_OFF + 2*B3_ELEMS)
#define RV_OFF  (RW_OFF + BW_ELEMS)
#define FRAG_BYTES ((size_t)(RV_OFF + BW_ELEMS)*2)
#define NEED2_BYTES (FRAG_BYTES + H_BYTES)
#define NEED3_BYTES (FRAG_BYTES + H_BYTES + G0_BYTES)

typedef float f32x4 __attribute__((ext_vector_type(4)));
typedef __bf16 bf16x8 __attribute__((ext_vector_type(8)));
union FB { uint4 u; bf16x8 v; };
__device__ __forceinline__ bf16x8 as_bf(uint4 u){ FB x; x.u = u; return x.v; }

__device__ __forceinline__ unsigned short bf16rne(float f){
  unsigned u = __float_as_uint(f);
  u = (u + 0x7FFFu + ((u >> 16) & 1u)) >> 16;
  return (unsigned short)u;
}
__device__ __forceinline__ float bfval(unsigned short h){
  return __uint_as_float(((unsigned)h) << 16);
}

__device__ __forceinline__ float sigf(float x){ return 1.0f/(1.0f + __expf(-x)); }
__device__ __forceinline__ float tanhx(float x){ return 1.0f - 2.0f/(1.0f + __expf(2.0f*x)); }

__device__ __forceinline__ float wmax64(float v){
#pragma unroll
  for (int m = 32; m; m >>= 1) v = fmaxf(v, __shfl_xor(v, m, 64));
  return v;
}
__device__ __forceinline__ float wsum64(float v){
#pragma unroll
  for (int m = 32; m; m >>= 1) v += __shfl_xor(v, m, 64);
  return v;
}

// ================= repack: weights -> fragment-ordered buffers =================
__global__ __launch_bounds__(256) void repack_kernel(
    const float* __restrict__ saW, const float* __restrict__ saU,
    const float* __restrict__ saWa, const float* __restrict__ saUa,
    const float* __restrict__ saVa,
    const float* __restrict__ taU, const float* __restrict__ taW,
    const float* __restrict__ taWa, const float* __restrict__ taVa,
    unsigned short* __restrict__ F)
{
  int id = blockIdx.x*256 + threadIdx.x;
  if (id < B1G_ELEMS){          // gate: k 0-127 = saU(h), 128-191 = saW(xw)
    int k = id >> 9, n = id & 511;
    float v = (k < 128) ? saU[(size_t)k*NG + n] : saW[(size_t)(k-128)*NG + n];
    int kk = k >> 5, kw = k & 31, nt = n >> 4, nc = n & 15;
    int lane = ((kw >> 3) << 4) | nc, j = kw & 7;
    size_t off = ((size_t)(nt*6 + kk)*64 + lane)*8 + j;
    unsigned short hi = bf16rne(v);
    F[GH_OFF + off] = hi; F[GL_OFF + off] = bf16rne(v - bfval(hi));
  }
  if (id < B1A_ELEMS){          // attn: k 0-255 = saUa(h,c), 256-319 = saWa(x)
    int k = id >> 6, n = id & 63;
    float v = (k < 256) ? saUa[(size_t)k*DD + n] : saWa[(size_t)(k-256)*DD + n];
    int kt = k >> 5, kw = k & 31, nt = n >> 4, nc = n & 15;
    int lane = ((kw >> 3) << 4) | nc, j = kw & 7;
    size_t off = ((size_t)(nt*10 + kt)*64 + lane)*8 + j;
    unsigned short hi = bf16rne(v);
    F[AH_OFF + off] = hi; F[AL_OFF + off] = bf16rne(v - bfval(hi));
  }
  if (id < BVA_ELEMS){          // saVa 64x64
    int k = id >> 6, n = id & 63;
    float v = saVa[(size_t)k*DD + n];
    int kt = k >> 5, kw = k & 31, nt = n >> 4, nc = n & 15;
    int lane = ((kw >> 3) << 4) | nc, j = kw & 7;
    size_t off = ((size_t)(nt*2 + kt)*64 + lane)*8 + j;
    unsigned short hi = bf16rne(v);
    F[VH_OFF + off] = hi; F[VL_OFF + off] = bf16rne(v - bfval(hi));
  }
  if (id < B3_ELEMS){           // ph3: k 0-127 = taU(lh), 128-255 = taW(ha)
    int k = id >> 9, n = id & 511;
    float v = (k < HH) ? taU[(size_t)k*NG + n] : taW[(size_t)(k-HH)*NG + n];
    int kt = k >> 5, kw = k & 31, nt = n >> 4, nc = n & 15;
    int lane = ((kw >> 3) << 4) | nc, j = kw & 7;
    size_t off = ((size_t)(nt*8 + kt)*64 + lane)*8 + j;
    unsigned short hi = bf16rne(v);
    F[B3H_OFF + off] = hi; F[B3L_OFF + off] = bf16rne(v - bfval(hi));
  }
  if (id < BW_ELEMS){           // ph2 bf16 frags
    int k = id >> 7, n = id & 127;
    int kt = k >> 5, kw = k & 31, nt = n >> 4, nc = n & 15;
    int lane = ((kw >> 3) << 4) | nc, j = kw & 7;
    size_t off = ((size_t)(nt*4 + kt)*64 + lane)*8 + j;
    F[RW_OFF + off] = bf16rne(taWa[(size_t)k*SS + n]);
    F[RV_OFF + off] = bf16rne(taVa[(size_t)k*SS + n]);
  }
}

// ================= mf_ph1: spatial-attn LSTM, fully MFMA =================
// af tiles: 0-3 h, 4-7 c, 8-9 x (attn A, K=320); {0-3 h, 10-11 xw} = gate A.
// Attn B + Va cached in LDS (one-time); gate B streamed from L2.
struct P1 {
  uint4 afh[12*64];    // 12K
  uint4 afl[12*64];    // 12K
  uint4 aah[2*64];     // 2K
  uint4 aal[2*64];     // 2K
  uint4 awh[2560];     // 40K  attn B hi (4 nt x 10 kt x 64)
  uint4 awl[2560];     // 40K  attn B lo
  uint4 vh[512];       // 8K   Va hi (4 nt x 2 kt x 64)
  uint4 vl[512];       // 8K   Va lo
  float xx[M][DD];     // 2K
  float cc[M][HH];     // 4K
  float red[2][M][64]; // 4K
  float g[M][NG];      // 16K
  float sbias[NG];     // 2K
};                     // 152K -> 1 blk/CU
struct P2S { float A[32][HH]; float tmp[32][SS]; float bp[32][SS]; };  // fallback

__global__ __launch_bounds__(NT, 2) __attribute__((amdgpu_waves_per_eu(2, 2)))
void mf_ph1_kernel(
    const float* __restrict__ X,   const float* __restrict__ sab,
    const float* __restrict__ saba,
    const unsigned short* __restrict__ Fr,
    float* __restrict__ out, float* __restrict__ Hws)
{
  __shared__ P1 sm;
  const int tid = threadIdx.x;
  const int b0  = blockIdx.x * M;
  const int w   = tid >> 6, l = tid & 63;

  {
    uint4 z4 = make_uint4(0,0,0,0);
    for (int i = tid; i < 12*64; i += NT){ sm.afh[i] = z4; sm.afl[i] = z4; }
    if (tid < 2*64){ sm.aah[tid] = z4; sm.aal[tid] = z4; }
    for (int i = tid; i < M*HH; i += NT) ((float*)sm.cc)[i] = 0.f;
    sm.sbias[tid] = sab[tid];
    // one-time: attn B + Va frags -> LDS
    const uint4* sh = (const uint4*)(Fr + AH_OFF);
    const uint4* sl = (const uint4*)(Fr + AL_OFF);
    for (int i = tid; i < 2560; i += NT){ sm.awh[i] = sh[i]; sm.awl[i] = sl[i]; }
    sm.vh[tid] = ((const uint4*)(Fr + VH_OFF))[tid];
    sm.vl[tid] = ((const uint4*)(Fr + VL_OFF))[tid];
  }
  __syncthreads();
  if (tid < 128){   // x(0) + x-frags (tiles 8-9)
    int r = tid >> 4, d0 = (tid & 15)*4;
    float4 v = *(const float4*)(X + (size_t)(b0+r)*SS*DD + d0);
    *(float4*)&sm.xx[r][d0] = v;
    unsigned short* AFH = (unsigned short*)sm.afh;
    unsigned short* AFL = (unsigned short*)sm.afl;
    int kt = 8 + (d0 >> 5), lane = (((d0 & 31) >> 3) << 4) | r, jj0 = d0 & 7;
    float vv[4] = {v.x, v.y, v.z, v.w};
#pragma unroll
    for (int p = 0; p < 4; ++p){
      unsigned short h_ = bf16rne(vv[p]);
      AFH[(kt*64 + lane)*8 + jj0 + p] = h_;
      AFL[(kt*64 + lane)*8 + jj0 + p] = bf16rne(vv[p] - bfval(h_));
    }
  }
  __syncthreads();

  for (int t = 0; t < SS; ++t){
    // ---- P1: attn MFMA (B from LDS) -> red  +  gate-h MFMA (kk0-3) -> accg ----
    f32x4 accg[4];
    {
      f32x4 zf = {0.f,0.f,0.f,0.f};
#pragma unroll
      for (int n4 = 0; n4 < 4; ++n4) accg[n4] = zf;
    }
    {
      const int nt = w & 3, kh = w >> 2;
      f32x4 a0 = {0.f,0.f,0.f,0.f}, a1 = {0.f,0.f,0.f,0.f};
#pragma unroll
      for (int q = 0; q < 5; ++q){
        const int kt = kh*5 + q;
        bf16x8 ah = as_bf(sm.afh[kt*64 + l]);
        bf16x8 av = as_bf(sm.afl[kt*64 + l]);
        bf16x8 bh = as_bf(sm.awh[(nt*10 + kt)*64 + l]);
        bf16x8 bl = as_bf(sm.awl[(nt*10 + kt)*64 + l]);
        if (q & 1){
          a1 = __builtin_amdgcn_mfma_f32_16x16x32_bf16(ah, bh, a1, 0, 0, 0);
          a1 = __builtin_amdgcn_mfma_f32_16x16x32_bf16(av, bh, a1, 0, 0, 0);
          a1 = __builtin_amdgcn_mfma_f32_16x16x32_bf16(ah, bl, a1, 0, 0, 0);
        } else {
          a0 = __builtin_amdgcn_mfma_f32_16x16x32_bf16(ah, bh, a0, 0, 0, 0);
          a0 = __builtin_amdgcn_mfma_f32_16x16x32_bf16(av, bh, a0, 0, 0, 0);
          a0 = __builtin_amdgcn_mfma_f32_16x16x32_bf16(ah, bl, a0, 0, 0, 0);
        }
      }
      f32x4 acc = a0 + a1;
      const int row0 = (l >> 4)*4, c0 = l & 15;
      if (row0 < 8){
#pragma unroll
        for (int jj = 0; jj < 4; ++jj)
          sm.red[kh][row0+jj][nt*16 + c0] = acc[jj];
      }
      // gate-h part (B from L2; results stay in accg)
      const uint4* GH = (const uint4*)(Fr + GH_OFF);
      const uint4* GL = (const uint4*)(Fr + GL_OFF);
#pragma unroll
      for (int kk = 0; kk < 4; ++kk){
        bf16x8 ah = as_bf(sm.afh[kk*64 + l]);
        bf16x8 av = as_bf(sm.afl[kk*64 + l]);
#pragma unroll
        for (int n4 = 0; n4 < 4; ++n4){
          const int ntg = w*4 + n4;
          bf16x8 bh = as_bf(GH[(ntg*6 + kk)*64 + l]);
          bf16x8 bl = as_bf(GL[(ntg*6 + kk)*64 + l]);
          accg[n4] = __builtin_amdgcn_mfma_f32_16x16x32_bf16(ah, bh, accg[n4], 0, 0, 0);
          accg[n4] = __builtin_amdgcn_mfma_f32_16x16x32_bf16(av, bh, accg[n4], 0, 0, 0);
          accg[n4] = __builtin_amdgcn_mfma_f32_16x16x32_bf16(ah, bl, accg[n4], 0, 0, 0);
        }
      }
    }
    __syncthreads();

    // ---- P2: combine + bias + tanh -> a-frags ----
    {
      const int r = w, col = l;
      float s = sm.red[0][r][col] + sm.red[1][r][col] + saba[col];
      float av = tanhx(s);
      unsigned short h_ = bf16rne(av);
      int kt = col >> 5, lane = (((col & 31) >> 3) << 4) | r, jj = col & 7;
      ((unsigned short*)sm.aah)[(kt*64 + lane)*8 + jj] = h_;
      ((unsigned short*)sm.aal)[(kt*64 + lane)*8 + jj] = bf16rne(av - bfval(h_));
    }
    __syncthreads();

    // ---- P3: GEMM2 MFMA  av = a @ saVa  (all LDS) ----
    {
      const int nt = w & 3, kt = w >> 2;   // kt 0-1
      f32x4 acc = {0.f,0.f,0.f,0.f};
      bf16x8 ah = as_bf(sm.aah[kt*64 + l]);
      bf16x8 av = as_bf(sm.aal[kt*64 + l]);
      bf16x8 bh = as_bf(sm.vh[(nt*2 + kt)*64 + l]);
      bf16x8 bl = as_bf(sm.vl[(nt*2 + kt)*64 + l]);
      acc = __builtin_amdgcn_mfma_f32_16x16x32_bf16(ah, bh, acc, 0, 0, 0);
      acc = __builtin_amdgcn_mfma_f32_16x16x32_bf16(av, bh, acc, 0, 0, 0);
      acc = __builtin_amdgcn_mfma_f32_16x16x32_bf16(ah, bl, acc, 0, 0, 0);
      const int row0 = (l >> 4)*4, c0 = l & 15;
      if (row0 < 8){
#pragma unroll
        for (int jj = 0; jj < 4; ++jj)
          sm.red[kt][row0+jj][nt*16 + c0] = acc[jj];
      }
    }
    __syncthreads();

    // ---- P4: softmax + alphas out + xw-frags (tiles 10-11) ----
    {
      const int r = w, col = l;
      float s = sm.red[0][r][col] + sm.red[1][r][col];
      float mm = wmax64(s);
      float e  = __expf(s - mm);
      float alv = e * (1.0f / wsum64(e));
      out[A_OFF + (size_t)t*BB*DD + (size_t)(b0+r)*DD + col] = alv;
      float xwv = alv * sm.xx[r][col];
      unsigned short h_ = bf16rne(xwv);
      int kt = 10 + (col >> 5), lane = (((col & 31) >> 3) << 4) | r, jj = col & 7;
      ((unsigned short*)sm.afh)[(kt*64 + lane)*8 + jj] = h_;
      ((unsigned short*)sm.afl)[(kt*64 + lane)*8 + jj] = bf16rne(xwv - bfval(h_));
    }
    __syncthreads();

    // ---- P5: gates xw-part (kk4-5) + x(t+1) prefetch issue ----
    float4 pf;
    const bool dox = (tid < 128) && (t + 1 < SS);
    if (dox){
      int r = tid >> 4, d0 = (tid & 15)*4;
      pf = *(const float4*)(X + (size_t)(b0+r)*SS*DD + (size_t)(t+1)*DD + d0);
    }
    {
      const uint4* GH = (const uint4*)(Fr + GH_OFF);
      const uint4* GL = (const uint4*)(Fr + GL_OFF);
#pragma unroll
      for (int kk = 4; kk < 6; ++kk){
        const int afi = kk + 6;   // 10, 11
        bf16x8 ah = as_bf(sm.afh[afi*64 + l]);
        bf16x8 av = as_bf(sm.afl[afi*64 + l]);
#pragma unroll
        for (int n4 = 0; n4 < 4; ++n4){
          const int ntg = w*4 + n4;
          bf16x8 bh = as_bf(GH[(ntg*6 + kk)*64 + l]);
          bf16x8 bl = as_bf(GL[(ntg*6 + kk)*64 + l]);
          accg[n4] = __builtin_amdgcn_mfma_f32_16x16x32_bf16(ah, bh, accg[n4], 0, 0, 0);
          accg[n4] = __builtin_amdgcn_mfma_f32_16x16x32_bf16(av, bh, accg[n4], 0, 0, 0);
          accg[n4] = __builtin_amdgcn_mfma_f32_16x16x32_bf16(ah, bl, accg[n4], 0, 0, 0);
        }
      }
      const int row0 = (l >> 4)*4, c0 = l & 15;
      if (row0 < 8){
#pragma unroll
        for (int n4 = 0; n4 < 4; ++n4){
          int col = w*64 + n4*16 + c0;
          float b = sm.sbias[col];
#pragma unroll
          for (int jj = 0; jj < 4; ++jj)
            sm.g[row0+jj][col] = accg[n4][jj] + b;
        }
      }
    }
    __syncthreads();

    // ---- P6: pointwise + h/c frag build + H store + x(t+1) commit ----
    {
      unsigned short* AFH = (unsigned short*)sm.afh;
      unsigned short* AFL = (unsigned short*)sm.afl;
#pragma unroll
      for (int h2 = 0; h2 < 2; ++h2){
        int idx = h2*NT + tid;
        int r = idx >> 7, j = idx & 127;
        float iv = sigf (sm.g[r][j]);
        float fv = sigf (sm.g[r][j + 128]);
        float gv = tanhx(sm.g[r][j + 256]);
        float ov = sigf (sm.g[r][j + 384]);
        float cn = fv * sm.cc[r][j] + iv * gv;
        float hn = ov * tanhx(cn);
        sm.cc[r][j] = cn;
        Hws[(size_t)(b0+r)*SS*HH + (size_t)t*HH + j] = hn;
        int lane = (((j & 31) >> 3) << 4) | r, jj = j & 7;
        int ktH = j >> 5, ktC = 4 + (j >> 5);
        unsigned short hh_ = bf16rne(hn);
        unsigned short ch_ = bf16rne(cn);
        AFH[(ktH*64 + lane)*8 + jj] = hh_;
        AFL[(ktH*64 + lane)*8 + jj] = bf16rne(hn - bfval(hh_));
        AFH[(ktC*64 + lane)*8 + jj] = ch_;
        AFL[(ktC*64 + lane)*8 + jj] = bf16rne(cn - bfval(ch_));
      }
      if (dox){
        int r = tid >> 4, d0 = (tid & 15)*4;
        *(float4*)&sm.xx[r][d0] = pf;
        int kt = 8 + (d0 >> 5), lane = (((d0 & 31) >> 3) << 4) | r, jj0 = d0 & 7;
        float vv[4] = {pf.x, pf.y, pf.z, pf.w};
#pragma unroll
        for (int p = 0; p < 4; ++p){
          unsigned short h_ = bf16rne(vv[p]);
          AFH[(kt*64 + lane)*8 + jj0 + p] = h_;
          AFL[(kt*64 + lane)*8 + jj0 + p] = bf16rne(vv[p] - bfval(h_));
        }
      }
    }
    __syncthreads();
  }
}

// ================= ph2g: betas + h_att + G0, all-MFMA, fused (tier-3) ==========
// Block b: betas from H[b], then G0[b][t][:] = h_att @ taW + tab (split x split).
// h_att never written to global.
struct PH2G {
  union { unsigned short S[128][136]; float SG[128][68]; } u1;  // 34.8K
  unsigned short S2[128][136];  // 34.8K  (h_att lo staging)
  uint4 fA[8][4][64];           // 32K   (A-frags hi; reused across stages)
  uint4 fB[8][4][64];           // 32K   (H B-frags; later h_att A-frags lo)
  float bias[SS];
};                              // ~134K -> 1 blk/CU

__global__ __launch_bounds__(NT, 2) void ph2g_kernel(
    const float* __restrict__ taba, const unsigned short* __restrict__ Fr,
    const float* __restrict__ tab,
    float* __restrict__ out, float* __restrict__ Hws, float* __restrict__ G0)
{
  __shared__ PH2G sm;
  const int tid = threadIdx.x;
  const int b   = blockIdx.x;
  const int w   = tid >> 6, l = tid & 63;
  const int g   = l >> 4, c0 = l & 15;
  const float* Hb = Hws + (size_t)b * SS * HH;

  if (tid < SS) sm.bias[tid] = taba[tid];
  {
    const float4* src = (const float4*)Hb;
#pragma unroll
    for (int i = 0; i < 8; ++i){
      int fidx = i*NT + tid;
      float4 v = src[fidx];
      int e0 = fidx*4, row = e0 >> 7, col = e0 & 127;
      sm.u1.S[row][col+0] = bf16rne(v.x);
      sm.u1.S[row][col+1] = bf16rne(v.y);
      sm.u1.S[row][col+2] = bf16rne(v.z);
      sm.u1.S[row][col+3] = bf16rne(v.w);
    }
  }
  __syncthreads();

#pragma unroll
  for (int i = 0; i < 4; ++i){
    int slot = i*NT + tid;
    int mt = slot >> 8, kt = (slot >> 6) & 3, ll = slot & 63;
    int row = mt*16 + (ll & 15), k0 = kt*32 + (ll >> 4)*8;
    ((uint4*)sm.fA)[slot] = *(const uint4*)&sm.u1.S[row][k0];
  }
#pragma unroll
  for (int i = 0; i < 4; ++i){
    int slot = i*NT + tid;
    int nt = slot >> 8, kt = (slot >> 6) & 3, ll = slot & 63;
    int col = nt*16 + (ll & 15), s0 = kt*32 + (ll >> 4)*8;
    unsigned u[4];
#pragma unroll
    for (int p = 0; p < 4; ++p)
      u[p] = (unsigned)sm.u1.S[s0+2*p][col] | ((unsigned)sm.u1.S[s0+2*p+1][col] << 16);
    ((uint4*)sm.fB)[slot] = make_uint4(u[0], u[1], u[2], u[3]);
  }
  __syncthreads();

  f32x4 acc[8];
  f32x4 zero4 = {0.f, 0.f, 0.f, 0.f};

  // ---- GEMM1: tmp = tanh(H @ taWa + ba) ----
#pragma unroll
  for (int nt = 0; nt < 8; ++nt) acc[nt] = zero4;
  {
    const uint4* BW = (const uint4*)(Fr + RW_OFF);
#pragma unroll
    for (int kt = 0; kt < 4; ++kt){
      bf16x8 a = as_bf(sm.fA[w][kt][l]);
#pragma unroll
      for (int nt = 0; nt < 8; ++nt){
        bf16x8 bv = as_bf(BW[(nt*4 + kt)*64 + l]);
        acc[nt] = __builtin_amdgcn_mfma_f32_16x16x32_bf16(a, bv, acc[nt], 0, 0, 0);
      }
    }
  }
#pragma unroll
  for (int nt = 0; nt < 8; ++nt){
    int col = nt*16 + c0;
    float bv = sm.bias[col];
#pragma unroll
    for (int j = 0; j < 4; ++j)
      sm.u1.S[w*16 + g*4 + j][col] = bf16rne(tanhx(acc[nt][j] + bv));
  }
  __syncthreads();

  // ---- rebuild fA from S (tmp) ----
#pragma unroll
  for (int i = 0; i < 4; ++i){
    int slot = i*NT + tid;
    int mt = slot >> 8, kt = (slot >> 6) & 3, ll = slot & 63;
    int row = mt*16 + (ll & 15), k0 = kt*32 + (ll >> 4)*8;
    ((uint4*)sm.fA)[slot] = *(const uint4*)&sm.u1.S[row][k0];
  }
  __syncthreads();

  // ---- GEMM2: bp = tmp @ taVa ----
#pragma unroll
  for (int nt = 0; nt < 8; ++nt) acc[nt] = zero4;
  {
    const uint4* BV = (const uint4*)(Fr + RV_OFF);
#pragma unroll
    for (int kt = 0; kt < 4; ++kt){
      bf16x8 a = as_bf(sm.fA[w][kt][l]);
#pragma unroll
      for (int nt = 0; nt < 8; ++nt){
        bf16x8 bv = as_bf(BV[(nt*4 + kt)*64 + l]);
        acc[nt] = __builtin_amdgcn_mfma_f32_16x16x32_bf16(a, bv, acc[nt], 0, 0, 0);
      }
    }
  }

  // ---- in-register softmax + betas out ----
#pragma unroll
  for (int j = 0; j < 4; ++j){
    float m = acc[0][j];
#pragma unroll
    for (int nt = 1; nt < 8; ++nt) m = fmaxf(m, acc[nt][j]);
#pragma unroll
    for (int ms = 1; ms < 16; ms <<= 1) m = fmaxf(m, __shfl_xor(m, ms, 64));
    float e[8], s = 0.f;
#pragma unroll
    for (int nt = 0; nt < 8; ++nt){ e[nt] = __expf(acc[nt][j] - m); s += e[nt]; }
#pragma unroll
    for (int ms = 1; ms < 16; ms <<= 1) s += __shfl_xor(s, ms, 64);
    float inv = 1.0f / s;
    int row = w*16 + g*4 + j;
    size_t bo = BETA_OFF + (size_t)row*BB*SS + (size_t)b*SS;
#pragma unroll
    for (int nt = 0; nt < 8; ++nt){
      float bv = e[nt] * inv;
      out[bo + nt*16 + c0] = bv;
      sm.u1.S[row][nt*16 + c0] = bf16rne(bv);
    }
  }
  __syncthreads();

  // ---- rebuild fA from S (beta) ----
#pragma unroll
  for (int i = 0; i < 4; ++i){
    int slot = i*NT + tid;
    int mt = slot >> 8, kt = (slot >> 6) & 3, ll = slot & 63;
    int row = mt*16 + (ll & 15), k0 = kt*32 + (ll >> 4)*8;
    ((uint4*)sm.fA)[slot] = *(const uint4*)&sm.u1.S[row][k0];
  }
  __syncthreads();

  // ---- GEMM3: h_att = beta @ H ----
#pragma unroll
  for (int nt = 0; nt < 8; ++nt) acc[nt] = zero4;
#pragma unroll
  for (int kt = 0; kt < 4; ++kt){
    bf16x8 a = as_bf(sm.fA[w][kt][l]);
#pragma unroll
    for (int nt = 0; nt < 8; ++nt){
      bf16x8 bv = as_bf(sm.fB[nt][kt][l]);
      acc[nt] = __builtin_amdgcn_mfma_f32_16x16x32_bf16(a, bv, acc[nt], 0, 0, 0);
    }
  }
  // stage h_att split-bf16: hi -> S, lo -> S2
#pragma unroll
  for (int nt = 0; nt < 8; ++nt){
#pragma unroll
    for (int j = 0; j < 4; ++j){
      int row = w*16 + g*4 + j, col = nt*16 + c0;
      float v = acc[nt][j];
      unsigned short h_ = bf16rne(v);
      sm.u1.S[row][col] = h_;            // safe: S(beta) reads done pre-GEMM3 barrier
      sm.S2[row][col]   = bf16rne(v - bfval(h_));
    }
  }
  __syncthreads();   // GEMM3 fA/fB reads + staging complete

  // ---- build h_att A-frags: hi -> fA, lo -> fB slot ----
#pragma unroll
  for (int i = 0; i < 4; ++i){
    int slot = i*NT + tid;
    int mt = slot >> 8, kt = (slot >> 6) & 3, ll = slot & 63;
    int row = mt*16 + (ll & 15), k0 = kt*32 + (ll >> 4)*8;
    ((uint4*)sm.fA)[slot] = *(const uint4*)&sm.u1.S[row][k0];
    ((uint4*)sm.fB)[slot] = *(const uint4*)&sm.S2[row][k0];
  }
  __syncthreads();

  // ---- G0 = h_att @ taW + tab, 8 passes of 64 cols; SG staged in S-union ----
  const uint4* BH = (const uint4*)(Fr + B3H_OFF);
  const uint4* BL = (const uint4*)(Fr + B3L_OFF);
  const size_t r0 = (size_t)b * SS;
#pragma unroll
  for (int p = 0; p < 8; ++p){
    f32x4 acc2[4];
#pragma unroll
    for (int q = 0; q < 4; ++q) acc2[q] = zero4;
#pragma unroll
    for (int q = 0; q < 4; ++q){          // nt_local
      const int ntg = p*4 + q;            // 0..31
#pragma unroll
      for (int kt = 0; kt < 4; ++kt){     // taW = kt 4-7 of B3
        bf16x8 ah = as_bf(sm.fA[w][kt][l]);
        bf16x8 av = as_bf(sm.fB[w][kt][l]);
        bf16x8 bh = as_bf(BH[(ntg*8 + 4 + kt)*64 + l]);
        bf16x8 bl = as_bf(BL[(ntg*8 + 4 + kt)*64 + l]);
        acc2[q] = __builtin_amdgcn_mfma_f32_16x16x32_bf16(ah, bh, acc2[q], 0, 0, 0);
        acc2[q] = __builtin_amdgcn_mfma_f32_16x16x32_bf16(av, bh, acc2[q], 0, 0, 0);
        acc2[q] = __builtin_amdgcn_mfma_f32_16x16x32_bf16(ah, bl, acc2[q], 0, 0, 0);
      }
    }
#pragma unroll
    for (int q = 0; q < 4; ++q){
      float tb = tab[p*64 + q*16 + c0];
#pragma unroll
      for (int j = 0; j < 4; ++j)
        sm.u1.SG[w*16 + g*4 + j][q*16 + c0] = acc2[q][j] + tb;
    }
    __syncthreads();
#pragma unroll
    for (int it = 0; it < 4; ++it){
      int flat = it*NT + tid;      // 2048 float4 = 128 rows x 16
      int row = flat >> 4, cq = flat & 15;
      *(float4*)(G0 + (r0 + row)*NG + p*64 + cq*4) = *(const float4*)&sm.u1.SG[row][cq*4];
    }
    __syncthreads();
  }
}

// ================= ph2 (tier-2, writes h_att to Hws; round-12 version) =========
struct PH2SM {
  union {
    struct { uint4 fA[8][4][64]; uint4 fB[8][4][64]; } f;
    float HO[128][132];
  } u;
  unsigned short S[128][136];
  float bias[SS];
};

__global__ __launch_bounds__(NT, 2) void ph2_kernel(
    const float* __restrict__ taba, const unsigned short* __restrict__ Fr,
    float* __restrict__ out, float* __restrict__ Hws)
{
  __shared__ PH2SM sm;
  const int tid = threadIdx.x;
  const int b   = blockIdx.x;
  const int w   = tid >> 6, l = tid & 63;
  const int g   = l >> 4, c0 = l & 15;
  float* Hb = Hws + (size_t)b * SS * HH;

  if (tid < SS) sm.bias[tid] = taba[tid];
  {
    const float4* src = (const float4*)Hb;
#pragma unroll
    for (int i = 0; i < 8; ++i){
      int fidx = i*NT + tid;
      float4 v = src[fidx];
      int e0 = fidx*4, row = e0 >> 7, col = e0 & 127;
      sm.S[row][col+0] = bf16rne(v.x);
      sm.S[row][col+1] = bf16rne(v.y);
      sm.S[row][col+2] = bf16rne(v.z);
      sm.S[row][col+3] = bf16rne(v.w);
    }
  }
  __syncthreads();

#pragma unroll
  for (int i = 0; i < 4; ++i){
    int slot = i*NT + tid;
    int mt = slot >> 8, kt = (slot >> 6) & 3, ll = slot & 63;
    int row = mt*16 + (ll & 15), k0 = kt*32 + (ll >> 4)*8;
    ((uint4*)sm.u.f.fA)[slot] = *(const uint4*)&sm.S[row][k0];
  }
#pragma unroll
  for (int i = 0; i < 4; ++i){
    int slot = i*NT + tid;
    int nt = slot >> 8, kt = (slot >> 6) & 3, ll = slot & 63;
    int col = nt*16 + (ll & 15), s0 = kt*32 + (ll >> 4)*8;
    unsigned u[4];
#pragma unroll
    for (int p = 0; p < 4; ++p)
      u[p] = (unsigned)sm.S[s0+2*p][col] | ((unsigned)sm.S[s0+2*p+1][col] << 16);
    ((uint4*)sm.u.f.fB)[slot] = make_uint4(u[0], u[1], u[2], u[3]);
  }
  __syncthreads();

  f32x4 acc[8];
  f32x4 zero4 = {0.f, 0.f, 0.f, 0.f};

#pragma unroll
  for (int nt = 0; nt < 8; ++nt) acc[nt] = zero4;
  {
    const uint4* BW = (const uint4*)(Fr + RW_OFF);
#pragma unroll
    for (int kt = 0; kt < 4; ++kt){
      bf16x8 a = as_bf(sm.u.f.fA[w][kt][l]);
#pragma unroll
      for (int nt = 0; nt < 8; ++nt){
        bf16x8 bv = as_bf(BW[(nt*4 + kt)*64 + l]);
        acc[nt] = __builtin_amdgcn_mfma_f32_16x16x32_bf16(a, bv, acc[nt], 0, 0, 0);
      }
    }
  }
#pragma unroll
  for (int nt = 0; nt < 8; ++nt){
    int col = nt*16 + c0;
    float bv = sm.bias[col];
#pragma unroll
    for (int j = 0; j < 4; ++j)
      sm.S[w*16 + g*4 + j][col] = bf16rne(tanhx(acc[nt][j] + bv));
  }
  __syncthreads();

#pragma unroll
  for (int i = 0; i < 4; ++i){
    int slot = i*NT + tid;
    int mt = slot >> 8, kt = (slot >> 6) & 3, ll = slot & 63;
    int row = mt*16 + (ll & 15), k0 = kt*32 + (ll >> 4)*8;
    ((uint4*)sm.u.f.fA)[slot] = *(const uint4*)&sm.S[row][k0];
  }
  __syncthreads();

#pragma unroll
  for (int nt = 0; nt < 8; ++nt) acc[nt] = zero4;
  {
    const uint4* BV = (const uint4*)(Fr + RV_OFF);
#pragma unroll
    for (int kt = 0; kt < 4; ++kt){
      bf16x8 a = as_bf(sm.u.f.fA[w][kt][l]);
#pragma unroll
      for (int nt = 0; nt < 8; ++nt){
        bf16x8 bv = as_bf(BV[(nt*4 + kt)*64 + l]);
        acc[nt] = __builtin_amdgcn_mfma_f32_16x16x32_bf16(a, bv, acc[nt], 0, 0, 0);
      }
    }
  }

#pragma unroll
  for (int j = 0; j < 4; ++j){
    float m = acc[0][j];
#pragma unroll
    for (int nt = 1; nt < 8; ++nt) m = fmaxf(m, acc[nt][j]);
#pragma unroll
    for (int ms = 1; ms < 16; ms <<= 1) m = fmaxf(m, __shfl_xor(m, ms, 64));
    float e[8], s = 0.f;
#pragma unroll
    for (int nt = 0; nt < 8; ++nt){ e[nt] = __expf(acc[nt][j] - m); s += e[nt]; }
#pragma unroll
    for (int ms = 1; ms < 16; ms <<= 1) s += __shfl_xor(s, ms, 64);
    float inv = 1.0f / s;
    int row = w*16 + g*4 + j;
    size_t bo = BETA_OFF + (size_t)row*BB*SS + (size_t)b*SS;
#pragma unroll
    for (int nt = 0; nt < 8; ++nt){
      float bv = e[nt] * inv;
      out[bo + nt*16 + c0] = bv;
      sm.S[row][nt*16 + c0] = bf16rne(bv);
    }
  }
  __syncthreads();

#pragma unroll
  for (int i = 0; i < 4; ++i){
    int slot = i*NT + tid;
    int mt = slot >> 8, kt = (slot >> 6) & 3, ll = slot & 63;
    int row = mt*16 + (ll & 15), k0 = kt*32 + (ll >> 4)*8;
    ((uint4*)sm.u.f.fA)[slot] = *(const uint4*)&sm.S[row][k0];
  }
  __syncthreads();

#pragma unroll
  for (int nt = 0; nt < 8; ++nt) acc[nt] = zero4;
#pragma unroll
  for (int kt = 0; kt < 4; ++kt){
    bf16x8 a = as_bf(sm.u.f.fA[w][kt][l]);
#pragma unroll
    for (int nt = 0; nt < 8; ++nt){
      bf16x8 bv = as_bf(sm.u.f.fB[nt][kt][l]);
      acc[nt] = __builtin_amdgcn_mfma_f32_16x16x32_bf16(a, bv, acc[nt], 0, 0, 0);
    }
  }
  __syncthreads();

#pragma unroll
  for (int nt = 0; nt < 8; ++nt)
#pragma unroll
    for (int j = 0; j < 4; ++j)
      sm.u.HO[w*16 + g*4 + j][nt*16 + c0] = acc[nt][j];
  __syncthreads();
#pragma unroll
  for (int it = 0; it < 8; ++it){
    int flat = it*NT + tid;
    int row = flat >> 5, cq = flat & 31;
    *(float4*)(Hb + (size_t)row*HH + cq*4) = *(const float4*)&sm.u.HO[row][cq*4];
  }
}

// ================= mf_ph3h: temporal LSTM, K=128, G0 prefetch =================
struct P3H {
  uint4 afh[4*64];     // 4K
  uint4 afl[4*64];     // 4K
  float lh[M][HH];     // 4K
  float lc[M][HH];     // 4K
  float g[M][NG];      // 16K
  float wy[NG];        // 2K
  float fcv[HH];
  float yp[M];
};
union __align__(16) SMCH { P3H s; float pad[21504]; };   // 84K -> 1 blk/CU

__global__ __launch_bounds__(NT, 2) __attribute__((amdgpu_waves_per_eu(2, 2)))
void mf_ph3h_kernel(
    const float* __restrict__ X, const unsigned short* __restrict__ Fr,
    const float* __restrict__ G0,
    const float* __restrict__ taWy,
    const float* __restrict__ fcw, const float* __restrict__ fcb,
    float* __restrict__ out)
{
  __shared__ SMCH sm;
  const int tid = threadIdx.x;
  const int b0  = blockIdx.x * M;
  const int w   = tid >> 6, l = tid & 63;
  const int row0 = (l >> 4)*4, c0 = l & 15;

  {
    uint4 z4 = make_uint4(0,0,0,0);
    if (tid < 4*64){ sm.s.afh[tid] = z4; sm.s.afl[tid] = z4; }
    for (int i = tid; i < M*HH; i += NT){
      ((float*)sm.s.lh)[i] = 0.f; ((float*)sm.s.lc)[i] = 0.f;
    }
    sm.s.wy[tid] = taWy[tid];
    if (tid < HH) sm.s.fcv[tid] = fcw[tid];
    if (tid < M)  sm.s.yp[tid] = X[(size_t)(b0+tid)*SS*DD + (DD-1)];
  }
  // preload G0 for t=0 (loop-carried)
  float g0v[16];
  if (row0 < 8){
#pragma unroll
    for (int n4 = 0; n4 < 4; ++n4)
#pragma unroll
      for (int j = 0; j < 4; ++j)
        g0v[n4*4+j] = G0[((size_t)(b0+row0+j)*SS + 0)*NG + (w*64 + n4*16 + c0)];
  }
  __syncthreads();

  for (int t = 0; t < SS; ++t){
    // ---- Q1: gates MFMA (K=128) using preloaded g0v ----
    {
      f32x4 zero4 = {0.f,0.f,0.f,0.f};
      f32x4 acc[4];
#pragma unroll
      for (int n4 = 0; n4 < 4; ++n4) acc[n4] = zero4;
      const uint4* BH = (const uint4*)(Fr + B3H_OFF);
      const uint4* BL = (const uint4*)(Fr + B3L_OFF);
#pragma unroll
      for (int kt = 0; kt < 4; ++kt){      // taU = kt 0-3
        bf16x8 ah = as_bf(sm.s.afh[kt*64 + l]);
        bf16x8 av = as_bf(sm.s.afl[kt*64 + l]);
#pragma unroll
        for (int n4 = 0; n4 < 4; ++n4){
          const int ntg = w*4 + n4;
          bf16x8 bh = as_bf(BH[(ntg*8 + kt)*64 + l]);
          bf16x8 bl = as_bf(BL[(ntg*8 + kt)*64 + l]);
          acc[n4] = __builtin_amdgcn_mfma_f32_16x16x32_bf16(ah, bh, acc[n4], 0, 0, 0);
          acc[n4] = __builtin_amdgcn_mfma_f32_16x16x32_bf16(av, bh, acc[n4], 0, 0, 0);
          acc[n4] = __builtin_amdgcn_mfma_f32_16x16x32_bf16(ah, bl, acc[n4], 0, 0, 0);
        }
      }
      if (row0 < 8){
#pragma unroll
        for (int n4 = 0; n4 < 4; ++n4){
          int col = w*64 + n4*16 + c0;
          float wv = sm.s.wy[col];
#pragma unroll
          for (int j = 0; j < 4; ++j)
            sm.s.g[row0+j][col] = acc[n4][j] + g0v[n4*4+j] + sm.s.yp[row0+j]*wv;
        }
      }
    }
    __syncthreads();

    // ---- Q2: issue G0(t+1) loads first, then pointwise + lh-frag build ----
    float g0n[16];
    const bool dog = (t + 1 < SS) && (row0 < 8);
    if (dog){
#pragma unroll
      for (int n4 = 0; n4 < 4; ++n4)
#pragma unroll
        for (int j = 0; j < 4; ++j)
          g0n[n4*4+j] = G0[((size_t)(b0+row0+j)*SS + (t+1))*NG + (w*64 + n4*16 + c0)];
    }
    {
      unsigned short* AFH = (unsigned short*)sm.s.afh;
      unsigned short* AFL = (unsigned short*)sm.s.afl;
#pragma unroll
      for (int h2 = 0; h2 < 2; ++h2){
        int idx = h2*NT + tid;
        int r = idx >> 7, j = idx & 127;
        float iv = sigf (sm.s.g[r][j]);
        float fv = sigf (sm.s.g[r][j + 128]);
        float gv = tanhx(sm.s.g[r][j + 256]);
        float ov = sigf (sm.s.g[r][j + 384]);
        float cn = fv * sm.s.lc[r][j] + iv * gv;
        float hn = ov * tanhx(cn);
        sm.s.lc[r][j] = cn; sm.s.lh[r][j] = hn;
        int kt = j >> 5, lane = (((j & 31) >> 3) << 4) | r, jj = j & 7;
        unsigned short h_ = bf16rne(hn);
        AFH[(kt*64 + lane)*8 + jj] = h_;
        AFL[(kt*64 + lane)*8 + jj] = bf16rne(hn - bfval(h_));
      }
    }
    __syncthreads();

    // ---- Q3: fc reduce + commit g0v ----
    {
      const int r = w, lx = l;
      float p = sm.s.lh[r][lx]*sm.s.fcv[lx] + sm.s.lh[r][lx+64]*sm.s.fcv[lx+64];
      p = wsum64(p);
      if (lx == 0) sm.s.yp[r] = p + fcb[0];
    }
    if (dog){
#pragma unroll
      for (int q = 0; q < 16; ++q) g0v[q] = g0n[q];
    }
    __syncthreads();
  }

  if (tid < M) out[b0 + tid] = sm.s.yp[tid];
}

// ================= mf_ph3full: K=256 variant (tier-2 fallback) ==========
struct P3 {
  uint4 afh[8*64];
  uint4 afl[8*64];
  float lh[M][HH];
  float lc[M][HH];
  float g[M][NG];
  float sb[NG];
  float wy[NG];
  float fcv[HH];
  float yp[M];
};
union __align__(16) SMC { P3 s; float pad[21504]; };

__global__ __launch_bounds__(NT, 2) void mf_ph3_kernel(
    const float* __restrict__ X, const float* __restrict__ Ha,
    const unsigned short* __restrict__ Fr,
    const float* __restrict__ tab, const float* __restrict__ taWy,
    const float* __restrict__ fcw, const float* __restrict__ fcb,
    float* __restrict__ out)
{
  __shared__ SMC sm;
  const int tid = threadIdx.x;
  const int b0  = blockIdx.x * M;
  const int w   = tid >> 6, l = tid & 63;

  {
    uint4 z4 = make_uint4(0,0,0,0);
    sm.s.afh[tid] = z4; sm.s.afl[tid] = z4;
    for (int i = tid; i < M*HH; i += NT){
      ((float*)sm.s.lh)[i] = 0.f; ((float*)sm.s.lc)[i] = 0.f;
    }
    sm.s.sb[tid] = tab[tid];
    sm.s.wy[tid] = taWy[tid];
    if (tid < HH) sm.s.fcv[tid] = fcw[tid];
    if (tid < M)  sm.s.yp[tid] = X[(size_t)(b0+tid)*SS*DD + (DD-1)];
  }
  __syncthreads();
  if (tid < 256){
    int r = tid >> 5, d0 = (tid & 31)*4;
    float4 v = *(const float4*)(Ha + (size_t)(b0+r)*SS*HH + d0);
    unsigned short* AFH = (unsigned short*)sm.s.afh;
    unsigned short* AFL = (unsigned short*)sm.s.afl;
    int kt = 4 + (d0 >> 5), lane = (((d0 & 31) >> 3) << 4) | r, jj0 = d0 & 7;
    float vv[4] = {v.x, v.y, v.z, v.w};
#pragma unroll
    for (int p = 0; p < 4; ++p){
      unsigned short h_ = bf16rne(vv[p]);
      AFH[(kt*64 + lane)*8 + jj0 + p] = h_;
      AFL[(kt*64 + lane)*8 + jj0 + p] = bf16rne(vv[p] - bfval(h_));
    }
  }
  __syncthreads();

  for (int t = 0; t < SS; ++t){
    float4 pf;
    const bool dop = (tid < 256) && (t + 1 < SS);
    if (dop){
      int r = tid >> 5, d0 = (tid & 31)*4;
      pf = *(const float4*)(Ha + (size_t)(b0+r)*SS*HH + (size_t)(t+1)*HH + d0);
    }
    {
      f32x4 zero4 = {0.f,0.f,0.f,0.f};
      f32x4 acc[4];
#pragma unroll
      for (int n4 = 0; n4 < 4; ++n4) acc[n4] = zero4;
      const uint4* BH = (const uint4*)(Fr + B3H_OFF);
      const uint4* BL = (const uint4*)(Fr + B3L_OFF);
#pragma unroll
      for (int kt = 0; kt < 8; ++kt){
        bf16x8 ah = as_bf(sm.s.afh[kt*64 + l]);
        bf16x8 av = as_bf(sm.s.afl[kt*64 + l]);
#pragma unroll
        for (int n4 = 0; n4 < 4; ++n4){
          const int ntg = w*4 + n4;
          bf16x8 bh = as_bf(BH[(ntg*8 + kt)*64 + l]);
          bf16x8 bl = as_bf(BL[(ntg*8 + kt)*64 + l]);
          acc[n4] = __builtin_amdgcn_mfma_f32_16x16x32_bf16(ah, bh, acc[n4], 0, 0, 0);
          acc[n4] = __builtin_amdgcn_mfma_f32_16x16x32_bf16(av, bh, acc[n4], 0, 0, 0);
          acc[n4] = __builtin_amdgcn_mfma_f32_16x16x32_bf16(ah, bl, acc[n4], 0, 0, 0);
        }
      }
      const int row0 = (l >> 4)*4;
      if (row0 < 8){
        const int colb = w*64 + (l & 15);
#pragma unroll
        for (int n4 = 0; n4 < 4; ++n4){
          int col = colb + n4*16;
          float b = sm.s.sb[col];
          float wv = sm.s.wy[col];
#pragma unroll
          for (int j = 0; j < 4; ++j)
            sm.s.g[row0+j][col] = acc[n4][j] + b + sm.s.yp[row0+j]*wv;
        }
      }
    }
    __syncthreads();

    {
      unsigned short* AFH = (unsigned short*)sm.s.afh;
      unsigned short* AFL = (unsigned short*)sm.s.afl;
#pragma unroll
      for (int h2 = 0; h2 < 2; ++h2){
        int idx = h2*NT + tid;
        int r = idx >> 7, j = idx & 127;
        float iv = sigf (sm.s.g[r][j]);
        float fv = sigf (sm.s.g[r][j + 128]);
        float gv = tanhx(sm.s.g[r][j + 256]);
        float ov = sigf (sm.s.g[r][j + 384]);
        float cn = fv * sm.s.lc[r][j] + iv * gv;
        float hn = ov * tanhx(cn);
        sm.s.lc[r][j] = cn; sm.s.lh[r][j] = hn;
        int kt = j >> 5, lane = (((j & 31) >> 3) << 4) | r, jj = j & 7;
        unsigned short h_ = bf16rne(hn);
        AFH[(kt*64 + lane)*8 + jj] = h_;
        AFL[(kt*64 + lane)*8 + jj] = bf16rne(hn - bfval(h_));
      }
    }
    __syncthreads();

    {
      const int r = w, lx = l;
      float p = sm.s.lh[r][lx]*sm.s.fcv[lx] + sm.s.lh[r][lx+64]*sm.s.fcv[lx+64];
      p = wsum64(p);
      if (lx == 0) sm.s.yp[r] = p + fcb[0];
    }
    if (dop){
      int r = tid >> 5, d0 = (tid & 31)*4;
      unsigned short* AFH = (unsigned short*)sm.s.afh;
      unsigned short* AFL = (unsigned short*)sm.s.afl;
      int kt = 4 + (d0 >> 5), lane = (((d0 & 31) >> 3) << 4) | r, jj0 = d0 & 7;
      float vv[4] = {pf.x, pf.y, pf.z, pf.w};
#pragma unroll
      for (int p = 0; p < 4; ++p){
        unsigned short h_ = bf16rne(vv[p]);
        AFH[(kt*64 + lane)*8 + jj0 + p] = h_;
        AFL[(kt*64 + lane)*8 + jj0 + p] = bf16rne(vv[p] - bfval(h_));
      }
    }
    __syncthreads();
  }

  if (tid < M) out[b0 + tid] = sm.s.yp[tid];
}

// ================= Fallback (round-3 VALU kernels, if ws tiny) ===============
struct FSM1 {
  float x[M][DD]; float h[M][HH]; float c[M][HH];
  float a[M][DD]; float xw[M][DD]; float g[M][NG];
};
struct FP1 { FSM1 s; float red[8][512]; };
union __align__(16) FSMA { FP1 p1; P2S p2; float pad[21504]; };

__global__ __launch_bounds__(NT, 2) void fb_ph12_kernel(
    const float* __restrict__ X,
    const float* __restrict__ saW,  const float* __restrict__ saU,  const float* __restrict__ sab,
    const float* __restrict__ saWa, const float* __restrict__ saUa, const float* __restrict__ saba,
    const float* __restrict__ saVa,
    const float* __restrict__ taWa, const float* __restrict__ taba, const float* __restrict__ taVa,
    float* __restrict__ out, float* __restrict__ Hws)
{
  __shared__ FSMA sm;
  const int tid = threadIdx.x;
  const int b0  = blockIdx.x * M;
  const int w   = tid >> 6, l = tid & 63;

  for (int idx = tid; idx < M*HH; idx += NT){
    int r = idx >> 7, j = idx & 127;
    sm.p1.s.h[r][j] = 0.f; sm.p1.s.c[r][j] = 0.f;
  }
  { int r = tid >> 6, d = tid & 63;
    sm.p1.s.x[r][d] = X[(size_t)(b0+r)*SS*DD + d]; }
  __syncthreads();

  for (int t = 0; t < SS; ++t){
    {
      float pr[M];
#pragma unroll
      for (int r = 0; r < M; ++r) pr[r] = 0.f;
      { const int kb = w*8;
#pragma unroll
        for (int q = 0; q < 2; ++q){
          const int k = kb + q*4;
          const float* wp = saWa + (size_t)k*DD + l;
          float w0 = wp[0], w1 = wp[DD], w2 = wp[2*DD], w3 = wp[3*DD];
#pragma unroll
          for (int r = 0; r < M; ++r){
            float4 v = *(const float4*)&sm.p1.s.x[r][k];
            pr[r] += w0*v.x + w1*v.y + w2*v.z + w3*v.w;
          }
        }
      }
      { const int kb = w*16;
#pragma unroll
        for (int q = 0; q < 4; ++q){
          const int k = kb + q*4;
          const float* wp = saUa + (size_t)k*DD + l;
          float w0 = wp[0], w1 = wp[DD], w2 = wp[2*DD], w3 = wp[3*DD];
#pragma unroll
          for (int r = 0; r < M; ++r){
            float4 v = *(const float4*)&sm.p1.s.h[r][k];
            pr[r] += w0*v.x + w1*v.y + w2*v.z + w3*v.w;
          }
        }
      }
      { const int kb = w*16;
#pragma unroll
        for (int q = 0; q < 4; ++q){
          const int k = kb + q*4;
          const float* wp = saUa + (size_t)(HH + k)*DD + l;
          float w0 = wp[0], w1 = wp[DD], w2 = wp[2*DD], w3 = wp[3*DD];
#pragma unroll
          for (int r = 0; r < M; ++r){
            float4 v = *(const float4*)&sm.p1.s.c[r][k];
            pr[r] += w0*v.x + w1*v.y + w2*v.z + w3*v.w;
          }
        }
      }
#pragma unroll
      for (int r = 0; r < M; ++r) sm.p1.red[w][r*64 + l] = pr[r];
    }
    __syncthreads();
    {
      float s = saba[l];
#pragma unroll
      for (int u = 0; u < 8; ++u) s += sm.p1.red[u][w*64 + l];
      sm.p1.s.a[w][l] = tanhx(s);
    }
    __syncthreads();
    {
      float pr[M];
#pragma unroll
      for (int r = 0; r < M; ++r) pr[r] = 0.f;
      const int kb = w*8;
#pragma unroll
      for (int q = 0; q < 2; ++q){
        const int k = kb + q*4;
        const float* wp = saVa + (size_t)k*DD + l;
        float w0 = wp[0], w1 = wp[DD], w2 = wp[2*DD], w3 = wp[3*DD];
#pragma unroll
        for (int r = 0; r < M; ++r){
          float4 v = *(const float4*)&sm.p1.s.a[r][k];
          pr[r] += w0*v.x + w1*v.y + w2*v.z + w3*v.w;
        }
      }
#pragma unroll
      for (int r = 0; r < M; ++r) sm.p1.red[w][r*64 + l] = pr[r];
    }
    __syncthreads();
    {
      float s = 0.f;
#pragma unroll
      for (int u = 0; u < 8; ++u) s += sm.p1.red[u][w*64 + l];
      float mm = wmax64(s);
      float e  = __expf(s - mm);
      float al = e * (1.0f / wsum64(e));
      out[A_OFF + (size_t)t*BB*DD + (size_t)(b0+w)*DD + l] = al;
      sm.p1.s.xw[w][l] = al * sm.p1.s.x[w][l];
    }
    __syncthreads();
    {
      const int c0 = tid;
      float acc[M];
      const float bv = sab[c0];
#pragma unroll
      for (int r = 0; r < M; ++r) acc[r] = bv;
      for (int k = 0; k < DD; k += 4){
        const float* wp = saW + (size_t)k*NG + c0;
        float w0 = wp[0], w1 = wp[NG], w2 = wp[2*NG], w3 = wp[3*NG];
#pragma unroll
        for (int r = 0; r < M; ++r){
          float4 v = *(const float4*)&sm.p1.s.xw[r][k];
          acc[r] += w0*v.x + w1*v.y + w2*v.z + w3*v.w;
        }
      }
      for (int k = 0; k < HH; k += 4){
        const float* wp = saU + (size_t)k*NG + c0;
        float w0 = wp[0], w1 = wp[NG], w2 = wp[2*NG], w3 = wp[3*NG];
#pragma unroll
        for (int r = 0; r < M; ++r){
          float4 v = *(const float4*)&sm.p1.s.h[r][k];
          acc[r] += w0*v.x + w1*v.y + w2*v.z + w3*v.w;
        }
      }
#pragma unroll
      for (int r = 0; r < M; ++r) sm.p1.s.g[r][c0] = acc[r];
    }
    __syncthreads();
    for (int idx = tid; idx < M*HH; idx += NT){
      int r = idx >> 7, j = idx & 127;
      float iv = sigf (sm.p1.s.g[r][j]);
      float fv = sigf (sm.p1.s.g[r][j +   HH]);
      float gv = tanhx(sm.p1.s.g[r][j + 2*HH]);
      float ov = sigf (sm.p1.s.g[r][j + 3*HH]);
      float cn = fv * sm.p1.s.c[r][j] + iv * gv;
      float hn = ov * tanhx(cn);
      sm.p1.s.c[r][j] = cn; sm.p1.s.h[r][j] = hn;
      Hws[(size_t)(b0+r)*SS*HH + (size_t)t*HH + j] = hn;
    }
    if (t + 1 < SS){
      int r = tid >> 6, d = tid & 63;
      sm.p1.s.x[r][d] = X[(size_t)(b0+r)*SS*DD + (size_t)(t+1)*DD + d];
    }
    __syncthreads();
  }

  for (int r = 0; r < M; ++r){
    float* Hrow = Hws + (size_t)(b0+r)*SS*HH;
    const int c  = tid & 127;
    const int th = tid >> 7;
    float hacc[32];
#pragma unroll
    for (int i = 0; i < 32; ++i) hacc[i] = 0.f;
#pragma unroll
    for (int ch = 0; ch < 4; ++ch){
      for (int idx = tid; idx < 32*HH/4; idx += NT)
        ((float4*)sm.p2.A)[idx] = ((const float4*)(Hrow + (size_t)ch*32*HH))[idx];
      __syncthreads();
      { float acc[8];
        const float bv = taba[c];
#pragma unroll
        for (int i = 0; i < 8; ++i) acc[i] = bv;
        for (int k = 0; k < HH; k += 4){
          const float* wp = taWa + (size_t)k*SS + c;
          float w0 = wp[0], w1 = wp[SS], w2 = wp[2*SS], w3 = wp[3*SS];
#pragma unroll
          for (int i = 0; i < 8; ++i){
            float4 v = *(const float4*)&sm.p2.A[th*8+i][k];
            acc[i] += w0*v.x + w1*v.y + w2*v.z + w3*v.w;
          }
        }
#pragma unroll
        for (int i = 0; i < 8; ++i) sm.p2.tmp[th*8+i][c] = tanhx(acc[i]);
      }
      __syncthreads();
      { float acc[8];
#pragma unroll
        for (int i = 0; i < 8; ++i) acc[i] = 0.f;
        for (int k = 0; k < SS; k += 4){
          const float* wp = taVa + (size_t)k*SS + c;
          float w0 = wp[0], w1 = wp[SS], w2 = wp[2*SS], w3 = wp[3*SS];
#pragma unroll
          for (int i = 0; i < 8; ++i){
            float4 v = *(const float4*)&sm.p2.tmp[th*8+i][k];
            acc[i] += w0*v.x + w1*v.y + w2*v.z + w3*v.w;
          }
        }
#pragma unroll
        for (int i = 0; i < 8; ++i) sm.p2.bp[th*8+i][c] = acc[i];
      }
      __syncthreads();
      { const int wv = tid >> 6, lane = tid & 63;
#pragma unroll
        for (int it = 0; it < 4; ++it){
          int tl = wv + 8*it;
          float v0 = sm.p2.bp[tl][lane], v1 = sm.p2.bp[tl][lane+64];
          float mm = wmax64(fmaxf(v0, v1));
          float e0 = __expf(v0 - mm), e1 = __expf(v1 - mm);
          float inv = 1.0f / wsum64(e0 + e1);
          e0 *= inv; e1 *= inv;
          size_t bo = BETA_OFF + (size_t)(ch*32+tl)*BB*SS + (size_t)(b0+r)*SS;
          out[bo + lane]      = e0;
          out[bo + lane + 64] = e1;
          sm.p2.bp[tl][lane]      = e0;
          sm.p2.bp[tl][lane + 64] = e1;
        }
      }
      __syncthreads();
      for (int k = 0; k < SS; k += 4){
        const float* hp = Hrow + (size_t)k*HH + c;
        float hv0 = hp[0], hv1 = hp[HH], hv2 = hp[2*HH], hv3 = hp[3*HH];
#pragma unroll
        for (int i = 0; i < 8; ++i){
          float4 bv = *(const float4*)&sm.p2.bp[th*8+i][k];
          hacc[ch*8+i] += bv.x*hv0 + bv.y*hv1 + bv.z*hv2 + bv.w*hv3;
        }
      }
    }
    __syncthreads();
#pragma unroll
    for (int ch = 0; ch < 4; ++ch)
#pragma unroll
      for (int i = 0; i < 8; ++i)
        Hrow[(size_t)(ch*32 + th*8 + i)*HH + c] = hacc[ch*8+i];
    __syncthreads();
  }
}

__global__ __launch_bounds__(NT, 2) void fb_ph3_kernel(
    const float* __restrict__ X, const float* __restrict__ Ha,
    const float* __restrict__ taW, const float* __restrict__ taU,
    const float* __restrict__ tab, const float* __restrict__ taWy,
    const float* __restrict__ fcw, const float* __restrict__ fcb,
    float* __restrict__ out)
{
  __shared__ struct {
    float ha[M][HH]; float lh[M][HH]; float lc[M][HH];
    float g[M][NG];  float yp[M];
  } s;
  const int tid = threadIdx.x;
  const int b0  = blockIdx.x * M;

  for (int idx = tid; idx < M*HH; idx += NT){
    int r = idx >> 7, j = idx & 127;
    s.lh[r][j] = 0.f; s.lc[r][j] = 0.f;
  }
  if (tid < M) s.yp[tid] = X[(size_t)(b0+tid)*SS*DD + (DD-1)];
  if (tid < M*HH/4){
    int r = tid >> 5, q = tid & 31;
    ((float4*)s.ha)[tid] = *(const float4*)(Ha + (size_t)(b0+r)*SS*HH + q*4);
  }
  __syncthreads();

  for (int t = 0; t < SS; ++t){
    {
      const int c0 = tid;
      const float wy = taWy[c0];
      const float tb = tab[c0];
      float acc[M];
#pragma unroll
      for (int r = 0; r < M; ++r) acc[r] = tb + s.yp[r]*wy;
      for (int k = 0; k < HH; k += 4){
        const float* wp = taW + (size_t)k*NG + c0;
        float a0 = wp[0], a1 = wp[NG], a2 = wp[2*NG], a3 = wp[3*NG];
#pragma unroll
        for (int r = 0; r < M; ++r){
          float4 v = *(const float4*)&s.ha[r][k];
          acc[r] += a0*v.x + a1*v.y + a2*v.z + a3*v.w;
        }
      }
      for (int k = 0; k < HH; k += 4){
        const float* wp = taU + (size_t)k*NG + c0;
        float a0 = wp[0], a1 = wp[NG], a2 = wp[2*NG], a3 = wp[3*NG];
#pragma unroll
        for (int r = 0; r < M; ++r){
          float4 v = *(const float4*)&s.lh[r][k];
          acc[r] += a0*v.x + a1*v.y + a2*v.z + a3*v.w;
        }
      }
#pragma unroll
      for (int r = 0; r < M; ++r) s.g[r][c0] = acc[r];
    }
    __syncthreads();
    for (int idx = tid; idx < M*HH; idx += NT){
      int r = idx >> 7, j = idx & 127;
      float iv = sigf (s.g[r][j]);
      float fv = sigf (s.g[r][j +   HH]);
      float gv = tanhx(s.g[r][j + 2*HH]);
      float ov = sigf (s.g[r][j + 3*HH]);
      float cn = fv * s.lc[r][j] + iv * gv;
      float hn = ov * tanhx(cn);
      s.lc[r][j] = cn; s.lh[r][j] = hn;
    }
    if (t + 1 < SS && tid < M*HH/4){
      int r = tid >> 5, q = tid & 31;
      ((float4*)s.ha)[tid] =
        *(const float4*)(Ha + (size_t)(b0+r)*SS*HH + (size_t)(t+1)*HH + q*4);
    }
    __syncthreads();
    {
      const int r = tid >> 6, lx = tid & 63;
      float p = s.lh[r][lx]*fcw[lx] + s.lh[r][lx+64]*fcw[lx+64];
      p = wsum64(p);
      if (lx == 0) s.yp[r] = p + fcb[0];
    }
    __syncthreads();
  }
  if (tid < M) out[b0 + tid] = s.yp[tid];
}

extern "C" void kernel_launch(void* const* d_in, const int* in_sizes, int n_in,
                              void* d_out, int out_size, void* d_ws, size_t ws_size,
                              hipStream_t stream) {
  (void)in_sizes; (void)n_in; (void)out_size;
  const float* X    = (const float*)d_in[0];
  const float* saW  = (const float*)d_in[1];
  const float* saU  = (const float*)d_in[2];
  const float* sab  = (const float*)d_in[3];
  const float* saWa = (const float*)d_in[4];
  const float* saUa = (const float*)d_in[5];
  const float* saba = (const float*)d_in[6];
  const float* saVa = (const float*)d_in[7];
  const float* taWa = (const float*)d_in[8];
  // d_in[9] = ta_Ua: unused by the reference forward pass
  const float* taba = (const float*)d_in[10];
  const float* taVa = (const float*)d_in[11];
  const float* taW  = (const float*)d_in[12];
  const float* taU  = (const float*)d_in[13];
  const float* tab  = (const float*)d_in[14];
  const float* taWy = (const float*)d_in[15];
  const float* fcw  = (const float*)d_in[16];
  const float* fcb  = (const float*)d_in[17];
  float* out = (float*)d_out;

  if (ws_size >= NEED2_BYTES){
    unsigned short* Fr = (unsigned short*)d_ws;
    float* Hws = (float*)((char*)d_ws + FRAG_BYTES);
    hipLaunchKernelGGL(repack_kernel, dim3(512), dim3(256), 0, stream,
                       saW, saU, saWa, saUa, saVa, taU, taW, taWa, taVa, Fr);
    hipLaunchKernelGGL(mf_ph1_kernel, dim3(BB / M), dim3(NT), 0, stream,
                       X, sab, saba, Fr, out, Hws);
    if (ws_size >= NEED3_BYTES){
      float* G0 = (float*)((char*)d_ws + FRAG_BYTES + H_BYTES);
      hipLaunchKernelGGL(ph2g_kernel, dim3(BB), dim3(NT), 0, stream,
                         taba, Fr, tab, out, Hws, G0);
      hipLaunchKernelGGL(mf_ph3h_kernel, dim3(BB / M), dim3(NT), 0, stream,
                         X, Fr, G0, taWy, fcw, fcb, out);
    } else {
      hipLaunchKernelGGL(ph2_kernel, dim3(BB), dim3(NT), 0, stream,
                         taba, Fr, out, Hws);
      hipLaunchKernelGGL(mf_ph3_kernel, dim3(BB / M), dim3(NT), 0, stream,
                         X, Hws, Fr, tab, taWy, fcw, fcb, out);
    }
  } else {
    float* Hws = (float*)d_ws;
    hipLaunchKernelGGL(fb_ph12_kernel, dim3(BB / M), dim3(NT), 0, stream,
                       X, saW, saU, sab, saWa, saUa, saba, saVa,
                       taWa, taba, taVa, out, Hws);
    hipLaunchKernelGGL(fb_ph3_kernel, dim3(BB / M), dim3(NT), 0, stream,
                       X, Hws, taW, taU, tab, taWy, fcw, fcb, out);
  }
}

// Round 14
// 1383.067 us; speedup vs baseline: 2.1113x; 1.0351x over previous
//
#include <hip/hip_runtime.h>

// STA-LSTM forward: B=2048, S=128, D=64, H1=H2=128, OUT=1
// Round 14 (base: round 13):
//  1. mf_ph3h: 2 barriers/step — fc-reduce folded into Q2 as per-wave partial
//     sums (red[r][half]); yp combined in Q1 epilogue from last step's partials.
//  2. ph2g: h_att frags written DIRECTLY to fA/fB after GEMM3 (own-wave region,
//     no extra barrier/staging; S2 deleted); G0 in 4x128-col passes (8 barriers
//     instead of 16+2). LDS ~132KB, 1 blk/CU.
// Kernels: repack -> mf_ph1 -> ph2g -> mf_ph3h     (full tier)
//          repack -> mf_ph1 -> ph2  -> mf_ph3full  (if ws lacks G0 space)
//          fb_* VALU kernels                        (if ws < 130 MB)
// NOTE: NT=512 + launch_bounds(512,2)/waves_per_eu(2,2) is the ONLY config that
// reliably avoids spills (NT=1024 variants collapse to VGPR=64 + scratch).
// NOTE: MFMA-fragment register->global scalar stores cause ~6x write
// amplification — always stage through LDS and emit >=256B dense segments.

#define BB 2048
#define SS 128
#define DD 64
#define HH 128
#define NG 512
#define M  8
#define NT 512

#define A_OFF    ((size_t)BB)
#define BETA_OFF ((size_t)BB + (size_t)SS*BB*DD)
#define H_BYTES  ((size_t)BB*SS*HH*4)
#define G0_BYTES ((size_t)BB*SS*NG*4)

// fragment buffer layout in ws (ushort offsets)
#define B1G_ELEMS (192*512)
#define B1A_ELEMS (320*64)
#define BVA_ELEMS (64*64)
#define B3_ELEMS  (256*512)
#define BW_ELEMS  (128*128)
#define GH_OFF 0
#define GL_OFF (B1G_ELEMS)
#define AH_OFF (2*B1G_ELEMS)
#define AL_OFF (2*B1G_ELEMS + B1A_ELEMS)
#define VH_OFF (2*B1G_ELEMS + 2*B1A_ELEMS)
#define VL_OFF (VH_OFF + BVA_ELEMS)
#define B3H_OFF (VH_OFF + 2*BVA_ELEMS)
#define B3L_OFF (B3H_OFF + B3_ELEMS)
#define RW_OFF  (B3H_OFF + 2*B3_ELEMS)
#define RV_OFF  (RW_OFF + BW_ELEMS)
#define FRAG_BYTES ((size_t)(RV_OFF + BW_ELEMS)*2)
#define NEED2_BYTES (FRAG_BYTES + H_BYTES)
#define NEED3_BYTES (FRAG_BYTES + H_BYTES + G0_BYTES)

typedef float f32x4 __attribute__((ext_vector_type(4)));
typedef __bf16 bf16x8 __attribute__((ext_vector_type(8)));
union FB { uint4 u; bf16x8 v; };
__device__ __forceinline__ bf16x8 as_bf(uint4 u){ FB x; x.u = u; return x.v; }

__device__ __forceinline__ unsigned short bf16rne(float f){
  unsigned u = __float_as_uint(f);
  u = (u + 0x7FFFu + ((u >> 16) & 1u)) >> 16;
  return (unsigned short)u;
}
__device__ __forceinline__ float bfval(unsigned short h){
  return __uint_as_float(((unsigned)h) << 16);
}

__device__ __forceinline__ float sigf(float x){ return 1.0f/(1.0f + __expf(-x)); }
__device__ __forceinline__ float tanhx(float x){ return 1.0f - 2.0f/(1.0f + __expf(2.0f*x)); }

__device__ __forceinline__ float wmax64(float v){
#pragma unroll
  for (int m = 32; m; m >>= 1) v = fmaxf(v, __shfl_xor(v, m, 64));
  return v;
}
__device__ __forceinline__ float wsum64(float v){
#pragma unroll
  for (int m = 32; m; m >>= 1) v += __shfl_xor(v, m, 64);
  return v;
}

// ================= repack: weights -> fragment-ordered buffers =================
__global__ __launch_bounds__(256) void repack_kernel(
    const float* __restrict__ saW, const float* __restrict__ saU,
    const float* __restrict__ saWa, const float* __restrict__ saUa,
    const float* __restrict__ saVa,
    const float* __restrict__ taU, const float* __restrict__ taW,
    const float* __restrict__ taWa, const float* __restrict__ taVa,
    unsigned short* __restrict__ F)
{
  int id = blockIdx.x*256 + threadIdx.x;
  if (id < B1G_ELEMS){          // gate: k 0-127 = saU(h), 128-191 = saW(xw)
    int k = id >> 9, n = id & 511;
    float v = (k < 128) ? saU[(size_t)k*NG + n] : saW[(size_t)(k-128)*NG + n];
    int kk = k >> 5, kw = k & 31, nt = n >> 4, nc = n & 15;
    int lane = ((kw >> 3) << 4) | nc, j = kw & 7;
    size_t off = ((size_t)(nt*6 + kk)*64 + lane)*8 + j;
    unsigned short hi = bf16rne(v);
    F[GH_OFF + off] = hi; F[GL_OFF + off] = bf16rne(v - bfval(hi));
  }
  if (id < B1A_ELEMS){          // attn: k 0-255 = saUa(h,c), 256-319 = saWa(x)
    int k = id >> 6, n = id & 63;
    float v = (k < 256) ? saUa[(size_t)k*DD + n] : saWa[(size_t)(k-256)*DD + n];
    int kt = k >> 5, kw = k & 31, nt = n >> 4, nc = n & 15;
    int lane = ((kw >> 3) << 4) | nc, j = kw & 7;
    size_t off = ((size_t)(nt*10 + kt)*64 + lane)*8 + j;
    unsigned short hi = bf16rne(v);
    F[AH_OFF + off] = hi; F[AL_OFF + off] = bf16rne(v - bfval(hi));
  }
  if (id < BVA_ELEMS){          // saVa 64x64
    int k = id >> 6, n = id & 63;
    float v = saVa[(size_t)k*DD + n];
    int kt = k >> 5, kw = k & 31, nt = n >> 4, nc = n & 15;
    int lane = ((kw >> 3) << 4) | nc, j = kw & 7;
    size_t off = ((size_t)(nt*2 + kt)*64 + lane)*8 + j;
    unsigned short hi = bf16rne(v);
    F[VH_OFF + off] = hi; F[VL_OFF + off] = bf16rne(v - bfval(hi));
  }
  if (id < B3_ELEMS){           // ph3: k 0-127 = taU(lh), 128-255 = taW(ha)
    int k = id >> 9, n = id & 511;
    float v = (k < HH) ? taU[(size_t)k*NG + n] : taW[(size_t)(k-HH)*NG + n];
    int kt = k >> 5, kw = k & 31, nt = n >> 4, nc = n & 15;
    int lane = ((kw >> 3) << 4) | nc, j = kw & 7;
    size_t off = ((size_t)(nt*8 + kt)*64 + lane)*8 + j;
    unsigned short hi = bf16rne(v);
    F[B3H_OFF + off] = hi; F[B3L_OFF + off] = bf16rne(v - bfval(hi));
  }
  if (id < BW_ELEMS){           // ph2 bf16 frags
    int k = id >> 7, n = id & 127;
    int kt = k >> 5, kw = k & 31, nt = n >> 4, nc = n & 15;
    int lane = ((kw >> 3) << 4) | nc, j = kw & 7;
    size_t off = ((size_t)(nt*4 + kt)*64 + lane)*8 + j;
    F[RW_OFF + off] = bf16rne(taWa[(size_t)k*SS + n]);
    F[RV_OFF + off] = bf16rne(taVa[(size_t)k*SS + n]);
  }
}

// ================= mf_ph1: spatial-attn LSTM, fully MFMA (round 13) =========
struct P1 {
  uint4 afh[12*64];    // 12K
  uint4 afl[12*64];    // 12K
  uint4 aah[2*64];     // 2K
  uint4 aal[2*64];     // 2K
  uint4 awh[2560];     // 40K  attn B hi (4 nt x 10 kt x 64)
  uint4 awl[2560];     // 40K  attn B lo
  uint4 vh[512];       // 8K   Va hi
  uint4 vl[512];       // 8K   Va lo
  float xx[M][DD];     // 2K
  float cc[M][HH];     // 4K
  float red[2][M][64]; // 4K
  float g[M][NG];      // 16K
  float sbias[NG];     // 2K
};                     // 152K -> 1 blk/CU
struct P2S { float A[32][HH]; float tmp[32][SS]; float bp[32][SS]; };  // fallback

__global__ __launch_bounds__(NT, 2) __attribute__((amdgpu_waves_per_eu(2, 2)))
void mf_ph1_kernel(
    const float* __restrict__ X,   const float* __restrict__ sab,
    const float* __restrict__ saba,
    const unsigned short* __restrict__ Fr,
    float* __restrict__ out, float* __restrict__ Hws)
{
  __shared__ P1 sm;
  const int tid = threadIdx.x;
  const int b0  = blockIdx.x * M;
  const int w   = tid >> 6, l = tid & 63;

  {
    uint4 z4 = make_uint4(0,0,0,0);
    for (int i = tid; i < 12*64; i += NT){ sm.afh[i] = z4; sm.afl[i] = z4; }
    if (tid < 2*64){ sm.aah[tid] = z4; sm.aal[tid] = z4; }
    for (int i = tid; i < M*HH; i += NT) ((float*)sm.cc)[i] = 0.f;
    sm.sbias[tid] = sab[tid];
    const uint4* sh = (const uint4*)(Fr + AH_OFF);
    const uint4* sl = (const uint4*)(Fr + AL_OFF);
    for (int i = tid; i < 2560; i += NT){ sm.awh[i] = sh[i]; sm.awl[i] = sl[i]; }
    sm.vh[tid] = ((const uint4*)(Fr + VH_OFF))[tid];
    sm.vl[tid] = ((const uint4*)(Fr + VL_OFF))[tid];
  }
  __syncthreads();
  if (tid < 128){   // x(0) + x-frags (tiles 8-9)
    int r = tid >> 4, d0 = (tid & 15)*4;
    float4 v = *(const float4*)(X + (size_t)(b0+r)*SS*DD + d0);
    *(float4*)&sm.xx[r][d0] = v;
    unsigned short* AFH = (unsigned short*)sm.afh;
    unsigned short* AFL = (unsigned short*)sm.afl;
    int kt = 8 + (d0 >> 5), lane = (((d0 & 31) >> 3) << 4) | r, jj0 = d0 & 7;
    float vv[4] = {v.x, v.y, v.z, v.w};
#pragma unroll
    for (int p = 0; p < 4; ++p){
      unsigned short h_ = bf16rne(vv[p]);
      AFH[(kt*64 + lane)*8 + jj0 + p] = h_;
      AFL[(kt*64 + lane)*8 + jj0 + p] = bf16rne(vv[p] - bfval(h_));
    }
  }
  __syncthreads();

  for (int t = 0; t < SS; ++t){
    // ---- P1: attn MFMA (B from LDS) -> red  +  gate-h MFMA (kk0-3) -> accg ----
    f32x4 accg[4];
    {
      f32x4 zf = {0.f,0.f,0.f,0.f};
#pragma unroll
      for (int n4 = 0; n4 < 4; ++n4) accg[n4] = zf;
    }
    {
      const int nt = w & 3, kh = w >> 2;
      f32x4 a0 = {0.f,0.f,0.f,0.f}, a1 = {0.f,0.f,0.f,0.f};
#pragma unroll
      for (int q = 0; q < 5; ++q){
        const int kt = kh*5 + q;
        bf16x8 ah = as_bf(sm.afh[kt*64 + l]);
        bf16x8 av = as_bf(sm.afl[kt*64 + l]);
        bf16x8 bh = as_bf(sm.awh[(nt*10 + kt)*64 + l]);
        bf16x8 bl = as_bf(sm.awl[(nt*10 + kt)*64 + l]);
        if (q & 1){
          a1 = __builtin_amdgcn_mfma_f32_16x16x32_bf16(ah, bh, a1, 0, 0, 0);
          a1 = __builtin_amdgcn_mfma_f32_16x16x32_bf16(av, bh, a1, 0, 0, 0);
          a1 = __builtin_amdgcn_mfma_f32_16x16x32_bf16(ah, bl, a1, 0, 0, 0);
        } else {
          a0 = __builtin_amdgcn_mfma_f32_16x16x32_bf16(ah, bh, a0, 0, 0, 0);
          a0 = __builtin_amdgcn_mfma_f32_16x16x32_bf16(av, bh, a0, 0, 0, 0);
          a0 = __builtin_amdgcn_mfma_f32_16x16x32_bf16(ah, bl, a0, 0, 0, 0);
        }
      }
      f32x4 acc = a0 + a1;
      const int row0 = (l >> 4)*4, c0 = l & 15;
      if (row0 < 8){
#pragma unroll
        for (int jj = 0; jj < 4; ++jj)
          sm.red[kh][row0+jj][nt*16 + c0] = acc[jj];
      }
      const uint4* GH = (const uint4*)(Fr + GH_OFF);
      const uint4* GL = (const uint4*)(Fr + GL_OFF);
#pragma unroll
      for (int kk = 0; kk < 4; ++kk){
        bf16x8 ah = as_bf(sm.afh[kk*64 + l]);
        bf16x8 av = as_bf(sm.afl[kk*64 + l]);
#pragma unroll
        for (int n4 = 0; n4 < 4; ++n4){
          const int ntg = w*4 + n4;
          bf16x8 bh = as_bf(GH[(ntg*6 + kk)*64 + l]);
          bf16x8 bl = as_bf(GL[(ntg*6 + kk)*64 + l]);
          accg[n4] = __builtin_amdgcn_mfma_f32_16x16x32_bf16(ah, bh, accg[n4], 0, 0, 0);
          accg[n4] = __builtin_amdgcn_mfma_f32_16x16x32_bf16(av, bh, accg[n4], 0, 0, 0);
          accg[n4] = __builtin_amdgcn_mfma_f32_16x16x32_bf16(ah, bl, accg[n4], 0, 0, 0);
        }
      }
    }
    __syncthreads();

    // ---- P2: combine + bias + tanh -> a-frags ----
    {
      const int r = w, col = l;
      float s = sm.red[0][r][col] + sm.red[1][r][col] + saba[col];
      float av = tanhx(s);
      unsigned short h_ = bf16rne(av);
      int kt = col >> 5, lane = (((col & 31) >> 3) << 4) | r, jj = col & 7;
      ((unsigned short*)sm.aah)[(kt*64 + lane)*8 + jj] = h_;
      ((unsigned short*)sm.aal)[(kt*64 + lane)*8 + jj] = bf16rne(av - bfval(h_));
    }
    __syncthreads();

    // ---- P3: GEMM2 MFMA  av = a @ saVa  (all LDS) ----
    {
      const int nt = w & 3, kt = w >> 2;   // kt 0-1
      f32x4 acc = {0.f,0.f,0.f,0.f};
      bf16x8 ah = as_bf(sm.aah[kt*64 + l]);
      bf16x8 av = as_bf(sm.aal[kt*64 + l]);
      bf16x8 bh = as_bf(sm.vh[(nt*2 + kt)*64 + l]);
      bf16x8 bl = as_bf(sm.vl[(nt*2 + kt)*64 + l]);
      acc = __builtin_amdgcn_mfma_f32_16x16x32_bf16(ah, bh, acc, 0, 0, 0);
      acc = __builtin_amdgcn_mfma_f32_16x16x32_bf16(av, bh, acc, 0, 0, 0);
      acc = __builtin_amdgcn_mfma_f32_16x16x32_bf16(ah, bl, acc, 0, 0, 0);
      const int row0 = (l >> 4)*4, c0 = l & 15;
      if (row0 < 8){
#pragma unroll
        for (int jj = 0; jj < 4; ++jj)
          sm.red[kt][row0+jj][nt*16 + c0] = acc[jj];
      }
    }
    __syncthreads();

    // ---- P4: softmax + alphas out + xw-frags (tiles 10-11) ----
    {
      const int r = w, col = l;
      float s = sm.red[0][r][col] + sm.red[1][r][col];
      float mm = wmax64(s);
      float e  = __expf(s - mm);
      float alv = e * (1.0f / wsum64(e));
      out[A_OFF + (size_t)t*BB*DD + (size_t)(b0+r)*DD + col] = alv;
      float xwv = alv * sm.xx[r][col];
      unsigned short h_ = bf16rne(xwv);
      int kt = 10 + (col >> 5), lane = (((col & 31) >> 3) << 4) | r, jj = col & 7;
      ((unsigned short*)sm.afh)[(kt*64 + lane)*8 + jj] = h_;
      ((unsigned short*)sm.afl)[(kt*64 + lane)*8 + jj] = bf16rne(xwv - bfval(h_));
    }
    __syncthreads();

    // ---- P5: gates xw-part (kk4-5) + x(t+1) prefetch issue ----
    float4 pf;
    const bool dox = (tid < 128) && (t + 1 < SS);
    if (dox){
      int r = tid >> 4, d0 = (tid & 15)*4;
      pf = *(const float4*)(X + (size_t)(b0+r)*SS*DD + (size_t)(t+1)*DD + d0);
    }
    {
      const uint4* GH = (const uint4*)(Fr + GH_OFF);
      const uint4* GL = (const uint4*)(Fr + GL_OFF);
#pragma unroll
      for (int kk = 4; kk < 6; ++kk){
        const int afi = kk + 6;   // 10, 11
        bf16x8 ah = as_bf(sm.afh[afi*64 + l]);
        bf16x8 av = as_bf(sm.afl[afi*64 + l]);
#pragma unroll
        for (int n4 = 0; n4 < 4; ++n4){
          const int ntg = w*4 + n4;
          bf16x8 bh = as_bf(GH[(ntg*6 + kk)*64 + l]);
          bf16x8 bl = as_bf(GL[(ntg*6 + kk)*64 + l]);
          accg[n4] = __builtin_amdgcn_mfma_f32_16x16x32_bf16(ah, bh, accg[n4], 0, 0, 0);
          accg[n4] = __builtin_amdgcn_mfma_f32_16x16x32_bf16(av, bh, accg[n4], 0, 0, 0);
          accg[n4] = __builtin_amdgcn_mfma_f32_16x16x32_bf16(ah, bl, accg[n4], 0, 0, 0);
        }
      }
      const int row0 = (l >> 4)*4, c0 = l & 15;
      if (row0 < 8){
#pragma unroll
        for (int n4 = 0; n4 < 4; ++n4){
          int col = w*64 + n4*16 + c0;
          float b = sm.sbias[col];
#pragma unroll
          for (int jj = 0; jj < 4; ++jj)
            sm.g[row0+jj][col] = accg[n4][jj] + b;
        }
      }
    }
    __syncthreads();

    // ---- P6: pointwise + h/c frag build + H store + x(t+1) commit ----
    {
      unsigned short* AFH = (unsigned short*)sm.afh;
      unsigned short* AFL = (unsigned short*)sm.afl;
#pragma unroll
      for (int h2 = 0; h2 < 2; ++h2){
        int idx = h2*NT + tid;
        int r = idx >> 7, j = idx & 127;
        float iv = sigf (sm.g[r][j]);
        float fv = sigf (sm.g[r][j + 128]);
        float gv = tanhx(sm.g[r][j + 256]);
        float ov = sigf (sm.g[r][j + 384]);
        float cn = fv * sm.cc[r][j] + iv * gv;
        float hn = ov * tanhx(cn);
        sm.cc[r][j] = cn;
        Hws[(size_t)(b0+r)*SS*HH + (size_t)t*HH + j] = hn;
        int lane = (((j & 31) >> 3) << 4) | r, jj = j & 7;
        int ktH = j >> 5, ktC = 4 + (j >> 5);
        unsigned short hh_ = bf16rne(hn);
        unsigned short ch_ = bf16rne(cn);
        AFH[(ktH*64 + lane)*8 + jj] = hh_;
        AFL[(ktH*64 + lane)*8 + jj] = bf16rne(hn - bfval(hh_));
        AFH[(ktC*64 + lane)*8 + jj] = ch_;
        AFL[(ktC*64 + lane)*8 + jj] = bf16rne(cn - bfval(ch_));
      }
      if (dox){
        int r = tid >> 4, d0 = (tid & 15)*4;
        *(float4*)&sm.xx[r][d0] = pf;
        int kt = 8 + (d0 >> 5), lane = (((d0 & 31) >> 3) << 4) | r, jj0 = d0 & 7;
        float vv[4] = {pf.x, pf.y, pf.z, pf.w};
#pragma unroll
        for (int p = 0; p < 4; ++p){
          unsigned short h_ = bf16rne(vv[p]);
          AFH[(kt*64 + lane)*8 + jj0 + p] = h_;
          AFL[(kt*64 + lane)*8 + jj0 + p] = bf16rne(vv[p] - bfval(h_));
        }
      }
    }
    __syncthreads();
  }
}

// ================= ph2g: betas + h_att + G0, all-MFMA, fused (tier-3) ==========
// Block b: betas from H[b]; h_att frags written DIRECTLY to fA(hi)/fB(lo);
// G0[b][t][:] = h_att @ taW + tab in 4x128-col passes via SG staging.
struct PH2G {
  union { unsigned short S[128][136]; float SG[128][132]; } u;  // 67.6K
  uint4 fA[8][4][64];           // 32K
  uint4 fB[8][4][64];           // 32K
  float bias[SS];
};                              // ~132K -> 1 blk/CU

__global__ __launch_bounds__(NT, 2) void ph2g_kernel(
    const float* __restrict__ taba, const unsigned short* __restrict__ Fr,
    const float* __restrict__ tab,
    float* __restrict__ out, float* __restrict__ Hws, float* __restrict__ G0)
{
  __shared__ PH2G sm;
  const int tid = threadIdx.x;
  const int b   = blockIdx.x;
  const int w   = tid >> 6, l = tid & 63;
  const int g   = l >> 4, c0 = l & 15;
  const float* Hb = Hws + (size_t)b * SS * HH;

  if (tid < SS) sm.bias[tid] = taba[tid];
  {
    const float4* src = (const float4*)Hb;
#pragma unroll
    for (int i = 0; i < 8; ++i){
      int fidx = i*NT + tid;
      float4 v = src[fidx];
      int e0 = fidx*4, row = e0 >> 7, col = e0 & 127;
      sm.u.S[row][col+0] = bf16rne(v.x);
      sm.u.S[row][col+1] = bf16rne(v.y);
      sm.u.S[row][col+2] = bf16rne(v.z);
      sm.u.S[row][col+3] = bf16rne(v.w);
    }
  }
  __syncthreads();

#pragma unroll
  for (int i = 0; i < 4; ++i){
    int slot = i*NT + tid;
    int mt = slot >> 8, kt = (slot >> 6) & 3, ll = slot & 63;
    int row = mt*16 + (ll & 15), k0 = kt*32 + (ll >> 4)*8;
    ((uint4*)sm.fA)[slot] = *(const uint4*)&sm.u.S[row][k0];
  }
#pragma unroll
  for (int i = 0; i < 4; ++i){
    int slot = i*NT + tid;
    int nt = slot >> 8, kt = (slot >> 6) & 3, ll = slot & 63;
    int col = nt*16 + (ll & 15), s0 = kt*32 + (ll >> 4)*8;
    unsigned u[4];
#pragma unroll
    for (int p = 0; p < 4; ++p)
      u[p] = (unsigned)sm.u.S[s0+2*p][col] | ((unsigned)sm.u.S[s0+2*p+1][col] << 16);
    ((uint4*)sm.fB)[slot] = make_uint4(u[0], u[1], u[2], u[3]);
  }
  __syncthreads();

  f32x4 acc[8];
  f32x4 zero4 = {0.f, 0.f, 0.f, 0.f};

  // ---- GEMM1: tmp = tanh(H @ taWa + ba) ----
#pragma unroll
  for (int nt = 0; nt < 8; ++nt) acc[nt] = zero4;
  {
    const uint4* BW = (const uint4*)(Fr + RW_OFF);
#pragma unroll
    for (int kt = 0; kt < 4; ++kt){
      bf16x8 a = as_bf(sm.fA[w][kt][l]);
#pragma unroll
      for (int nt = 0; nt < 8; ++nt){
        bf16x8 bv = as_bf(BW[(nt*4 + kt)*64 + l]);
        acc[nt] = __builtin_amdgcn_mfma_f32_16x16x32_bf16(a, bv, acc[nt], 0, 0, 0);
      }
    }
  }
#pragma unroll
  for (int nt = 0; nt < 8; ++nt){
    int col = nt*16 + c0;
    float bv = sm.bias[col];
#pragma unroll
    for (int j = 0; j < 4; ++j)
      sm.u.S[w*16 + g*4 + j][col] = bf16rne(tanhx(acc[nt][j] + bv));
  }
  __syncthreads();

  // ---- rebuild fA from S (tmp) ----
#pragma unroll
  for (int i = 0; i < 4; ++i){
    int slot = i*NT + tid;
    int mt = slot >> 8, kt = (slot >> 6) & 3, ll = slot & 63;
    int row = mt*16 + (ll & 15), k0 = kt*32 + (ll >> 4)*8;
    ((uint4*)sm.fA)[slot] = *(const uint4*)&sm.u.S[row][k0];
  }
  __syncthreads();

  // ---- GEMM2: bp = tmp @ taVa ----
#pragma unroll
  for (int nt = 0; nt < 8; ++nt) acc[nt] = zero4;
  {
    const uint4* BV = (const uint4*)(Fr + RV_OFF);
#pragma unroll
    for (int kt = 0; kt < 4; ++kt){
      bf16x8 a = as_bf(sm.fA[w][kt][l]);
#pragma unroll
      for (int nt = 0; nt < 8; ++nt){
        bf16x8 bv = as_bf(BV[(nt*4 + kt)*64 + l]);
        acc[nt] = __builtin_amdgcn_mfma_f32_16x16x32_bf16(a, bv, acc[nt], 0, 0, 0);
      }
    }
  }

  // ---- in-register softmax + betas out ----
#pragma unroll
  for (int j = 0; j < 4; ++j){
    float m = acc[0][j];
#pragma unroll
    for (int nt = 1; nt < 8; ++nt) m = fmaxf(m, acc[nt][j]);
#pragma unroll
    for (int ms = 1; ms < 16; ms <<= 1) m = fmaxf(m, __shfl_xor(m, ms, 64));
    float e[8], s = 0.f;
#pragma unroll
    for (int nt = 0; nt < 8; ++nt){ e[nt] = __expf(acc[nt][j] - m); s += e[nt]; }
#pragma unroll
    for (int ms = 1; ms < 16; ms <<= 1) s += __shfl_xor(s, ms, 64);
    float inv = 1.0f / s;
    int row = w*16 + g*4 + j;
    size_t bo = BETA_OFF + (size_t)row*BB*SS + (size_t)b*SS;
#pragma unroll
    for (int nt = 0; nt < 8; ++nt){
      float bv = e[nt] * inv;
      out[bo + nt*16 + c0] = bv;
      sm.u.S[row][nt*16 + c0] = bf16rne(bv);
    }
  }
  __syncthreads();

  // ---- rebuild fA from S (beta) ----
#pragma unroll
  for (int i = 0; i < 4; ++i){
    int slot = i*NT + tid;
    int mt = slot >> 8, kt = (slot >> 6) & 3, ll = slot & 63;
    int row = mt*16 + (ll & 15), k0 = kt*32 + (ll >> 4)*8;
    ((uint4*)sm.fA)[slot] = *(const uint4*)&sm.u.S[row][k0];
  }
  __syncthreads();

  // ---- GEMM3: h_att = beta @ H ----
#pragma unroll
  for (int nt = 0; nt < 8; ++nt) acc[nt] = zero4;
#pragma unroll
  for (int kt = 0; kt < 4; ++kt){
    bf16x8 a = as_bf(sm.fA[w][kt][l]);
#pragma unroll
    for (int nt = 0; nt < 8; ++nt){
      bf16x8 bv = as_bf(sm.fB[nt][kt][l]);
      acc[nt] = __builtin_amdgcn_mfma_f32_16x16x32_bf16(a, bv, acc[nt], 0, 0, 0);
    }
  }
  __syncthreads();   // cross-wave fA/fB reads done before overwrite

  // ---- direct h_att split-bf16 frag write: hi->fA, lo->fB (own-wave region) ----
  {
    unsigned short* FH = (unsigned short*)sm.fA;
    unsigned short* FL = (unsigned short*)sm.fB;
    const int jj = c0 & 7;
#pragma unroll
    for (int nt = 0; nt < 8; ++nt){
      const int kt = nt >> 1;
      const int laneb = ((nt & 1)*2 + (c0 >> 3))*16;
#pragma unroll
      for (int j = 0; j < 4; ++j){
        int lane = laneb + (g*4 + j);
        float v = acc[nt][j];
        unsigned short h_ = bf16rne(v);
        size_t idxs = ((size_t)(w*4 + kt)*64 + lane)*8 + jj;
        FH[idxs] = h_;
        FL[idxs] = bf16rne(v - bfval(h_));
      }
    }
  }
  // no barrier: G0 passes read only own-wave fA[w]/fB[w] (within-wave LDS order)

  // ---- G0 = h_att @ taW + tab, 4 passes of 128 cols; SG staging ----
  const uint4* BH = (const uint4*)(Fr + B3H_OFF);
  const uint4* BL = (const uint4*)(Fr + B3L_OFF);
  const size_t r0 = (size_t)b * SS;
#pragma unroll
  for (int p = 0; p < 4; ++p){
    f32x4 acc2[8];
#pragma unroll
    for (int q = 0; q < 8; ++q) acc2[q] = zero4;
#pragma unroll
    for (int q = 0; q < 8; ++q){
      const int ntg = p*8 + q;            // 0..31
#pragma unroll
      for (int kt = 0; kt < 4; ++kt){     // taW = kt 4-7 of B3
        bf16x8 ah = as_bf(sm.fA[w][kt][l]);
        bf16x8 av = as_bf(sm.fB[w][kt][l]);
        bf16x8 bh = as_bf(BH[(ntg*8 + 4 + kt)*64 + l]);
        bf16x8 bl = as_bf(BL[(ntg*8 + 4 + kt)*64 + l]);
        acc2[q] = __builtin_amdgcn_mfma_f32_16x16x32_bf16(ah, bh, acc2[q], 0, 0, 0);
        acc2[q] = __builtin_amdgcn_mfma_f32_16x16x32_bf16(av, bh, acc2[q], 0, 0, 0);
        acc2[q] = __builtin_amdgcn_mfma_f32_16x16x32_bf16(ah, bl, acc2[q], 0, 0, 0);
      }
    }
#pragma unroll
    for (int q = 0; q < 8; ++q){
      float tb = tab[p*128 + q*16 + c0];
#pragma unroll
      for (int j = 0; j < 4; ++j)
        sm.u.SG[w*16 + g*4 + j][q*16 + c0] = acc2[q][j] + tb;
    }
    __syncthreads();
#pragma unroll
    for (int it = 0; it < 8; ++it){
      int flat = it*NT + tid;      // 4096 float4 = 128 rows x 32
      int row = flat >> 5, cq = flat & 31;
      *(float4*)(G0 + (r0 + row)*NG + p*128 + cq*4) = *(const float4*)&sm.u.SG[row][cq*4];
    }
    __syncthreads();
  }
}

// ================= ph2 (tier-2, writes h_att to Hws; round-12 version) =========
struct PH2SM {
  union {
    struct { uint4 fA[8][4][64]; uint4 fB[8][4][64]; } f;
    float HO[128][132];
  } u;
  unsigned short S[128][136];
  float bias[SS];
};

__global__ __launch_bounds__(NT, 2) void ph2_kernel(
    const float* __restrict__ taba, const unsigned short* __restrict__ Fr,
    float* __restrict__ out, float* __restrict__ Hws)
{
  __shared__ PH2SM sm;
  const int tid = threadIdx.x;
  const int b   = blockIdx.x;
  const int w   = tid >> 6, l = tid & 63;
  const int g   = l >> 4, c0 = l & 15;
  float* Hb = Hws + (size_t)b * SS * HH;

  if (tid < SS) sm.bias[tid] = taba[tid];
  {
    const float4* src = (const float4*)Hb;
#pragma unroll
    for (int i = 0; i < 8; ++i){
      int fidx = i*NT + tid;
      float4 v = src[fidx];
      int e0 = fidx*4, row = e0 >> 7, col = e0 & 127;
      sm.S[row][col+0] = bf16rne(v.x);
      sm.S[row][col+1] = bf16rne(v.y);
      sm.S[row][col+2] = bf16rne(v.z);
      sm.S[row][col+3] = bf16rne(v.w);
    }
  }
  __syncthreads();

#pragma unroll
  for (int i = 0; i < 4; ++i){
    int slot = i*NT + tid;
    int mt = slot >> 8, kt = (slot >> 6) & 3, ll = slot & 63;
    int row = mt*16 + (ll & 15), k0 = kt*32 + (ll >> 4)*8;
    ((uint4*)sm.u.f.fA)[slot] = *(const uint4*)&sm.S[row][k0];
  }
#pragma unroll
  for (int i = 0; i < 4; ++i){
    int slot = i*NT + tid;
    int nt = slot >> 8, kt = (slot >> 6) & 3, ll = slot & 63;
    int col = nt*16 + (ll & 15), s0 = kt*32 + (ll >> 4)*8;
    unsigned u[4];
#pragma unroll
    for (int p = 0; p < 4; ++p)
      u[p] = (unsigned)sm.S[s0+2*p][col] | ((unsigned)sm.S[s0+2*p+1][col] << 16);
    ((uint4*)sm.u.f.fB)[slot] = make_uint4(u[0], u[1], u[2], u[3]);
  }
  __syncthreads();

  f32x4 acc[8];
  f32x4 zero4 = {0.f, 0.f, 0.f, 0.f};

#pragma unroll
  for (int nt = 0; nt < 8; ++nt) acc[nt] = zero4;
  {
    const uint4* BW = (const uint4*)(Fr + RW_OFF);
#pragma unroll
    for (int kt = 0; kt < 4; ++kt){
      bf16x8 a = as_bf(sm.u.f.fA[w][kt][l]);
#pragma unroll
      for (int nt = 0; nt < 8; ++nt){
        bf16x8 bv = as_bf(BW[(nt*4 + kt)*64 + l]);
        acc[nt] = __builtin_amdgcn_mfma_f32_16x16x32_bf16(a, bv, acc[nt], 0, 0, 0);
      }
    }
  }
#pragma unroll
  for (int nt = 0; nt < 8; ++nt){
    int col = nt*16 + c0;
    float bv = sm.bias[col];
#pragma unroll
    for (int j = 0; j < 4; ++j)
      sm.S[w*16 + g*4 + j][col] = bf16rne(tanhx(acc[nt][j] + bv));
  }
  __syncthreads();

#pragma unroll
  for (int i = 0; i < 4; ++i){
    int slot = i*NT + tid;
    int mt = slot >> 8, kt = (slot >> 6) & 3, ll = slot & 63;
    int row = mt*16 + (ll & 15), k0 = kt*32 + (ll >> 4)*8;
    ((uint4*)sm.u.f.fA)[slot] = *(const uint4*)&sm.S[row][k0];
  }
  __syncthreads();

#pragma unroll
  for (int nt = 0; nt < 8; ++nt) acc[nt] = zero4;
  {
    const uint4* BV = (const uint4*)(Fr + RV_OFF);
#pragma unroll
    for (int kt = 0; kt < 4; ++kt){
      bf16x8 a = as_bf(sm.u.f.fA[w][kt][l]);
#pragma unroll
      for (int nt = 0; nt < 8; ++nt){
        bf16x8 bv = as_bf(BV[(nt*4 + kt)*64 + l]);
        acc[nt] = __builtin_amdgcn_mfma_f32_16x16x32_bf16(a, bv, acc[nt], 0, 0, 0);
      }
    }
  }

#pragma unroll
  for (int j = 0; j < 4; ++j){
    float m = acc[0][j];
#pragma unroll
    for (int nt = 1; nt < 8; ++nt) m = fmaxf(m, acc[nt][j]);
#pragma unroll
    for (int ms = 1; ms < 16; ms <<= 1) m = fmaxf(m, __shfl_xor(m, ms, 64));
    float e[8], s = 0.f;
#pragma unroll
    for (int nt = 0; nt < 8; ++nt){ e[nt] = __expf(acc[nt][j] - m); s += e[nt]; }
#pragma unroll
    for (int ms = 1; ms < 16; ms <<= 1) s += __shfl_xor(s, ms, 64);
    float inv = 1.0f / s;
    int row = w*16 + g*4 + j;
    size_t bo = BETA_OFF + (size_t)row*BB*SS + (size_t)b*SS;
#pragma unroll
    for (int nt = 0; nt < 8; ++nt){
      float bv = e[nt] * inv;
      out[bo + nt*16 + c0] = bv;
      sm.S[row][nt*16 + c0] = bf16rne(bv);
    }
  }
  __syncthreads();

#pragma unroll
  for (int i = 0; i < 4; ++i){
    int slot = i*NT + tid;
    int mt = slot >> 8, kt = (slot >> 6) & 3, ll = slot & 63;
    int row = mt*16 + (ll & 15), k0 = kt*32 + (ll >> 4)*8;
    ((uint4*)sm.u.f.fA)[slot] = *(const uint4*)&sm.S[row][k0];
  }
  __syncthreads();

#pragma unroll
  for (int nt = 0; nt < 8; ++nt) acc[nt] = zero4;
#pragma unroll
  for (int kt = 0; kt < 4; ++kt){
    bf16x8 a = as_bf(sm.u.f.fA[w][kt][l]);
#pragma unroll
    for (int nt = 0; nt < 8; ++nt){
      bf16x8 bv = as_bf(sm.u.f.fB[nt][kt][l]);
      acc[nt] = __builtin_amdgcn_mfma_f32_16x16x32_bf16(a, bv, acc[nt], 0, 0, 0);
    }
  }
  __syncthreads();

#pragma unroll
  for (int nt = 0; nt < 8; ++nt)
#pragma unroll
    for (int j = 0; j < 4; ++j)
      sm.u.HO[w*16 + g*4 + j][nt*16 + c0] = acc[nt][j];
  __syncthreads();
#pragma unroll
  for (int it = 0; it < 8; ++it){
    int flat = it*NT + tid;
    int row = flat >> 5, cq = flat & 31;
    *(float4*)(Hb + (size_t)row*HH + cq*4) = *(const float4*)&sm.u.HO[row][cq*4];
  }
}

// ================= mf_ph3h: temporal LSTM, K=128, 2 barriers/step ==============
// fc-reduce folded into Q2 (per-wave partials in red); yp combined in Q1.
struct P3H {
  uint4 afh[4*64];     // 4K
  uint4 afl[4*64];     // 4K
  float lh[M][HH];     // 4K
  float lc[M][HH];     // 4K
  float g[M][NG];      // 16K
  float wy[NG];        // 2K
  float fcv[HH];
  float red[M][2];     // fc partials (row, half)
  float ypinit[M];
  float fcb0;
};
union __align__(16) SMCH { P3H s; float pad[21504]; };   // 84K -> 1 blk/CU

__global__ __launch_bounds__(NT, 2) __attribute__((amdgpu_waves_per_eu(2, 2)))
void mf_ph3h_kernel(
    const float* __restrict__ X, const unsigned short* __restrict__ Fr,
    const float* __restrict__ G0,
    const float* __restrict__ taWy,
    const float* __restrict__ fcw, const float* __restrict__ fcb,
    float* __restrict__ out)
{
  __shared__ SMCH sm;
  const int tid = threadIdx.x;
  const int b0  = blockIdx.x * M;
  const int w   = tid >> 6, l = tid & 63;
  const int row0 = (l >> 4)*4, c0 = l & 15;

  {
    uint4 z4 = make_uint4(0,0,0,0);
    if (tid < 4*64){ sm.s.afh[tid] = z4; sm.s.afl[tid] = z4; }
    for (int i = tid; i < M*HH; i += NT){
      ((float*)sm.s.lh)[i] = 0.f; ((float*)sm.s.lc)[i] = 0.f;
    }
    sm.s.wy[tid] = taWy[tid];
    if (tid < HH) sm.s.fcv[tid] = fcw[tid];
    if (tid < M)  sm.s.ypinit[tid] = X[(size_t)(b0+tid)*SS*DD + (DD-1)];
    if (tid == 0) sm.s.fcb0 = fcb[0];
  }
  // preload G0 for t=0 (loop-carried)
  float g0v[16];
  if (row0 < 8){
#pragma unroll
    for (int n4 = 0; n4 < 4; ++n4)
#pragma unroll
      for (int j = 0; j < 4; ++j)
        g0v[n4*4+j] = G0[((size_t)(b0+row0+j)*SS + 0)*NG + (w*64 + n4*16 + c0)];
  }
  __syncthreads();

  for (int t = 0; t < SS; ++t){
    // ---- Q1: yp combine + gates MFMA (K=128) ----
    {
      float ypr[4];
      if (row0 < 8){
#pragma unroll
        for (int j = 0; j < 4; ++j){
          int r = row0 + j;
          ypr[j] = (t == 0) ? sm.s.ypinit[r]
                            : (sm.s.red[r][0] + sm.s.red[r][1] + sm.s.fcb0);
        }
      }
      f32x4 zero4 = {0.f,0.f,0.f,0.f};
      f32x4 acc[4];
#pragma unroll
      for (int n4 = 0; n4 < 4; ++n4) acc[n4] = zero4;
      const uint4* BH = (const uint4*)(Fr + B3H_OFF);
      const uint4* BL = (const uint4*)(Fr + B3L_OFF);
#pragma unroll
      for (int kt = 0; kt < 4; ++kt){      // taU = kt 0-3
        bf16x8 ah = as_bf(sm.s.afh[kt*64 + l]);
        bf16x8 av = as_bf(sm.s.afl[kt*64 + l]);
#pragma unroll
        for (int n4 = 0; n4 < 4; ++n4){
          const int ntg = w*4 + n4;
          bf16x8 bh = as_bf(BH[(ntg*8 + kt)*64 + l]);
          bf16x8 bl = as_bf(BL[(ntg*8 + kt)*64 + l]);
          acc[n4] = __builtin_amdgcn_mfma_f32_16x16x32_bf16(ah, bh, acc[n4], 0, 0, 0);
          acc[n4] = __builtin_amdgcn_mfma_f32_16x16x32_bf16(av, bh, acc[n4], 0, 0, 0);
          acc[n4] = __builtin_amdgcn_mfma_f32_16x16x32_bf16(ah, bl, acc[n4], 0, 0, 0);
        }
      }
      if (row0 < 8){
#pragma unroll
        for (int n4 = 0; n4 < 4; ++n4){
          int col = w*64 + n4*16 + c0;
          float wv = sm.s.wy[col];
#pragma unroll
          for (int j = 0; j < 4; ++j)
            sm.s.g[row0+j][col] = acc[n4][j] + g0v[n4*4+j] + ypr[j]*wv;
        }
      }
    }
    __syncthreads();

    // ---- Q2: G0(t+1) issue + pointwise + lh-frags + fc partials ----
    float g0n[16];
    const bool dog = (t + 1 < SS) && (row0 < 8);
    if (dog){
#pragma unroll
      for (int n4 = 0; n4 < 4; ++n4)
#pragma unroll
        for (int j = 0; j < 4; ++j)
          g0n[n4*4+j] = G0[((size_t)(b0+row0+j)*SS + (t+1))*NG + (w*64 + n4*16 + c0)];
    }
    {
      unsigned short* AFH = (unsigned short*)sm.s.afh;
      unsigned short* AFL = (unsigned short*)sm.s.afl;
#pragma unroll
      for (int h2 = 0; h2 < 2; ++h2){
        int idx = h2*NT + tid;
        int r = idx >> 7, j = idx & 127;
        float iv = sigf (sm.s.g[r][j]);
        float fv = sigf (sm.s.g[r][j + 128]);
        float gv = tanhx(sm.s.g[r][j + 256]);
        float ov = sigf (sm.s.g[r][j + 384]);
        float cn = fv * sm.s.lc[r][j] + iv * gv;
        float hn = ov * tanhx(cn);
        sm.s.lc[r][j] = cn; sm.s.lh[r][j] = hn;
        int kt = j >> 5, lane = (((j & 31) >> 3) << 4) | r, jj = j & 7;
        unsigned short h_ = bf16rne(hn);
        AFH[(kt*64 + lane)*8 + jj] = h_;
        AFL[(kt*64 + lane)*8 + jj] = bf16rne(hn - bfval(h_));
        // fc partial: whole wave shares r; j spans a 64-col half
        float ps = hn * sm.s.fcv[j];
        ps = wsum64(ps);
        if (l == 0) sm.s.red[r][w & 1] = ps;
      }
    }
    if (dog){
#pragma unroll
      for (int q = 0; q < 16; ++q) g0v[q] = g0n[q];
    }
    __syncthreads();
  }

  if (tid < M) out[b0 + tid] = sm.s.red[tid][0] + sm.s.red[tid][1] + sm.s.fcb0;
}

// ================= mf_ph3full: K=256 variant (tier-2 fallback) ==========
struct P3 {
  uint4 afh[8*64];
  uint4 afl[8*64];
  float lh[M][HH];
  float lc[M][HH];
  float g[M][NG];
  float sb[NG];
  float wy[NG];
  float fcv[HH];
  float yp[M];
};
union __align__(16) SMC { P3 s; float pad[21504]; };

__global__ __launch_bounds__(NT, 2) void mf_ph3_kernel(
    const float* __restrict__ X, const float* __restrict__ Ha,
    const unsigned short* __restrict__ Fr,
    const float* __restrict__ tab, const float* __restrict__ taWy,
    const float* __restrict__ fcw, const float* __restrict__ fcb,
    float* __restrict__ out)
{
  __shared__ SMC sm;
  const int tid = threadIdx.x;
  const int b0  = blockIdx.x * M;
  const int w   = tid >> 6, l = tid & 63;

  {
    uint4 z4 = make_uint4(0,0,0,0);
    sm.s.afh[tid] = z4; sm.s.afl[tid] = z4;
    for (int i = tid; i < M*HH; i += NT){
      ((float*)sm.s.lh)[i] = 0.f; ((float*)sm.s.lc)[i] = 0.f;
    }
    sm.s.sb[tid] = tab[tid];
    sm.s.wy[tid] = taWy[tid];
    if (tid < HH) sm.s.fcv[tid] = fcw[tid];
    if (tid < M)  sm.s.yp[tid] = X[(size_t)(b0+tid)*SS*DD + (DD-1)];
  }
  __syncthreads();
  if (tid < 256){
    int r = tid >> 5, d0 = (tid & 31)*4;
    float4 v = *(const float4*)(Ha + (size_t)(b0+r)*SS*HH + d0);
    unsigned short* AFH = (unsigned short*)sm.s.afh;
    unsigned short* AFL = (unsigned short*)sm.s.afl;
    int kt = 4 + (d0 >> 5), lane = (((d0 & 31) >> 3) << 4) | r, jj0 = d0 & 7;
    float vv[4] = {v.x, v.y, v.z, v.w};
#pragma unroll
    for (int p = 0; p < 4; ++p){
      unsigned short h_ = bf16rne(vv[p]);
      AFH[(kt*64 + lane)*8 + jj0 + p] = h_;
      AFL[(kt*64 + lane)*8 + jj0 + p] = bf16rne(vv[p] - bfval(h_));
    }
  }
  __syncthreads();

  for (int t = 0; t < SS; ++t){
    float4 pf;
    const bool dop = (tid < 256) && (t + 1 < SS);
    if (dop){
      int r = tid >> 5, d0 = (tid & 31)*4;
      pf = *(const float4*)(Ha + (size_t)(b0+r)*SS*HH + (size_t)(t+1)*HH + d0);
    }
    {
      f32x4 zero4 = {0.f,0.f,0.f,0.f};
      f32x4 acc[4];
#pragma unroll
      for (int n4 = 0; n4 < 4; ++n4) acc[n4] = zero4;
      const uint4* BH = (const uint4*)(Fr + B3H_OFF);
      const uint4* BL = (const uint4*)(Fr + B3L_OFF);
#pragma unroll
      for (int kt = 0; kt < 8; ++kt){
        bf16x8 ah = as_bf(sm.s.afh[kt*64 + l]);
        bf16x8 av = as_bf(sm.s.afl[kt*64 + l]);
#pragma unroll
        for (int n4 = 0; n4 < 4; ++n4){
          const int ntg = w*4 + n4;
          bf16x8 bh = as_bf(BH[(ntg*8 + kt)*64 + l]);
          bf16x8 bl = as_bf(BL[(ntg*8 + kt)*64 + l]);
          acc[n4] = __builtin_amdgcn_mfma_f32_16x16x32_bf16(ah, bh, acc[n4], 0, 0, 0);
          acc[n4] = __builtin_amdgcn_mfma_f32_16x16x32_bf16(av, bh, acc[n4], 0, 0, 0);
          acc[n4] = __builtin_amdgcn_mfma_f32_16x16x32_bf16(ah, bl, acc[n4], 0, 0, 0);
        }
      }
      const int row0 = (l >> 4)*4;
      if (row0 < 8){
        const int colb = w*64 + (l & 15);
#pragma unroll
        for (int n4 = 0; n4 < 4; ++n4){
          int col = colb + n4*16;
          float b = sm.s.sb[col];
          float wv = sm.s.wy[col];
#pragma unroll
          for (int j = 0; j < 4; ++j)
            sm.s.g[row0+j][col] = acc[n4][j] + b + sm.s.yp[row0+j]*wv;
        }
      }
    }
    __syncthreads();

    {
      unsigned short* AFH = (unsigned short*)sm.s.afh;
      unsigned short* AFL = (unsigned short*)sm.s.afl;
#pragma unroll
      for (int h2 = 0; h2 < 2; ++h2){
        int idx = h2*NT + tid;
        int r = idx >> 7, j = idx & 127;
        float iv = sigf (sm.s.g[r][j]);
        float fv = sigf (sm.s.g[r][j + 128]);
        float gv = tanhx(sm.s.g[r][j + 256]);
        float ov = sigf (sm.s.g[r][j + 384]);
        float cn = fv * sm.s.lc[r][j] + iv * gv;
        float hn = ov * tanhx(cn);
        sm.s.lc[r][j] = cn; sm.s.lh[r][j] = hn;
        int kt = j >> 5, lane = (((j & 31) >> 3) << 4) | r, jj = j & 7;
        unsigned short h_ = bf16rne(hn);
        AFH[(kt*64 + lane)*8 + jj] = h_;
        AFL[(kt*64 + lane)*8 + jj] = bf16rne(hn - bfval(h_));
      }
    }
    __syncthreads();

    {
      const int r = w, lx = l;
      float p = sm.s.lh[r][lx]*sm.s.fcv[lx] + sm.s.lh[r][lx+64]*sm.s.fcv[lx+64];
      p = wsum64(p);
      if (lx == 0) sm.s.yp[r] = p + fcb[0];
    }
    if (dop){
      int r = tid >> 5, d0 = (tid & 31)*4;
      unsigned short* AFH = (unsigned short*)sm.s.afh;
      unsigned short* AFL = (unsigned short*)sm.s.afl;
      int kt = 4 + (d0 >> 5), lane = (((d0 & 31) >> 3) << 4) | r, jj0 = d0 & 7;
      float vv[4] = {pf.x, pf.y, pf.z, pf.w};
#pragma unroll
      for (int p = 0; p < 4; ++p){
        unsigned short h_ = bf16rne(vv[p]);
        AFH[(kt*64 + lane)*8 + jj0 + p] = h_;
        AFL[(kt*64 + lane)*8 + jj0 + p] = bf16rne(vv[p] - bfval(h_));
      }
    }
    __syncthreads();
  }

  if (tid < M) out[b0 + tid] = sm.s.yp[tid];
}

// ================= Fallback (round-3 VALU kernels, if ws tiny) ===============
struct FSM1 {
  float x[M][DD]; float h[M][HH]; float c[M][HH];
  float a[M][DD]; float xw[M][DD]; float g[M][NG];
};
struct FP1 { FSM1 s; float red[8][512]; };
union __align__(16) FSMA { FP1 p1; P2S p2; float pad[21504]; };

__global__ __launch_bounds__(NT, 2) void fb_ph12_kernel(
    const float* __restrict__ X,
    const float* __restrict__ saW,  const float* __restrict__ saU,  const float* __restrict__ sab,
    const float* __restrict__ saWa, const float* __restrict__ saUa, const float* __restrict__ saba,
    const float* __restrict__ saVa,
    const float* __restrict__ taWa, const float* __restrict__ taba, const float* __restrict__ taVa,
    float* __restrict__ out, float* __restrict__ Hws)
{
  __shared__ FSMA sm;
  const int tid = threadIdx.x;
  const int b0  = blockIdx.x * M;
  const int w   = tid >> 6, l = tid & 63;

  for (int idx = tid; idx < M*HH; idx += NT){
    int r = idx >> 7, j = idx & 127;
    sm.p1.s.h[r][j] = 0.f; sm.p1.s.c[r][j] = 0.f;
  }
  { int r = tid >> 6, d = tid & 63;
    sm.p1.s.x[r][d] = X[(size_t)(b0+r)*SS*DD + d]; }
  __syncthreads();

  for (int t = 0; t < SS; ++t){
    {
      float pr[M];
#pragma unroll
      for (int r = 0; r < M; ++r) pr[r] = 0.f;
      { const int kb = w*8;
#pragma unroll
        for (int q = 0; q < 2; ++q){
          const int k = kb + q*4;
          const float* wp = saWa + (size_t)k*DD + l;
          float w0 = wp[0], w1 = wp[DD], w2 = wp[2*DD], w3 = wp[3*DD];
#pragma unroll
          for (int r = 0; r < M; ++r){
            float4 v = *(const float4*)&sm.p1.s.x[r][k];
            pr[r] += w0*v.x + w1*v.y + w2*v.z + w3*v.w;
          }
        }
      }
      { const int kb = w*16;
#pragma unroll
        for (int q = 0; q < 4; ++q){
          const int k = kb + q*4;
          const float* wp = saUa + (size_t)k*DD + l;
          float w0 = wp[0], w1 = wp[DD], w2 = wp[2*DD], w3 = wp[3*DD];
#pragma unroll
          for (int r = 0; r < M; ++r){
            float4 v = *(const float4*)&sm.p1.s.h[r][k];
            pr[r] += w0*v.x + w1*v.y + w2*v.z + w3*v.w;
          }
        }
      }
      { const int kb = w*16;
#pragma unroll
        for (int q = 0; q < 4; ++q){
          const int k = kb + q*4;
          const float* wp = saUa + (size_t)(HH + k)*DD + l;
          float w0 = wp[0], w1 = wp[DD], w2 = wp[2*DD], w3 = wp[3*DD];
#pragma unroll
          for (int r = 0; r < M; ++r){
            float4 v = *(const float4*)&sm.p1.s.c[r][k];
            pr[r] += w0*v.x + w1*v.y + w2*v.z + w3*v.w;
          }
        }
      }
#pragma unroll
      for (int r = 0; r < M; ++r) sm.p1.red[w][r*64 + l] = pr[r];
    }
    __syncthreads();
    {
      float s = saba[l];
#pragma unroll
      for (int u = 0; u < 8; ++u) s += sm.p1.red[u][w*64 + l];
      sm.p1.s.a[w][l] = tanhx(s);
    }
    __syncthreads();
    {
      float pr[M];
#pragma unroll
      for (int r = 0; r < M; ++r) pr[r] = 0.f;
      const int kb = w*8;
#pragma unroll
      for (int q = 0; q < 2; ++q){
        const int k = kb + q*4;
        const float* wp = saVa + (size_t)k*DD + l;
        float w0 = wp[0], w1 = wp[DD], w2 = wp[2*DD], w3 = wp[3*DD];
#pragma unroll
        for (int r = 0; r < M; ++r){
          float4 v = *(const float4*)&sm.p1.s.a[r][k];
          pr[r] += w0*v.x + w1*v.y + w2*v.z + w3*v.w;
        }
      }
#pragma unroll
      for (int r = 0; r < M; ++r) sm.p1.red[w][r*64 + l] = pr[r];
    }
    __syncthreads();
    {
      float s = 0.f;
#pragma unroll
      for (int u = 0; u < 8; ++u) s += sm.p1.red[u][w*64 + l];
      float mm = wmax64(s);
      float e  = __expf(s - mm);
      float al = e * (1.0f / wsum64(e));
      out[A_OFF + (size_t)t*BB*DD + (size_t)(b0+w)*DD + l] = al;
      sm.p1.s.xw[w][l] = al * sm.p1.s.x[w][l];
    }
    __syncthreads();
    {
      const int c0 = tid;
      float acc[M];
      const float bv = sab[c0];
#pragma unroll
      for (int r = 0; r < M; ++r) acc[r] = bv;
      for (int k = 0; k < DD; k += 4){
        const float* wp = saW + (size_t)k*NG + c0;
        float w0 = wp[0], w1 = wp[NG], w2 = wp[2*NG], w3 = wp[3*NG];
#pragma unroll
        for (int r = 0; r < M; ++r){
          float4 v = *(const float4*)&sm.p1.s.xw[r][k];
          acc[r] += w0*v.x + w1*v.y + w2*v.z + w3*v.w;
        }
      }
      for (int k = 0; k < HH; k += 4){
        const float* wp = saU + (size_t)k*NG + c0;
        float w0 = wp[0], w1 = wp[NG], w2 = wp[2*NG], w3 = wp[3*NG];
#pragma unroll
        for (int r = 0; r < M; ++r){
          float4 v = *(const float4*)&sm.p1.s.h[r][k];
          acc[r] += w0*v.x + w1*v.y + w2*v.z + w3*v.w;
        }
      }
#pragma unroll
      for (int r = 0; r < M; ++r) sm.p1.s.g[r][c0] = acc[r];
    }
    __syncthreads();
    for (int idx = tid; idx < M*HH; idx += NT){
      int r = idx >> 7, j = idx & 127;
      float iv = sigf (sm.p1.s.g[r][j]);
      float fv = sigf (sm.p1.s.g[r][j +   HH]);
      float gv = tanhx(sm.p1.s.g[r][j + 2*HH]);
      float ov = sigf (sm.p1.s.g[r][j + 3*HH]);
      float cn = fv * sm.p1.s.c[r][j] + iv * gv;
      float hn = ov * tanhx(cn);
      sm.p1.s.c[r][j] = cn; sm.p1.s.h[r][j] = hn;
      Hws[(size_t)(b0+r)*SS*HH + (size_t)t*HH + j] = hn;
    }
    if (t + 1 < SS){
      int r = tid >> 6, d = tid & 63;
      sm.p1.s.x[r][d] = X[(size_t)(b0+r)*SS*DD + (size_t)(t+1)*DD + d];
    }
    __syncthreads();
  }

  for (int r = 0; r < M; ++r){
    float* Hrow = Hws + (size_t)(b0+r)*SS*HH;
    const int c  = tid & 127;
    const int th = tid >> 7;
    float hacc[32];
#pragma unroll
    for (int i = 0; i < 32; ++i) hacc[i] = 0.f;
#pragma unroll
    for (int ch = 0; ch < 4; ++ch){
      for (int idx = tid; idx < 32*HH/4; idx += NT)
        ((float4*)sm.p2.A)[idx] = ((const float4*)(Hrow + (size_t)ch*32*HH))[idx];
      __syncthreads();
      { float acc[8];
        const float bv = taba[c];
#pragma unroll
        for (int i = 0; i < 8; ++i) acc[i] = bv;
        for (int k = 0; k < HH; k += 4){
          const float* wp = taWa + (size_t)k*SS + c;
          float w0 = wp[0], w1 = wp[SS], w2 = wp[2*SS], w3 = wp[3*SS];
#pragma unroll
          for (int i = 0; i < 8; ++i){
            float4 v = *(const float4*)&sm.p2.A[th*8+i][k];
            acc[i] += w0*v.x + w1*v.y + w2*v.z + w3*v.w;
          }
        }
#pragma unroll
        for (int i = 0; i < 8; ++i) sm.p2.tmp[th*8+i][c] = tanhx(acc[i]);
      }
      __syncthreads();
      { float acc[8];
#pragma unroll
        for (int i = 0; i < 8; ++i) acc[i] = 0.f;
        for (int k = 0; k < SS; k += 4){
          const float* wp = taVa + (size_t)k*SS + c;
          float w0 = wp[0], w1 = wp[SS], w2 = wp[2*SS], w3 = wp[3*SS];
#pragma unroll
          for (int i = 0; i < 8; ++i){
            float4 v = *(const float4*)&sm.p2.tmp[th*8+i][k];
            acc[i] += w0*v.x + w1*v.y + w2*v.z + w3*v.w;
          }
        }
#pragma unroll
        for (int i = 0; i < 8; ++i) sm.p2.bp[th*8+i][c] = acc[i];
      }
      __syncthreads();
      { const int wv = tid >> 6, lane = tid & 63;
#pragma unroll
        for (int it = 0; it < 4; ++it){
          int tl = wv + 8*it;
          float v0 = sm.p2.bp[tl][lane], v1 = sm.p2.bp[tl][lane+64];
          float mm = wmax64(fmaxf(v0, v1));
          float e0 = __expf(v0 - mm), e1 = __expf(v1 - mm);
          float inv = 1.0f / wsum64(e0 + e1);
          e0 *= inv; e1 *= inv;
          size_t bo = BETA_OFF + (size_t)(ch*32+tl)*BB*SS + (size_t)(b0+r)*SS;
          out[bo + lane]      = e0;
          out[bo + lane + 64] = e1;
          sm.p2.bp[tl][lane]      = e0;
          sm.p2.bp[tl][lane + 64] = e1;
        }
      }
      __syncthreads();
      for (int k = 0; k < SS; k += 4){
        const float* hp = Hrow + (size_t)k*HH + c;
        float hv0 = hp[0], hv1 = hp[HH], hv2 = hp[2*HH], hv3 = hp[3*HH];
#pragma unroll
        for (int i = 0; i < 8; ++i){
          float4 bv = *(const float4*)&sm.p2.bp[th*8+i][k];
          hacc[ch*8+i] += bv.x*hv0 + bv.y*hv1 + bv.z*hv2 + bv.w*hv3;
        }
      }
    }
    __syncthreads();
#pragma unroll
    for (int ch = 0; ch < 4; ++ch)
#pragma unroll
      for (int i = 0; i < 8; ++i)
        Hrow[(size_t)(ch*32 + th*8 + i)*HH + c] = hacc[ch*8+i];
    __syncthreads();
  }
}

__global__ __launch_bounds__(NT, 2) void fb_ph3_kernel(
    const float* __restrict__ X, const float* __restrict__ Ha,
    const float* __restrict__ taW, const float* __restrict__ taU,
    const float* __restrict__ tab, const float* __restrict__ taWy,
    const float* __restrict__ fcw, const float* __restrict__ fcb,
    float* __restrict__ out)
{
  __shared__ struct {
    float ha[M][HH]; float lh[M][HH]; float lc[M][HH];
    float g[M][NG];  float yp[M];
  } s;
  const int tid = threadIdx.x;
  const int b0  = blockIdx.x * M;

  for (int idx = tid; idx < M*HH; idx += NT){
    int r = idx >> 7, j = idx & 127;
    s.lh[r][j] = 0.f; s.lc[r][j] = 0.f;
  }
  if (tid < M) s.yp[tid] = X[(size_t)(b0+tid)*SS*DD + (DD-1)];
  if (tid < M*HH/4){
    int r = tid >> 5, q = tid & 31;
    ((float4*)s.ha)[tid] = *(const float4*)(Ha + (size_t)(b0+r)*SS*HH + q*4);
  }
  __syncthreads();

  for (int t = 0; t < SS; ++t){
    {
      const int c0 = tid;
      const float wy = taWy[c0];
      const float tb = tab[c0];
      float acc[M];
#pragma unroll
      for (int r = 0; r < M; ++r) acc[r] = tb + s.yp[r]*wy;
      for (int k = 0; k < HH; k += 4){
        const float* wp = taW + (size_t)k*NG + c0;
        float a0 = wp[0], a1 = wp[NG], a2 = wp[2*NG], a3 = wp[3*NG];
#pragma unroll
        for (int r = 0; r < M; ++r){
          float4 v = *(const float4*)&s.ha[r][k];
          acc[r] += a0*v.x + a1*v.y + a2*v.z + a3*v.w;
        }
      }
      for (int k = 0; k < HH; k += 4){
        const float* wp = taU + (size_t)k*NG + c0;
        float a0 = wp[0], a1 = wp[NG], a2 = wp[2*NG], a3 = wp[3*NG];
#pragma unroll
        for (int r = 0; r < M; ++r){
          float4 v = *(const float4*)&s.lh[r][k];
          acc[r] += a0*v.x + a1*v.y + a2*v.z + a3*v.w;
        }
      }
#pragma unroll
      for (int r = 0; r < M; ++r) s.g[r][c0] = acc[r];
    }
    __syncthreads();
    for (int idx = tid; idx < M*HH; idx += NT){
      int r = idx >> 7, j = idx & 127;
      float iv = sigf (s.g[r][j]);
      float fv = sigf (s.g[r][j +   HH]);
      float gv = tanhx(s.g[r][j + 2*HH]);
      float ov = sigf (s.g[r][j + 3*HH]);
      float cn = fv * s.lc[r][j] + iv * gv;
      float hn = ov * tanhx(cn);
      s.lc[r][j] = cn; s.lh[r][j] = hn;
    }
    if (t + 1 < SS && tid < M*HH/4){
      int r = tid >> 5, q = tid & 31;
      ((float4*)s.ha)[tid] =
        *(const float4*)(Ha + (size_t)(b0+r)*SS*HH + (size_t)(t+1)*HH + q*4);
    }
    __syncthreads();
    {
      const int r = tid >> 6, lx = tid & 63;
      float p = s.lh[r][lx]*fcw[lx] + s.lh[r][lx+64]*fcw[lx+64];
      p = wsum64(p);
      if (lx == 0) s.yp[r] = p + fcb[0];
    }
    __syncthreads();
  }
  if (tid < M) out[b0 + tid] = s.yp[tid];
}

extern "C" void kernel_launch(void* const* d_in, const int* in_sizes, int n_in,
                              void* d_out, int out_size, void* d_ws, size_t ws_size,
                              hipStream_t stream) {
  (void)in_sizes; (void)n_in; (void)out_size;
  const float* X    = (const float*)d_in[0];
  const float* saW  = (const float*)d_in[1];
  const float* saU  = (const float*)d_in[2];
  const float* sab  = (const float*)d_in[3];
  const float* saWa = (const float*)d_in[4];
  const float* saUa = (const float*)d_in[5];
  const float* saba = (const float*)d_in[6];
  const float* saVa = (const float*)d_in[7];
  const float* taWa = (const float*)d_in[8];
  // d_in[9] = ta_Ua: unused by the reference forward pass
  const float* taba = (const float*)d_in[10];
  const float* taVa = (const float*)d_in[11];
  const float* taW  = (const float*)d_in[12];
  const float* taU  = (const float*)d_in[13];
  const float* tab  = (const float*)d_in[14];
  const float* taWy = (const float*)d_in[15];
  const float* fcw  = (const float*)d_in[16];
  const float* fcb  = (const float*)d_in[17];
  float* out = (float*)d_out;

  if (ws_size >= NEED2_BYTES){
    unsigned short* Fr = (unsigned short*)d_ws;
    float* Hws = (float*)((char*)d_ws + FRAG_BYTES);
    hipLaunchKernelGGL(repack_kernel, dim3(512), dim3(256), 0, stream,
                       saW, saU, saWa, saUa, saVa, taU, taW, taWa, taVa, Fr);
    hipLaunchKernelGGL(mf_ph1_kernel, dim3(BB / M), dim3(NT), 0, stream,
                       X, sab, saba, Fr, out, Hws);
    if (ws_size >= NEED3_BYTES){
      float* G0 = (float*)((char*)d_ws + FRAG_BYTES + H_BYTES);
      hipLaunchKernelGGL(ph2g_kernel, dim3(BB), dim3(NT), 0, stream,
                         taba, Fr, tab, out, Hws, G0);
      hipLaunchKernelGGL(mf_ph3h_kernel, dim3(BB / M), dim3(NT), 0, stream,
                         X, Fr, G0, taWy, fcw, fcb, out);
    } else {
      hipLaunchKernelGGL(ph2_kernel, dim3(BB), dim3(NT), 0, stream,
                         taba, Fr, out, Hws);
      hipLaunchKernelGGL(mf_ph3_kernel, dim3(BB / M), dim3(NT), 0, stream,
                         X, Hws, Fr, tab, taWy, fcw, fcb, out);
    }
  } else {
    float* Hws = (float*)d_ws;
    hipLaunchKernelGGL(fb_ph12_kernel, dim3(BB / M), dim3(NT), 0, stream,
                       X, saW, saU, sab, saWa, saUa, saba, saVa,
                       taWa, taba, taVa, out, Hws);
    hipLaunchKernelGGL(fb_ph3_kernel, dim3(BB / M), dim3(NT), 0, stream,
                       X, Hws, taW, taU, tab, taWy, fcw, fcb, out);
  }
}